// Round 4
// baseline (32294.107 us; speedup 1.0000x reference)
//
#include <hip/hip_runtime.h>
#include <hip/hip_bf16.h>

typedef __hip_bfloat16 bf16;

// Problem dims
#define B_    16
#define T_    128
#define S_    192
#define H_    768
#define G4_   3072      // 4*H
#define V_    30522
#define AV_   200
#define L_    191       // L_SRC-1
#define TM1_  127       // T-1
#define R_    2032      // B*(T-1)
#define K5_   3840      // 5*H

__device__ __forceinline__ float bf2f(bf16 v) { return __bfloat162float(v); }
__device__ __forceinline__ bf16  f2bf(float v) { return __float2bfloat16(v); }
__device__ __forceinline__ unsigned short f2us(float v) { bf16 h = f2bf(v); return *reinterpret_cast<unsigned short*>(&h); }
__device__ __forceinline__ float uslo(unsigned u) { union { unsigned i; float f; } x; x.i = u << 16; return x.f; }
__device__ __forceinline__ float ushi(unsigned u) { union { unsigned i; float f; } x; x.i = u & 0xffff0000u; return x.f; }
__device__ __forceinline__ float us2f(unsigned short u) { union { unsigned i; float f; } x; x.i = ((unsigned)u) << 16; return x.f; }
__device__ __forceinline__ float sigm(float x) { return 1.0f / (1.0f + expf(-x)); }

// 4-element converting loads (16B-or-8B vector loads)
__device__ __forceinline__ float4 ld4(const float* p) { return *(const float4*)p; }
__device__ __forceinline__ float4 ld4(const bf16* p) {
    ushort4 v = *(const ushort4*)p;
    return make_float4(us2f(v.x), us2f(v.y), us2f(v.z), us2f(v.w));
}

// ---------------------------------------------------------------------------
// Generic GEMM: C[M,N] = act( A[M,K] * W[N,K]^T + bias1 + bias2 )
// A: TA rows (K contiguous, leading dim lda); W: TW rows (K contiguous).
// Output to bf16 (Ch) or f32 (Cf). rowdiv>0 remaps A row r -> r + r/rowdiv + 1
// (the enc [:,1:] slice). 64x64 tile, 256 threads, 4x4/thread, K-step 16.
// ---------------------------------------------------------------------------
template <typename TA, typename TW>
__global__ __launch_bounds__(256) void gemm_bt(
    const TA* __restrict__ A, const TW* __restrict__ W,
    const float* __restrict__ bias1, const float* __restrict__ bias2,
    bf16* __restrict__ Ch, float* __restrict__ Cf,
    int M, int N, int K, int act, int rowdiv, int lda)
{
    __shared__ float As[16][64];
    __shared__ float Ws[16][64];
    const int tid = threadIdx.x;
    const int tx = tid & 15;
    const int ty = tid >> 4;
    const int bm = blockIdx.x * 64;
    const int bn = blockIdx.y * 64;
    const int lr = tid >> 2;          // 0..63 (tile row for staging)
    const int lk = (tid & 3) * 4;     // 0,4,8,12

    const int rA = bm + lr;
    const int ra = (rowdiv > 0) ? (rA + rA / rowdiv + 1) : rA;
    const TA* aRow = A + (size_t)ra * lda;
    const int rW = bn + lr;
    const TW* wRow = W + (size_t)rW * K;
    const bool aOK = (rA < M);
    const bool wOK = (rW < N);

    float acc[4][4];
#pragma unroll
    for (int i = 0; i < 4; ++i)
#pragma unroll
        for (int j = 0; j < 4; ++j) acc[i][j] = 0.f;

    for (int k0 = 0; k0 < K; k0 += 16) {
        float4 av = make_float4(0.f, 0.f, 0.f, 0.f);
        float4 wv = make_float4(0.f, 0.f, 0.f, 0.f);
        if (aOK) av = ld4(aRow + k0 + lk);
        if (wOK) wv = ld4(wRow + k0 + lk);
        As[lk + 0][lr] = av.x; As[lk + 1][lr] = av.y; As[lk + 2][lr] = av.z; As[lk + 3][lr] = av.w;
        Ws[lk + 0][lr] = wv.x; Ws[lk + 1][lr] = wv.y; Ws[lk + 2][lr] = wv.z; Ws[lk + 3][lr] = wv.w;
        __syncthreads();
#pragma unroll
        for (int kk = 0; kk < 16; ++kk) {
            float a0 = As[kk][ty * 4 + 0];
            float a1 = As[kk][ty * 4 + 1];
            float a2 = As[kk][ty * 4 + 2];
            float a3 = As[kk][ty * 4 + 3];
            float w0 = Ws[kk][tx * 4 + 0];
            float w1 = Ws[kk][tx * 4 + 1];
            float w2 = Ws[kk][tx * 4 + 2];
            float w3 = Ws[kk][tx * 4 + 3];
            acc[0][0] += a0 * w0; acc[0][1] += a0 * w1; acc[0][2] += a0 * w2; acc[0][3] += a0 * w3;
            acc[1][0] += a1 * w0; acc[1][1] += a1 * w1; acc[1][2] += a1 * w2; acc[1][3] += a1 * w3;
            acc[2][0] += a2 * w0; acc[2][1] += a2 * w1; acc[2][2] += a2 * w2; acc[2][3] += a2 * w3;
            acc[3][0] += a3 * w0; acc[3][1] += a3 * w1; acc[3][2] += a3 * w2; acc[3][3] += a3 * w3;
        }
        __syncthreads();
    }

#pragma unroll
    for (int i = 0; i < 4; ++i) {
        const int row = bm + ty * 4 + i;
        if (row >= M) continue;
#pragma unroll
        for (int j = 0; j < 4; ++j) {
            const int col = bn + tx * 4 + j;
            if (col >= N) continue;
            float v = acc[i][j];
            if (bias1) v += bias1[col];
            if (bias2) v += bias2[col];
            if (act == 1) v = tanhf(v);
            if (Ch) Ch[(size_t)row * N + col] = f2bf(v);
            else    Cf[(size_t)row * N + col] = v;
        }
    }
}

// ---------------------------------------------------------------------------
// f32 -> bf16 bulk convert (for Whh matrices)
// ---------------------------------------------------------------------------
__global__ void f2b_kernel(const float* __restrict__ in, bf16* __restrict__ out, int n4)
{
    const int i = blockIdx.x * 256 + threadIdx.x;
    if (i >= n4) return;
    float4 v = *(const float4*)(in + (size_t)i * 4);
    ushort4 o;
    o.x = f2us(v.x); o.y = f2us(v.y); o.z = f2us(v.z); o.w = f2us(v.w);
    *(ushort4*)(out + (size_t)i * 4) = o;
}

// ---------------------------------------------------------------------------
// Row gather + convert: out[r][:] = bf16(emb[ids[r]][:])   (768 per row)
// ---------------------------------------------------------------------------
__global__ void gather_rows_kernel(const int* __restrict__ ids,
                                   const float* __restrict__ emb,
                                   bf16* __restrict__ out)
{
    const int r = blockIdx.x;
    const float4* src = (const float4*)(emb + (size_t)ids[r] * H_);
    ushort4* dst = (ushort4*)(out + (size_t)r * H_);
    for (int h = threadIdx.x; h < H_ / 4; h += 256) {
        float4 v = src[h];
        ushort4 o;
        o.x = f2us(v.x); o.y = f2us(v.y); o.z = f2us(v.z); o.w = f2us(v.w);
        dst[h] = o;
    }
}

// ---------------------------------------------------------------------------
// Fused 3x LSTM. 48 blocks: block = (which_lstm, batch). h,c,g in LDS.
// px = x@Wih^T + bih + bhh precomputed (bf16). Whh (bf16) streamed per step.
// ---------------------------------------------------------------------------
__global__ __launch_bounds__(1024) void lstm3_kernel(
    const bf16* __restrict__ pxe, const bf16* __restrict__ pxa, const bf16* __restrict__ pxw,
    const bf16* __restrict__ We,  const bf16* __restrict__ Wa,  const bf16* __restrict__ Ww,
    bf16* __restrict__ oute, bf16* __restrict__ outa, bf16* __restrict__ outw)
{
    const int bid = blockIdx.x;
    const int which = bid >> 4;
    const int b = bid & 15;
    const bf16* px; const bf16* Whh; bf16* out; int Tn;
    if (which == 0)      { px = pxe; Whh = We; out = oute; Tn = T_; }
    else if (which == 1) { px = pxa; Whh = Wa; out = outa; Tn = T_; }
    else                 { px = pxw; Whh = Ww; out = outw; Tn = S_; }

    __shared__ float hS[H_];
    __shared__ float cS[H_];
    __shared__ float gS[G4_];
    const int tid = threadIdx.x;
    if (tid < H_) { hS[tid] = 0.f; cS[tid] = 0.f; }
    __syncthreads();

    for (int t = 0; t < Tn; ++t) {
        const bf16* pxt = px + ((size_t)b * Tn + t) * G4_;
#pragma unroll
        for (int jj = 0; jj < 3; ++jj) {
            const int j = tid + jj * 1024;
            const uint4* wr = (const uint4*)(Whh + (size_t)j * H_);
            float s = 0.f;
#pragma unroll 8
            for (int k8 = 0; k8 < H_ / 8; ++k8) {
                uint4 u = wr[k8];
                const int kb = k8 * 8;
                s += hS[kb + 0] * uslo(u.x) + hS[kb + 1] * ushi(u.x);
                s += hS[kb + 2] * uslo(u.y) + hS[kb + 3] * ushi(u.y);
                s += hS[kb + 4] * uslo(u.z) + hS[kb + 5] * ushi(u.z);
                s += hS[kb + 6] * uslo(u.w) + hS[kb + 7] * ushi(u.w);
            }
            gS[j] = s + bf2f(pxt[j]);
        }
        __syncthreads();
        if (tid < H_) {
            const float ig = gS[tid];
            const float fg = gS[tid + H_];
            const float gg = gS[tid + 2 * H_];
            const float og = gS[tid + 3 * H_];
            const float cn = sigm(fg) * cS[tid] + sigm(ig) * tanhf(gg);
            const float hn = sigm(og) * tanhf(cn);
            cS[tid] = cn; hS[tid] = hn;
            out[((size_t)b * Tn + t) * H_ + tid] = f2bf(hn);
        }
        __syncthreads();
    }
}

// ---------------------------------------------------------------------------
// Counters scan (reference compute_counters). 16 lanes, 127 sequential steps.
// ---------------------------------------------------------------------------
__global__ void counters_kernel(const int* __restrict__ edits, const int* __restrict__ org,
                                int* __restrict__ cd, int* __restrict__ ci, int* __restrict__ ca)
{
    const int b = threadIdx.x;
    if (b >= B_) return;
    int vd = 0, vi = 0, va = 0;
    for (int t = 0; t < TM1_; ++t) {
        cd[b * TM1_ + t] = vd; ci[b * TM1_ + t] = vi; ca[b * TM1_ + t] = va;
        const int g = edits[b * T_ + t + 1];
        const int vd2 = vd + ((g == 3 || g == 4) ? 1 : 0);
        const int alive = (g != 4 && g != 2 && g != 0) ? 1 : 0;
        const int vi2 = vi + alive;
        int nxt = va + 1; if (nxt > L_ - 1) nxt = L_ - 1;
        const int tok = org[b * L_ + nxt];
        const bool cond = alive && (g != 3) && (va + 1 < L_) && (tok == 103 || tok == 3 || tok == 4);
        const int va2 = cond ? (va + 1) : max(vd2, va);
        vd = vd2; vi = vi2; va = va2;
    }
}

// c_word[r][:] = out_w[b][ci[r]][:]
__global__ void gather_cword_kernel(const bf16* __restrict__ outw, const int* __restrict__ ci,
                                    bf16* __restrict__ cw)
{
    const int r = blockIdx.x;
    const int b = r / TM1_;
    const unsigned* src = (const unsigned*)(outw + ((size_t)b * S_ + ci[r]) * H_);
    unsigned* dst = (unsigned*)(cw + (size_t)r * H_);
    for (int h = threadIdx.x; h < H_ / 2; h += 256) dst[h] = src[h];
}

// ---------------------------------------------------------------------------
// wref softmax (2-way) for edit & action decoders + mix c_input/c_anno.
// block per row r=(b,t).
// ---------------------------------------------------------------------------
__global__ __launch_bounds__(256) void ref_combine_kernel(
    const bf16* __restrict__ oute, const bf16* __restrict__ outa, const bf16* __restrict__ enc,
    const float* __restrict__ Wref, const float* __restrict__ bref,
    const int* __restrict__ cd, const int* __restrict__ ca,
    bf16* __restrict__ ced, bf16* __restrict__ cac)
{
    const int r = blockIdx.x;
    const int b = r / TM1_;
    const int t = r % TM1_;
    const bf16* de = oute + ((size_t)b * T_ + t) * H_;
    const bf16* da = outa + ((size_t)b * T_ + t) * H_;
    const int tid = threadIdx.x;
    __shared__ float red[256][4];
    float s0 = 0.f, s1 = 0.f, s2 = 0.f, s3 = 0.f;
    for (int k = tid; k < H_; k += 256) {
        const float w0 = Wref[k];
        const float w1 = Wref[H_ + k];
        const float e = bf2f(de[k]);
        const float a = bf2f(da[k]);
        s0 += e * w0; s1 += e * w1; s2 += a * w0; s3 += a * w1;
    }
    red[tid][0] = s0; red[tid][1] = s1; red[tid][2] = s2; red[tid][3] = s3;
    __syncthreads();
    for (int off = 128; off > 0; off >>= 1) {
        if (tid < off) {
            red[tid][0] += red[tid + off][0];
            red[tid][1] += red[tid + off][1];
            red[tid][2] += red[tid + off][2];
            red[tid][3] += red[tid + off][3];
        }
        __syncthreads();
    }
    const float br0 = bref[0], br1 = bref[1];
    const float xe0 = red[0][0] + br0, xe1 = red[0][1] + br1;
    const float xa0 = red[0][2] + br0, xa1 = red[0][3] + br1;
    // 2-way softmax
    const float me = fmaxf(xe0, xe1);
    const float ee0 = expf(xe0 - me), ee1 = expf(xe1 - me);
    const float pe0 = ee0 / (ee0 + ee1), pe1 = ee1 / (ee0 + ee1);
    const float ma = fmaxf(xa0, xa1);
    const float ea0 = expf(xa0 - ma), ea1 = expf(xa1 - ma);
    const float pa0 = ea0 / (ea0 + ea1), pa1 = ea1 / (ea0 + ea1);

    const bf16* ei = enc + ((size_t)b * L_ + cd[r]) * H_;
    const bf16* ea = enc + ((size_t)b * L_ + ca[r]) * H_;
    for (int h = tid; h < H_; h += 256) {
        const float vi = bf2f(ei[h]);
        const float va = bf2f(ea[h]);
        ced[(size_t)r * H_ + h] = f2bf(pe0 * vi + pe1 * va);
        cac[(size_t)r * H_ + h] = f2bf(pa0 * vi + pa1 * va);
    }
}

// ---------------------------------------------------------------------------
// Attention: scores over L=191, softmax, applied. block per row r=(b,t).
// ---------------------------------------------------------------------------
__global__ __launch_bounds__(256) void attn_kernel(const bf16* __restrict__ q,
                                                   const bf16* __restrict__ enc,
                                                   bf16* __restrict__ app)
{
    const int r = blockIdx.x;
    const int b = r / TM1_;
    const int tid = threadIdx.x;
    __shared__ float qs[H_];
    __shared__ float p[L_ + 1];
    __shared__ float red[256];
    const bf16* qrow = q + (size_t)r * H_;
    for (int h = tid; h < H_; h += 256) qs[h] = bf2f(qrow[h]);
    __syncthreads();
    const bf16* eb = enc + (size_t)b * L_ * H_;
    float myv = -1e30f;
    if (tid < L_) {
        const unsigned* er = (const unsigned*)(eb + (size_t)tid * H_);
        float s = 0.f;
        for (int k2 = 0; k2 < H_ / 2; ++k2) {
            const unsigned u = er[k2];
            s += qs[2 * k2] * uslo(u) + qs[2 * k2 + 1] * ushi(u);
        }
        p[tid] = s;
        myv = s;
    }
    red[tid] = myv;
    __syncthreads();
    for (int off = 128; off > 0; off >>= 1) {
        if (tid < off) red[tid] = fmaxf(red[tid], red[tid + off]);
        __syncthreads();
    }
    const float m = red[0];
    __syncthreads();
    float e = 0.f;
    if (tid < L_) e = expf(p[tid] - m);
    red[tid] = e;
    __syncthreads();
    for (int off = 128; off > 0; off >>= 1) {
        if (tid < off) red[tid] += red[tid + off];
        __syncthreads();
    }
    const float invZ = 1.f / red[0];
    __syncthreads();
    if (tid < L_) p[tid] = e * invZ;
    __syncthreads();
    for (int h = tid; h < H_; h += 256) {
        float s = 0.f;
        for (int l = 0; l < L_; ++l) s += p[l] * bf2f(eb[(size_t)l * H_ + h]);
        app[(size_t)r * H_ + h] = f2bf(s);
    }
}

// feat_e = [dec_e, dec_a, app, ced, cw]; feat_a = [dec_a, dec_e, app, cac, cw]
__global__ void feat_kernel(const bf16* __restrict__ oute, const bf16* __restrict__ outa,
                            const bf16* __restrict__ app, const bf16* __restrict__ ced,
                            const bf16* __restrict__ cac, const bf16* __restrict__ cw,
                            bf16* __restrict__ fe, bf16* __restrict__ fa)
{
    const int r = blockIdx.x;
    const int b = r / TM1_;
    const int t = r % TM1_;
    const unsigned* de  = (const unsigned*)(oute + ((size_t)b * T_ + t) * H_);
    const unsigned* da  = (const unsigned*)(outa + ((size_t)b * T_ + t) * H_);
    const unsigned* ap  = (const unsigned*)(app + (size_t)r * H_);
    const unsigned* ce  = (const unsigned*)(ced + (size_t)r * H_);
    const unsigned* cA  = (const unsigned*)(cac + (size_t)r * H_);
    const unsigned* cwp = (const unsigned*)(cw + (size_t)r * H_);
    unsigned* pfe = (unsigned*)(fe + (size_t)r * K5_);
    unsigned* pfa = (unsigned*)(fa + (size_t)r * K5_);
    const int HW = H_ / 2;  // 384 uints per segment
    for (int h = threadIdx.x; h < HW; h += 256) {
        const unsigned ve = de[h], va = da[h], vap = ap[h], vce = ce[h], vca = cA[h], vcw = cwp[h];
        pfe[h] = ve;  pfe[HW + h] = va;  pfe[2 * HW + h] = vap; pfe[3 * HW + h] = vce; pfe[4 * HW + h] = vcw;
        pfa[h] = va;  pfa[HW + h] = ve;  pfa[2 * HW + h] = vap; pfa[3 * HW + h] = vca; pfa[4 * HW + h] = vcw;
    }
}

// In-place log-softmax over f32 rows (edit head, N=30522). block per row.
__global__ __launch_bounds__(1024) void logsoftmax_edit_kernel(float* __restrict__ out)
{
    float* row = out + (size_t)blockIdx.x * V_;
    const int tid = threadIdx.x;
    __shared__ float red[1024];
    float m = -1e30f;
    for (int i = tid; i < V_; i += 1024) m = fmaxf(m, row[i]);
    red[tid] = m;
    __syncthreads();
    for (int off = 512; off > 0; off >>= 1) {
        if (tid < off) red[tid] = fmaxf(red[tid], red[tid + off]);
        __syncthreads();
    }
    m = red[0];
    __syncthreads();
    float s = 0.f;
    for (int i = tid; i < V_; i += 1024) s += expf(row[i] - m);
    red[tid] = s;
    __syncthreads();
    for (int off = 512; off > 0; off >>= 1) {
        if (tid < off) red[tid] += red[tid + off];
        __syncthreads();
    }
    const float lz = m + logf(red[0]);
    __syncthreads();
    for (int i = tid; i < V_; i += 1024) row[i] = row[i] - lz;
}

// Act head log-softmax: f32 in (2032x200) -> f32 out. block per row.
__global__ __launch_bounds__(256) void logsoftmax_act_kernel(const float* __restrict__ in,
                                                             float* __restrict__ out)
{
    const float* row = in + (size_t)blockIdx.x * AV_;
    float* orow = out + (size_t)blockIdx.x * AV_;
    const int tid = threadIdx.x;
    __shared__ float red[256];
    float m = -1e30f;
    if (tid < AV_) m = row[tid];
    red[tid] = m;
    __syncthreads();
    for (int off = 128; off > 0; off >>= 1) {
        if (tid < off) red[tid] = fmaxf(red[tid], red[tid + off]);
        __syncthreads();
    }
    m = red[0];
    __syncthreads();
    float s = 0.f;
    if (tid < AV_) s = expf(row[tid] - m);
    red[tid] = s;
    __syncthreads();
    for (int off = 128; off > 0; off >>= 1) {
        if (tid < off) red[tid] += red[tid + off];
        __syncthreads();
    }
    const float lz = m + logf(red[0]);
    if (tid < AV_) orow[tid] = row[tid] - lz;
}

// ---------------------------------------------------------------------------
extern "C" void kernel_launch(void* const* d_in, const int* in_sizes, int n_in,
                              void* d_out, int out_size, void* d_ws, size_t ws_size,
                              hipStream_t stream)
{
    const int* input_edits   = (const int*)d_in[0];
    const int* input_actions = (const int*)d_in[1];
    const int* simp_sent     = (const int*)d_in[2];
    const int* org_ids       = (const int*)d_in[3];
    const float* enc_org     = (const float*)d_in[4];
    const float* emb         = (const float*)d_in[5];
    const float* Wih_e = (const float*)d_in[6];
    const float* Whh_e = (const float*)d_in[7];
    const float* bih_e = (const float*)d_in[8];
    const float* bhh_e = (const float*)d_in[9];
    const float* Wih_a = (const float*)d_in[10];
    const float* Whh_a = (const float*)d_in[11];
    const float* bih_a = (const float*)d_in[12];
    const float* bhh_a = (const float*)d_in[13];
    const float* Wih_w = (const float*)d_in[14];
    const float* Whh_w = (const float*)d_in[15];
    const float* bih_w = (const float*)d_in[16];
    const float* bhh_w = (const float*)d_in[17];
    const float* W_align = (const float*)d_in[18];
    const float* W_proj  = (const float*)d_in[19];
    const float* W_ref   = (const float*)d_in[20];
    const float* b_ref   = (const float*)d_in[21];
    const float* W_mlp   = (const float*)d_in[22];
    const float* b_mlp   = (const float*)d_in[23];
    const float* W_act   = (const float*)d_in[24];
    const float* b_act   = (const float*)d_in[25];
    const float* W_out   = (const float*)d_in[26];
    const float* b_out   = (const float*)d_in[27];
    const float* W_outact = (const float*)d_in[28];
    const float* b_outact = (const float*)d_in[29];
    const float* action_mask = (const float*)d_in[30];

    float* out = (float*)d_out;
    float* edit_out = out;                               // (2032, 30522) f32
    float* act_out  = out + (size_t)R_ * V_;             // (2032, 200)   f32

    // Workspace layout (~140 MB)
    char* p = (char*)d_ws;
    auto take = [&](size_t bytes) { void* q = (void*)p; p += ((bytes + 255) / 256) * 256; return q; };
    bf16* WhhE = (bf16*)take((size_t)G4_ * H_ * 2);
    bf16* WhhA = (bf16*)take((size_t)G4_ * H_ * 2);
    bf16* WhhW = (bf16*)take((size_t)G4_ * H_ * 2);
    bf16* xe   = (bf16*)take((size_t)B_ * T_ * H_ * 2);
    bf16* xa   = (bf16*)take((size_t)B_ * T_ * H_ * 2);
    bf16* xw   = (bf16*)take((size_t)B_ * S_ * H_ * 2);
    bf16* pxe  = (bf16*)take((size_t)B_ * T_ * G4_ * 2);
    bf16* pxa  = (bf16*)take((size_t)B_ * T_ * G4_ * 2);
    bf16* pxw  = (bf16*)take((size_t)B_ * S_ * G4_ * 2);
    bf16* oute = (bf16*)take((size_t)B_ * T_ * H_ * 2);
    bf16* outa = (bf16*)take((size_t)B_ * T_ * H_ * 2);
    bf16* outw = (bf16*)take((size_t)B_ * S_ * H_ * 2);
    bf16* enc  = (bf16*)take((size_t)B_ * L_ * H_ * 2);
    bf16* cw   = (bf16*)take((size_t)R_ * H_ * 2);
    bf16* ced  = (bf16*)take((size_t)R_ * H_ * 2);
    bf16* cac  = (bf16*)take((size_t)R_ * H_ * 2);
    bf16* qb   = (bf16*)take((size_t)R_ * H_ * 2);
    bf16* app  = (bf16*)take((size_t)R_ * H_ * 2);
    bf16* fe   = (bf16*)take((size_t)R_ * K5_ * 2);
    bf16* fa   = (bf16*)take((size_t)R_ * K5_ * 2);
    bf16* he   = (bf16*)take((size_t)R_ * H_ * 2);
    bf16* ha   = (bf16*)take((size_t)R_ * H_ * 2);
    int*  cd   = (int*)take((size_t)R_ * 4);
    int*  ci   = (int*)take((size_t)R_ * 4);
    int*  ca   = (int*)take((size_t)R_ * 4);
    float* actbuf = (float*)take((size_t)R_ * AV_ * 4);

    // 0. Convert Whh matrices to bf16 (2.36M elements each)
    const int nW4 = G4_ * H_ / 4;
    f2b_kernel<<<(nW4 + 255) / 256, 256, 0, stream>>>(Whh_e, WhhE, nW4);
    f2b_kernel<<<(nW4 + 255) / 256, 256, 0, stream>>>(Whh_a, WhhA, nW4);
    f2b_kernel<<<(nW4 + 255) / 256, 256, 0, stream>>>(Whh_w, WhhW, nW4);

    // 1. Embedding gathers (f32 emb -> bf16 rows)
    gather_rows_kernel<<<B_ * T_, 256, 0, stream>>>(input_edits, emb, xe);
    gather_rows_kernel<<<B_ * T_, 256, 0, stream>>>(input_actions, emb, xa);
    gather_rows_kernel<<<B_ * S_, 256, 0, stream>>>(simp_sent, emb, xw);

    // 2. Precompute x@Wih^T + bih + bhh for all timesteps
    dim3 g1((B_ * T_ + 63) / 64, (G4_ + 63) / 64);
    gemm_bt<bf16, float><<<g1, 256, 0, stream>>>(xe, Wih_e, bih_e, bhh_e, pxe, nullptr, B_ * T_, G4_, H_, 0, 0, H_);
    gemm_bt<bf16, float><<<g1, 256, 0, stream>>>(xa, Wih_a, bih_a, bhh_a, pxa, nullptr, B_ * T_, G4_, H_, 0, 0, H_);
    dim3 g1w((B_ * S_ + 63) / 64, (G4_ + 63) / 64);
    gemm_bt<bf16, float><<<g1w, 256, 0, stream>>>(xw, Wih_w, bih_w, bhh_w, pxw, nullptr, B_ * S_, G4_, H_, 0, 0, H_);

    // 3. enc = tanh(enc_org @ W_align^T)[:, 1:]  (row remap r -> r + r/191 + 1)
    dim3 g2((B_ * L_ + 63) / 64, (H_ + 63) / 64);
    gemm_bt<float, float><<<g2, 256, 0, stream>>>(enc_org, W_align, nullptr, nullptr, enc, nullptr, B_ * L_, H_, H_, 1, L_, H_);

    // 4. Counters scan
    counters_kernel<<<1, 64, 0, stream>>>(input_edits, org_ids, cd, ci, ca);

    // 5. The three LSTMs, concurrently (48 blocks)
    lstm3_kernel<<<48, 1024, 0, stream>>>(pxe, pxa, pxw, WhhE, WhhA, WhhW, oute, outa, outw);

    // 6. c_word gather
    gather_cword_kernel<<<R_, 256, 0, stream>>>(outw, ci, cw);

    // 7. wref mixing -> c_edit, c_action
    ref_combine_kernel<<<R_, 256, 0, stream>>>(oute, outa, enc, W_ref, b_ref, cd, ca, ced, cac);

    // 8. q = c_word @ W_proj^T
    dim3 g3((R_ + 63) / 64, (H_ + 63) / 64);
    gemm_bt<bf16, float><<<g3, 256, 0, stream>>>(cw, W_proj, nullptr, nullptr, qb, nullptr, R_, H_, H_, 0, 0, H_);

    // 9. attention -> applied
    attn_kernel<<<R_, 256, 0, stream>>>(qb, enc, app);

    // 10. feature concat
    feat_kernel<<<R_, 256, 0, stream>>>(oute, outa, app, ced, cac, cw, fe, fa);

    // 11. hidden layers (tanh)
    gemm_bt<bf16, float><<<g3, 256, 0, stream>>>(fe, W_mlp, b_mlp, nullptr, he, nullptr, R_, H_, K5_, 1, 0, K5_);
    gemm_bt<bf16, float><<<g3, 256, 0, stream>>>(fa, W_act, b_act, nullptr, ha, nullptr, R_, H_, K5_, 1, 0, K5_);

    // 12. act head: logits (f32) then log-softmax -> d_out tail (f32)
    dim3 g4((R_ + 63) / 64, (AV_ + 63) / 64);
    gemm_bt<bf16, float><<<g4, 256, 0, stream>>>(ha, W_outact, b_outact, action_mask, nullptr, actbuf, R_, AV_, H_, 0, 0, H_);
    logsoftmax_act_kernel<<<R_, 256, 0, stream>>>(actbuf, act_out);

    // 13. edit head: logits (f32, straight into d_out) then in-place log-softmax
    dim3 g5((R_ + 63) / 64, (V_ + 63) / 64);
    gemm_bt<bf16, float><<<g5, 256, 0, stream>>>(he, W_out, b_out, nullptr, nullptr, edit_out, R_, V_, H_, 0, 0, H_);
    logsoftmax_edit_kernel<<<R_, 1024, 0, stream>>>(edit_out);
}

// Round 5
// 11955.036 us; speedup vs baseline: 2.7013x; 2.7013x over previous
//
#include <hip/hip_runtime.h>
#include <hip/hip_bf16.h>

typedef __hip_bfloat16 bf16;
typedef _Float16 f16;
typedef f16 f16x2 __attribute__((ext_vector_type(2)));

// Problem dims
#define B_    16
#define T_    128
#define S_    192
#define H_    768
#define G4_   3072      // 4*H
#define V_    30522
#define AV_   200
#define L_    191       // L_SRC-1
#define TM1_  127       // T-1
#define R_    2032      // B*(T-1)
#define K5_   3840      // 5*H
#define KK_   384       // H/2 (k-pairs)

__device__ __forceinline__ float bf2f(bf16 v) { return __bfloat162float(v); }
__device__ __forceinline__ bf16  f2bf(float v) { return __float2bfloat16(v); }
__device__ __forceinline__ unsigned short f2us(float v) { bf16 h = f2bf(v); return *reinterpret_cast<unsigned short*>(&h); }
__device__ __forceinline__ float uslo(unsigned u) { union { unsigned i; float f; } x; x.i = u << 16; return x.f; }
__device__ __forceinline__ float ushi(unsigned u) { union { unsigned i; float f; } x; x.i = u & 0xffff0000u; return x.f; }
__device__ __forceinline__ float us2f(unsigned short u) { union { unsigned i; float f; } x; x.i = ((unsigned)u) << 16; return x.f; }
__device__ __forceinline__ float sigm(float x) { return 1.0f / (1.0f + expf(-x)); }

__device__ __forceinline__ f16x2 as_h2(unsigned u) { union { unsigned i; f16x2 h; } x; x.i = u; return x.h; }
__device__ __forceinline__ unsigned short f2h_bits(float v) { union { f16 f; unsigned short s; } x; x.f = (f16)v; return x.s; }
__device__ __forceinline__ unsigned pack_h2(float a, float b) {
    union { f16x2 h; unsigned u; } x; x.h[0] = (f16)a; x.h[1] = (f16)b; return x.u;
}

#if defined(__has_builtin)
#if __has_builtin(__builtin_amdgcn_fdot2)
#define HAVE_FDOT2 1
#endif
#endif

__device__ __forceinline__ float dot2f(f16x2 a, f16x2 b, float c) {
#ifdef HAVE_FDOT2
    return __builtin_amdgcn_fdot2(a, b, c, false);
#else
    return c + (float)a[0] * (float)b[0] + (float)a[1] * (float)b[1];
#endif
}

// 4-element converting loads
__device__ __forceinline__ float4 ld4(const float* p) { return *(const float4*)p; }
__device__ __forceinline__ float4 ld4(const bf16* p) {
    ushort4 v = *(const ushort4*)p;
    return make_float4(us2f(v.x), us2f(v.y), us2f(v.z), us2f(v.w));
}

// ---------------------------------------------------------------------------
// Generic GEMM: C[M,N] = act( A[M,K] * W[N,K]^T + bias1 + bias2 )
// ---------------------------------------------------------------------------
template <typename TA, typename TW>
__global__ __launch_bounds__(256) void gemm_bt(
    const TA* __restrict__ A, const TW* __restrict__ W,
    const float* __restrict__ bias1, const float* __restrict__ bias2,
    bf16* __restrict__ Ch, float* __restrict__ Cf,
    int M, int N, int K, int act, int rowdiv, int lda)
{
    __shared__ float As[16][64];
    __shared__ float Ws[16][64];
    const int tid = threadIdx.x;
    const int tx = tid & 15;
    const int ty = tid >> 4;
    const int bm = blockIdx.x * 64;
    const int bn = blockIdx.y * 64;
    const int lr = tid >> 2;
    const int lk = (tid & 3) * 4;

    const int rA = bm + lr;
    const int ra = (rowdiv > 0) ? (rA + rA / rowdiv + 1) : rA;
    const TA* aRow = A + (size_t)ra * lda;
    const int rW = bn + lr;
    const TW* wRow = W + (size_t)rW * K;
    const bool aOK = (rA < M);
    const bool wOK = (rW < N);

    float acc[4][4];
#pragma unroll
    for (int i = 0; i < 4; ++i)
#pragma unroll
        for (int j = 0; j < 4; ++j) acc[i][j] = 0.f;

    for (int k0 = 0; k0 < K; k0 += 16) {
        float4 av = make_float4(0.f, 0.f, 0.f, 0.f);
        float4 wv = make_float4(0.f, 0.f, 0.f, 0.f);
        if (aOK) av = ld4(aRow + k0 + lk);
        if (wOK) wv = ld4(wRow + k0 + lk);
        As[lk + 0][lr] = av.x; As[lk + 1][lr] = av.y; As[lk + 2][lr] = av.z; As[lk + 3][lr] = av.w;
        Ws[lk + 0][lr] = wv.x; Ws[lk + 1][lr] = wv.y; Ws[lk + 2][lr] = wv.z; Ws[lk + 3][lr] = wv.w;
        __syncthreads();
#pragma unroll
        for (int kk = 0; kk < 16; ++kk) {
            float a0 = As[kk][ty * 4 + 0];
            float a1 = As[kk][ty * 4 + 1];
            float a2 = As[kk][ty * 4 + 2];
            float a3 = As[kk][ty * 4 + 3];
            float w0 = Ws[kk][tx * 4 + 0];
            float w1 = Ws[kk][tx * 4 + 1];
            float w2 = Ws[kk][tx * 4 + 2];
            float w3 = Ws[kk][tx * 4 + 3];
            acc[0][0] += a0 * w0; acc[0][1] += a0 * w1; acc[0][2] += a0 * w2; acc[0][3] += a0 * w3;
            acc[1][0] += a1 * w0; acc[1][1] += a1 * w1; acc[1][2] += a1 * w2; acc[1][3] += a1 * w3;
            acc[2][0] += a2 * w0; acc[2][1] += a2 * w1; acc[2][2] += a2 * w2; acc[2][3] += a2 * w3;
            acc[3][0] += a3 * w0; acc[3][1] += a3 * w1; acc[3][2] += a3 * w2; acc[3][3] += a3 * w3;
        }
        __syncthreads();
    }

#pragma unroll
    for (int i = 0; i < 4; ++i) {
        const int row = bm + ty * 4 + i;
        if (row >= M) continue;
#pragma unroll
        for (int j = 0; j < 4; ++j) {
            const int col = bn + tx * 4 + j;
            if (col >= N) continue;
            float v = acc[i][j];
            if (bias1) v += bias1[col];
            if (bias2) v += bias2[col];
            if (act == 1) v = tanhf(v);
            if (Ch) Ch[(size_t)row * N + col] = f2bf(v);
            else    Cf[(size_t)row * N + col] = v;
        }
    }
}

// ---------------------------------------------------------------------------
// Whh transpose+convert: f32 [3072][768] -> uint [384][3072], each uint holds
// f16 pair (W[j][2kk], W[j][2kk+1]) at out[kk*3072 + j].
// grid (12, 96, 3), block (32, 32).
// ---------------------------------------------------------------------------
__global__ __launch_bounds__(1024) void wtrans_kernel(
    const float* __restrict__ We, const float* __restrict__ Wa, const float* __restrict__ Ww,
    unsigned* __restrict__ Oe, unsigned* __restrict__ Oa, unsigned* __restrict__ Ow)
{
    const int which = blockIdx.z;
    const float* src = (which == 0) ? We : (which == 1) ? Wa : Ww;
    unsigned* dst = (which == 0) ? Oe : (which == 1) ? Oa : Ow;
    __shared__ unsigned tile[32][33];
    const int kkt = blockIdx.x * 32;
    const int jt = blockIdx.y * 32;
    const int tx = threadIdx.x, ty = threadIdx.y;
    const float2 v = *(const float2*)(src + (size_t)(jt + ty) * H_ + 2 * (kkt + tx));
    tile[ty][tx] = pack_h2(v.x, v.y);
    __syncthreads();
    dst[(size_t)(kkt + ty) * G4_ + jt + tx] = tile[tx][ty];
}

// ---------------------------------------------------------------------------
// Streaming LSTM: 24 blocks = 3 LSTMs x 8 batch-pairs. 768 threads.
// Thread owns 4 gate columns (uint4 = 4 cols x f16 k-pair, coalesced 1KB/wave).
// h in LDS as f16 pairs (uniform broadcast); c in registers; g staged in LDS.
// ---------------------------------------------------------------------------
__global__ __launch_bounds__(768) void lstm_stream_kernel(
    const bf16* __restrict__ pxe, const bf16* __restrict__ pxa, const bf16* __restrict__ pxw,
    const unsigned* __restrict__ We2, const unsigned* __restrict__ Wa2, const unsigned* __restrict__ Ww2,
    bf16* __restrict__ oute, bf16* __restrict__ outa, bf16* __restrict__ outw)
{
    const int bid = blockIdx.x;
    const int which = bid >> 3;
    const int b0 = (bid & 7) * 2;
    const bf16* px; const unsigned* W2; bf16* out; int Tn;
    if (which == 0)      { px = pxe; W2 = We2; out = oute; Tn = T_; }
    else if (which == 1) { px = pxa; W2 = Wa2; out = outa; Tn = T_; }
    else                 { px = pxw; W2 = Ww2; out = outw; Tn = S_; }

    __shared__ float gS[2][G4_];
    __shared__ unsigned short hS[2][H_];
    const int tid = threadIdx.x;      // 0..767
    const int c0 = tid * 4;           // gate-column base

    hS[0][tid] = 0; hS[1][tid] = 0;
    float cr0 = 0.f, cr1 = 0.f;
    __syncthreads();

    const unsigned* hU0 = (const unsigned*)&hS[0][0];   // [384] k-pair view
    const unsigned* hU1 = (const unsigned*)&hS[1][0];
    const uint4* wbase = ((const uint4*)W2) + tid;      // + kk*768 per k-pair

    for (int t = 0; t < Tn; ++t) {
        float a0[4], a1[4];
        {
            const bf16* p0 = px + ((size_t)(b0 + 0) * Tn + t) * G4_ + c0;
            const bf16* p1 = px + ((size_t)(b0 + 1) * Tn + t) * G4_ + c0;
            const uint2 u0 = *(const uint2*)p0;
            const uint2 u1 = *(const uint2*)p1;
            a0[0] = uslo(u0.x); a0[1] = ushi(u0.x); a0[2] = uslo(u0.y); a0[3] = ushi(u0.y);
            a1[0] = uslo(u1.x); a1[1] = ushi(u1.x); a1[2] = uslo(u1.y); a1[3] = ushi(u1.y);
        }
#pragma unroll 4
        for (int kk = 0; kk < KK_; ++kk) {
            const uint4 w = wbase[(size_t)kk * (G4_ / 4)];
            const f16x2 h0 = as_h2(hU0[kk]);
            const f16x2 h1 = as_h2(hU1[kk]);
            a0[0] = dot2f(as_h2(w.x), h0, a0[0]);
            a0[1] = dot2f(as_h2(w.y), h0, a0[1]);
            a0[2] = dot2f(as_h2(w.z), h0, a0[2]);
            a0[3] = dot2f(as_h2(w.w), h0, a0[3]);
            a1[0] = dot2f(as_h2(w.x), h1, a1[0]);
            a1[1] = dot2f(as_h2(w.y), h1, a1[1]);
            a1[2] = dot2f(as_h2(w.z), h1, a1[2]);
            a1[3] = dot2f(as_h2(w.w), h1, a1[3]);
        }
        ((float4*)&gS[0][0])[tid] = make_float4(a0[0], a0[1], a0[2], a0[3]);
        ((float4*)&gS[1][0])[tid] = make_float4(a1[0], a1[1], a1[2], a1[3]);
        __syncthreads();
        {
            // b0
            float ig = gS[0][tid], fg = gS[0][tid + H_], gg = gS[0][tid + 2 * H_], og = gS[0][tid + 3 * H_];
            float cn = sigm(fg) * cr0 + sigm(ig) * tanhf(gg);
            float hn = sigm(og) * tanhf(cn);
            cr0 = cn;
            hS[0][tid] = f2h_bits(hn);
            out[((size_t)(b0 + 0) * Tn + t) * H_ + tid] = f2bf(hn);
            // b0+1
            ig = gS[1][tid]; fg = gS[1][tid + H_]; gg = gS[1][tid + 2 * H_]; og = gS[1][tid + 3 * H_];
            cn = sigm(fg) * cr1 + sigm(ig) * tanhf(gg);
            hn = sigm(og) * tanhf(cn);
            cr1 = cn;
            hS[1][tid] = f2h_bits(hn);
            out[((size_t)(b0 + 1) * Tn + t) * H_ + tid] = f2bf(hn);
        }
        __syncthreads();
    }
}

// ---------------------------------------------------------------------------
// Row gather + convert: out[r][:] = bf16(emb[ids[r]][:])
// ---------------------------------------------------------------------------
__global__ void gather_rows_kernel(const int* __restrict__ ids,
                                   const float* __restrict__ emb,
                                   bf16* __restrict__ out)
{
    const int r = blockIdx.x;
    const float4* src = (const float4*)(emb + (size_t)ids[r] * H_);
    ushort4* dst = (ushort4*)(out + (size_t)r * H_);
    for (int h = threadIdx.x; h < H_ / 4; h += 256) {
        float4 v = src[h];
        ushort4 o;
        o.x = f2us(v.x); o.y = f2us(v.y); o.z = f2us(v.z); o.w = f2us(v.w);
        dst[h] = o;
    }
}

// ---------------------------------------------------------------------------
// Counters scan
// ---------------------------------------------------------------------------
__global__ void counters_kernel(const int* __restrict__ edits, const int* __restrict__ org,
                                int* __restrict__ cd, int* __restrict__ ci, int* __restrict__ ca)
{
    const int b = threadIdx.x;
    if (b >= B_) return;
    int vd = 0, vi = 0, va = 0;
    for (int t = 0; t < TM1_; ++t) {
        cd[b * TM1_ + t] = vd; ci[b * TM1_ + t] = vi; ca[b * TM1_ + t] = va;
        const int g = edits[b * T_ + t + 1];
        const int vd2 = vd + ((g == 3 || g == 4) ? 1 : 0);
        const int alive = (g != 4 && g != 2 && g != 0) ? 1 : 0;
        const int vi2 = vi + alive;
        int nxt = va + 1; if (nxt > L_ - 1) nxt = L_ - 1;
        const int tok = org[b * L_ + nxt];
        const bool cond = alive && (g != 3) && (va + 1 < L_) && (tok == 103 || tok == 3 || tok == 4);
        const int va2 = cond ? (va + 1) : max(vd2, va);
        vd = vd2; vi = vi2; va = va2;
    }
}

// c_word[r][:] = out_w[b][ci[r]][:]
__global__ void gather_cword_kernel(const bf16* __restrict__ outw, const int* __restrict__ ci,
                                    bf16* __restrict__ cw)
{
    const int r = blockIdx.x;
    const int b = r / TM1_;
    const unsigned* src = (const unsigned*)(outw + ((size_t)b * S_ + ci[r]) * H_);
    unsigned* dst = (unsigned*)(cw + (size_t)r * H_);
    for (int h = threadIdx.x; h < H_ / 2; h += 256) dst[h] = src[h];
}

// ---------------------------------------------------------------------------
// wref softmax (2-way) + mix c_input/c_anno
// ---------------------------------------------------------------------------
__global__ __launch_bounds__(256) void ref_combine_kernel(
    const bf16* __restrict__ oute, const bf16* __restrict__ outa, const bf16* __restrict__ enc,
    const float* __restrict__ Wref, const float* __restrict__ bref,
    const int* __restrict__ cd, const int* __restrict__ ca,
    bf16* __restrict__ ced, bf16* __restrict__ cac)
{
    const int r = blockIdx.x;
    const int b = r / TM1_;
    const int t = r % TM1_;
    const bf16* de = oute + ((size_t)b * T_ + t) * H_;
    const bf16* da = outa + ((size_t)b * T_ + t) * H_;
    const int tid = threadIdx.x;
    __shared__ float red[256][4];
    float s0 = 0.f, s1 = 0.f, s2 = 0.f, s3 = 0.f;
    for (int k = tid; k < H_; k += 256) {
        const float w0 = Wref[k];
        const float w1 = Wref[H_ + k];
        const float e = bf2f(de[k]);
        const float a = bf2f(da[k]);
        s0 += e * w0; s1 += e * w1; s2 += a * w0; s3 += a * w1;
    }
    red[tid][0] = s0; red[tid][1] = s1; red[tid][2] = s2; red[tid][3] = s3;
    __syncthreads();
    for (int off = 128; off > 0; off >>= 1) {
        if (tid < off) {
            red[tid][0] += red[tid + off][0];
            red[tid][1] += red[tid + off][1];
            red[tid][2] += red[tid + off][2];
            red[tid][3] += red[tid + off][3];
        }
        __syncthreads();
    }
    const float br0 = bref[0], br1 = bref[1];
    const float xe0 = red[0][0] + br0, xe1 = red[0][1] + br1;
    const float xa0 = red[0][2] + br0, xa1 = red[0][3] + br1;
    const float me = fmaxf(xe0, xe1);
    const float ee0 = expf(xe0 - me), ee1 = expf(xe1 - me);
    const float pe0 = ee0 / (ee0 + ee1), pe1 = ee1 / (ee0 + ee1);
    const float ma = fmaxf(xa0, xa1);
    const float ea0 = expf(xa0 - ma), ea1 = expf(xa1 - ma);
    const float pa0 = ea0 / (ea0 + ea1), pa1 = ea1 / (ea0 + ea1);

    const bf16* ei = enc + ((size_t)b * L_ + cd[r]) * H_;
    const bf16* ea = enc + ((size_t)b * L_ + ca[r]) * H_;
    for (int h = tid; h < H_; h += 256) {
        const float vi = bf2f(ei[h]);
        const float va = bf2f(ea[h]);
        ced[(size_t)r * H_ + h] = f2bf(pe0 * vi + pe1 * va);
        cac[(size_t)r * H_ + h] = f2bf(pa0 * vi + pa1 * va);
    }
}

// ---------------------------------------------------------------------------
// Attention over L=191
// ---------------------------------------------------------------------------
__global__ __launch_bounds__(256) void attn_kernel(const bf16* __restrict__ q,
                                                   const bf16* __restrict__ enc,
                                                   bf16* __restrict__ app)
{
    const int r = blockIdx.x;
    const int b = r / TM1_;
    const int tid = threadIdx.x;
    __shared__ float qs[H_];
    __shared__ float p[L_ + 1];
    __shared__ float red[256];
    const bf16* qrow = q + (size_t)r * H_;
    for (int h = tid; h < H_; h += 256) qs[h] = bf2f(qrow[h]);
    __syncthreads();
    const bf16* eb = enc + (size_t)b * L_ * H_;
    float myv = -1e30f;
    if (tid < L_) {
        const unsigned* er = (const unsigned*)(eb + (size_t)tid * H_);
        float s = 0.f;
        for (int k2 = 0; k2 < H_ / 2; ++k2) {
            const unsigned u = er[k2];
            s += qs[2 * k2] * uslo(u) + qs[2 * k2 + 1] * ushi(u);
        }
        p[tid] = s;
        myv = s;
    }
    red[tid] = myv;
    __syncthreads();
    for (int off = 128; off > 0; off >>= 1) {
        if (tid < off) red[tid] = fmaxf(red[tid], red[tid + off]);
        __syncthreads();
    }
    const float m = red[0];
    __syncthreads();
    float e = 0.f;
    if (tid < L_) e = expf(p[tid] - m);
    red[tid] = e;
    __syncthreads();
    for (int off = 128; off > 0; off >>= 1) {
        if (tid < off) red[tid] += red[tid + off];
        __syncthreads();
    }
    const float invZ = 1.f / red[0];
    __syncthreads();
    if (tid < L_) p[tid] = e * invZ;
    __syncthreads();
    for (int h = tid; h < H_; h += 256) {
        float s = 0.f;
        for (int l = 0; l < L_; ++l) s += p[l] * bf2f(eb[(size_t)l * H_ + h]);
        app[(size_t)r * H_ + h] = f2bf(s);
    }
}

// feat_e = [dec_e, dec_a, app, ced, cw]; feat_a = [dec_a, dec_e, app, cac, cw]
__global__ void feat_kernel(const bf16* __restrict__ oute, const bf16* __restrict__ outa,
                            const bf16* __restrict__ app, const bf16* __restrict__ ced,
                            const bf16* __restrict__ cac, const bf16* __restrict__ cw,
                            bf16* __restrict__ fe, bf16* __restrict__ fa)
{
    const int r = blockIdx.x;
    const int b = r / TM1_;
    const int t = r % TM1_;
    const unsigned* de  = (const unsigned*)(oute + ((size_t)b * T_ + t) * H_);
    const unsigned* da  = (const unsigned*)(outa + ((size_t)b * T_ + t) * H_);
    const unsigned* ap  = (const unsigned*)(app + (size_t)r * H_);
    const unsigned* ce  = (const unsigned*)(ced + (size_t)r * H_);
    const unsigned* cA  = (const unsigned*)(cac + (size_t)r * H_);
    const unsigned* cwp = (const unsigned*)(cw + (size_t)r * H_);
    unsigned* pfe = (unsigned*)(fe + (size_t)r * K5_);
    unsigned* pfa = (unsigned*)(fa + (size_t)r * K5_);
    const int HW = H_ / 2;
    for (int h = threadIdx.x; h < HW; h += 256) {
        const unsigned ve = de[h], va = da[h], vap = ap[h], vce = ce[h], vca = cA[h], vcw = cwp[h];
        pfe[h] = ve;  pfe[HW + h] = va;  pfe[2 * HW + h] = vap; pfe[3 * HW + h] = vce; pfe[4 * HW + h] = vcw;
        pfa[h] = va;  pfa[HW + h] = ve;  pfa[2 * HW + h] = vap; pfa[3 * HW + h] = vca; pfa[4 * HW + h] = vcw;
    }
}

// In-place log-softmax over f32 rows (edit head, N=30522)
__global__ __launch_bounds__(1024) void logsoftmax_edit_kernel(float* __restrict__ out)
{
    float* row = out + (size_t)blockIdx.x * V_;
    const int tid = threadIdx.x;
    __shared__ float red[1024];
    float m = -1e30f;
    for (int i = tid; i < V_; i += 1024) m = fmaxf(m, row[i]);
    red[tid] = m;
    __syncthreads();
    for (int off = 512; off > 0; off >>= 1) {
        if (tid < off) red[tid] = fmaxf(red[tid], red[tid + off]);
        __syncthreads();
    }
    m = red[0];
    __syncthreads();
    float s = 0.f;
    for (int i = tid; i < V_; i += 1024) s += expf(row[i] - m);
    red[tid] = s;
    __syncthreads();
    for (int off = 512; off > 0; off >>= 1) {
        if (tid < off) red[tid] += red[tid + off];
        __syncthreads();
    }
    const float lz = m + logf(red[0]);
    __syncthreads();
    for (int i = tid; i < V_; i += 1024) row[i] = row[i] - lz;
}

// Act head log-softmax: f32 in -> f32 out
__global__ __launch_bounds__(256) void logsoftmax_act_kernel(const float* __restrict__ in,
                                                             float* __restrict__ out)
{
    const float* row = in + (size_t)blockIdx.x * AV_;
    float* orow = out + (size_t)blockIdx.x * AV_;
    const int tid = threadIdx.x;
    __shared__ float red[256];
    float m = -1e30f;
    if (tid < AV_) m = row[tid];
    red[tid] = m;
    __syncthreads();
    for (int off = 128; off > 0; off >>= 1) {
        if (tid < off) red[tid] = fmaxf(red[tid], red[tid + off]);
        __syncthreads();
    }
    m = red[0];
    __syncthreads();
    float s = 0.f;
    if (tid < AV_) s = expf(row[tid] - m);
    red[tid] = s;
    __syncthreads();
    for (int off = 128; off > 0; off >>= 1) {
        if (tid < off) red[tid] += red[tid + off];
        __syncthreads();
    }
    const float lz = m + logf(red[0]);
    if (tid < AV_) orow[tid] = row[tid] - lz;
}

// ---------------------------------------------------------------------------
extern "C" void kernel_launch(void* const* d_in, const int* in_sizes, int n_in,
                              void* d_out, int out_size, void* d_ws, size_t ws_size,
                              hipStream_t stream)
{
    const int* input_edits   = (const int*)d_in[0];
    const int* input_actions = (const int*)d_in[1];
    const int* simp_sent     = (const int*)d_in[2];
    const int* org_ids       = (const int*)d_in[3];
    const float* enc_org     = (const float*)d_in[4];
    const float* emb         = (const float*)d_in[5];
    const float* Wih_e = (const float*)d_in[6];
    const float* Whh_e = (const float*)d_in[7];
    const float* bih_e = (const float*)d_in[8];
    const float* bhh_e = (const float*)d_in[9];
    const float* Wih_a = (const float*)d_in[10];
    const float* Whh_a = (const float*)d_in[11];
    const float* bih_a = (const float*)d_in[12];
    const float* bhh_a = (const float*)d_in[13];
    const float* Wih_w = (const float*)d_in[14];
    const float* Whh_w = (const float*)d_in[15];
    const float* bih_w = (const float*)d_in[16];
    const float* bhh_w = (const float*)d_in[17];
    const float* W_align = (const float*)d_in[18];
    const float* W_proj  = (const float*)d_in[19];
    const float* W_ref   = (const float*)d_in[20];
    const float* b_ref   = (const float*)d_in[21];
    const float* W_mlp   = (const float*)d_in[22];
    const float* b_mlp   = (const float*)d_in[23];
    const float* W_act   = (const float*)d_in[24];
    const float* b_act   = (const float*)d_in[25];
    const float* W_out   = (const float*)d_in[26];
    const float* b_out   = (const float*)d_in[27];
    const float* W_outact = (const float*)d_in[28];
    const float* b_outact = (const float*)d_in[29];
    const float* action_mask = (const float*)d_in[30];

    float* out = (float*)d_out;
    float* edit_out = out;                               // (2032, 30522) f32
    float* act_out  = out + (size_t)R_ * V_;             // (2032, 200)   f32

    // Workspace layout (~140 MB)
    char* p = (char*)d_ws;
    auto take = [&](size_t bytes) { void* q = (void*)p; p += ((bytes + 255) / 256) * 256; return q; };
    unsigned* WT2e = (unsigned*)take((size_t)KK_ * G4_ * 4);   // f16-pair transposed Whh
    unsigned* WT2a = (unsigned*)take((size_t)KK_ * G4_ * 4);
    unsigned* WT2w = (unsigned*)take((size_t)KK_ * G4_ * 4);
    bf16* xe   = (bf16*)take((size_t)B_ * T_ * H_ * 2);
    bf16* xa   = (bf16*)take((size_t)B_ * T_ * H_ * 2);
    bf16* xw   = (bf16*)take((size_t)B_ * S_ * H_ * 2);
    bf16* pxe  = (bf16*)take((size_t)B_ * T_ * G4_ * 2);
    bf16* pxa  = (bf16*)take((size_t)B_ * T_ * G4_ * 2);
    bf16* pxw  = (bf16*)take((size_t)B_ * S_ * G4_ * 2);
    bf16* oute = (bf16*)take((size_t)B_ * T_ * H_ * 2);
    bf16* outa = (bf16*)take((size_t)B_ * T_ * H_ * 2);
    bf16* outw = (bf16*)take((size_t)B_ * S_ * H_ * 2);
    bf16* enc  = (bf16*)take((size_t)B_ * L_ * H_ * 2);
    bf16* cw   = (bf16*)take((size_t)R_ * H_ * 2);
    bf16* ced  = (bf16*)take((size_t)R_ * H_ * 2);
    bf16* cac  = (bf16*)take((size_t)R_ * H_ * 2);
    bf16* qb   = (bf16*)take((size_t)R_ * H_ * 2);
    bf16* app  = (bf16*)take((size_t)R_ * H_ * 2);
    bf16* fe   = (bf16*)take((size_t)R_ * K5_ * 2);
    bf16* fa   = (bf16*)take((size_t)R_ * K5_ * 2);
    bf16* he   = (bf16*)take((size_t)R_ * H_ * 2);
    bf16* ha   = (bf16*)take((size_t)R_ * H_ * 2);
    int*  cd   = (int*)take((size_t)R_ * 4);
    int*  ci   = (int*)take((size_t)R_ * 4);
    int*  ca   = (int*)take((size_t)R_ * 4);
    float* actbuf = (float*)take((size_t)R_ * AV_ * 4);

    // 0. Transpose+convert Whh -> f16-pair k-major layout
    wtrans_kernel<<<dim3(KK_ / 32, G4_ / 32, 3), dim3(32, 32), 0, stream>>>(
        Whh_e, Whh_a, Whh_w, WT2e, WT2a, WT2w);

    // 1. Embedding gathers (f32 emb -> bf16 rows)
    gather_rows_kernel<<<B_ * T_, 256, 0, stream>>>(input_edits, emb, xe);
    gather_rows_kernel<<<B_ * T_, 256, 0, stream>>>(input_actions, emb, xa);
    gather_rows_kernel<<<B_ * S_, 256, 0, stream>>>(simp_sent, emb, xw);

    // 2. Precompute x@Wih^T + bih + bhh for all timesteps
    dim3 g1((B_ * T_ + 63) / 64, (G4_ + 63) / 64);
    gemm_bt<bf16, float><<<g1, 256, 0, stream>>>(xe, Wih_e, bih_e, bhh_e, pxe, nullptr, B_ * T_, G4_, H_, 0, 0, H_);
    gemm_bt<bf16, float><<<g1, 256, 0, stream>>>(xa, Wih_a, bih_a, bhh_a, pxa, nullptr, B_ * T_, G4_, H_, 0, 0, H_);
    dim3 g1w((B_ * S_ + 63) / 64, (G4_ + 63) / 64);
    gemm_bt<bf16, float><<<g1w, 256, 0, stream>>>(xw, Wih_w, bih_w, bhh_w, pxw, nullptr, B_ * S_, G4_, H_, 0, 0, H_);

    // 3. enc = tanh(enc_org @ W_align^T)[:, 1:]
    dim3 g2((B_ * L_ + 63) / 64, (H_ + 63) / 64);
    gemm_bt<float, float><<<g2, 256, 0, stream>>>(enc_org, W_align, nullptr, nullptr, enc, nullptr, B_ * L_, H_, H_, 1, L_, H_);

    // 4. Counters scan
    counters_kernel<<<1, 64, 0, stream>>>(input_edits, org_ids, cd, ci, ca);

    // 5. The three LSTMs, coalesced streaming (24 blocks)
    lstm_stream_kernel<<<24, 768, 0, stream>>>(pxe, pxa, pxw, WT2e, WT2a, WT2w, oute, outa, outw);

    // 6. c_word gather
    gather_cword_kernel<<<R_, 256, 0, stream>>>(outw, ci, cw);

    // 7. wref mixing -> c_edit, c_action
    ref_combine_kernel<<<R_, 256, 0, stream>>>(oute, outa, enc, W_ref, b_ref, cd, ca, ced, cac);

    // 8. q = c_word @ W_proj^T
    dim3 g3((R_ + 63) / 64, (H_ + 63) / 64);
    gemm_bt<bf16, float><<<g3, 256, 0, stream>>>(cw, W_proj, nullptr, nullptr, qb, nullptr, R_, H_, H_, 0, 0, H_);

    // 9. attention -> applied
    attn_kernel<<<R_, 256, 0, stream>>>(qb, enc, app);

    // 10. feature concat
    feat_kernel<<<R_, 256, 0, stream>>>(oute, outa, app, ced, cac, cw, fe, fa);

    // 11. hidden layers (tanh)
    gemm_bt<bf16, float><<<g3, 256, 0, stream>>>(fe, W_mlp, b_mlp, nullptr, he, nullptr, R_, H_, K5_, 1, 0, K5_);
    gemm_bt<bf16, float><<<g3, 256, 0, stream>>>(fa, W_act, b_act, nullptr, ha, nullptr, R_, H_, K5_, 1, 0, K5_);

    // 12. act head
    dim3 g4((R_ + 63) / 64, (AV_ + 63) / 64);
    gemm_bt<bf16, float><<<g4, 256, 0, stream>>>(ha, W_outact, b_outact, action_mask, nullptr, actbuf, R_, AV_, H_, 0, 0, H_);
    logsoftmax_act_kernel<<<R_, 256, 0, stream>>>(actbuf, act_out);

    // 13. edit head: logits f32 straight into d_out, in-place log-softmax
    dim3 g5((R_ + 63) / 64, (V_ + 63) / 64);
    gemm_bt<bf16, float><<<g5, 256, 0, stream>>>(he, W_out, b_out, nullptr, nullptr, edit_out, R_, V_, H_, 0, 0, H_);
    logsoftmax_edit_kernel<<<R_, 1024, 0, stream>>>(edit_out);
}

// Round 6
// 6116.479 us; speedup vs baseline: 5.2799x; 1.9546x over previous
//
#include <hip/hip_runtime.h>
#include <hip/hip_bf16.h>

typedef __hip_bfloat16 bf16;

// Problem dims
#define B_    16
#define T_    128
#define S_    192
#define H_    768
#define G4_   3072      // 4*H
#define V_    30522
#define AV_   200
#define L_    191       // L_SRC-1
#define TM1_  127       // T-1
#define R_    2032      // B*(T-1)
#define K5_   3840      // 5*H
#define NB_   48        // blocks per LSTM (persistent)
#define HSL_  16        // h-slice per block (768/48)

typedef short bf16x8_t __attribute__((ext_vector_type(8)));
typedef float f32x4_t  __attribute__((ext_vector_type(4)));

__device__ __forceinline__ float bf2f(bf16 v) { return __bfloat162float(v); }
__device__ __forceinline__ bf16  f2bf(float v) { return __float2bfloat16(v); }
__device__ __forceinline__ unsigned short f2us(float v) { bf16 h = f2bf(v); return *reinterpret_cast<unsigned short*>(&h); }
__device__ __forceinline__ float uslo(unsigned u) { union { unsigned i; float f; } x; x.i = u << 16; return x.f; }
__device__ __forceinline__ float ushi(unsigned u) { union { unsigned i; float f; } x; x.i = u & 0xffff0000u; return x.f; }
__device__ __forceinline__ float us2f(unsigned short u) { union { unsigned i; float f; } x; x.i = ((unsigned)u) << 16; return x.f; }
__device__ __forceinline__ float sigm(float x) { return 1.0f / (1.0f + expf(-x)); }

// 4-element converting loads
__device__ __forceinline__ float4 ld4(const float* p) { return *(const float4*)p; }
__device__ __forceinline__ float4 ld4(const bf16* p) {
    ushort4 v = *(const ushort4*)p;
    return make_float4(us2f(v.x), us2f(v.y), us2f(v.z), us2f(v.w));
}

// ---------------------------------------------------------------------------
// Generic GEMM: C[M,N] = act( A[M,K] * W[N,K]^T + bias1 + bias2 )
// ---------------------------------------------------------------------------
template <typename TA, typename TW>
__global__ __launch_bounds__(256) void gemm_bt(
    const TA* __restrict__ A, const TW* __restrict__ W,
    const float* __restrict__ bias1, const float* __restrict__ bias2,
    bf16* __restrict__ Ch, float* __restrict__ Cf,
    int M, int N, int K, int act, int rowdiv, int lda)
{
    __shared__ float As[16][64];
    __shared__ float Ws[16][64];
    const int tid = threadIdx.x;
    const int tx = tid & 15;
    const int ty = tid >> 4;
    const int bm = blockIdx.x * 64;
    const int bn = blockIdx.y * 64;
    const int lr = tid >> 2;
    const int lk = (tid & 3) * 4;

    const int rA = bm + lr;
    const int ra = (rowdiv > 0) ? (rA + rA / rowdiv + 1) : rA;
    const TA* aRow = A + (size_t)ra * lda;
    const int rW = bn + lr;
    const TW* wRow = W + (size_t)rW * K;
    const bool aOK = (rA < M);
    const bool wOK = (rW < N);

    float acc[4][4];
#pragma unroll
    for (int i = 0; i < 4; ++i)
#pragma unroll
        for (int j = 0; j < 4; ++j) acc[i][j] = 0.f;

    for (int k0 = 0; k0 < K; k0 += 16) {
        float4 av = make_float4(0.f, 0.f, 0.f, 0.f);
        float4 wv = make_float4(0.f, 0.f, 0.f, 0.f);
        if (aOK) av = ld4(aRow + k0 + lk);
        if (wOK) wv = ld4(wRow + k0 + lk);
        As[lk + 0][lr] = av.x; As[lk + 1][lr] = av.y; As[lk + 2][lr] = av.z; As[lk + 3][lr] = av.w;
        Ws[lk + 0][lr] = wv.x; Ws[lk + 1][lr] = wv.y; Ws[lk + 2][lr] = wv.z; Ws[lk + 3][lr] = wv.w;
        __syncthreads();
#pragma unroll
        for (int kk = 0; kk < 16; ++kk) {
            float a0 = As[kk][ty * 4 + 0];
            float a1 = As[kk][ty * 4 + 1];
            float a2 = As[kk][ty * 4 + 2];
            float a3 = As[kk][ty * 4 + 3];
            float w0 = Ws[kk][tx * 4 + 0];
            float w1 = Ws[kk][tx * 4 + 1];
            float w2 = Ws[kk][tx * 4 + 2];
            float w3 = Ws[kk][tx * 4 + 3];
            acc[0][0] += a0 * w0; acc[0][1] += a0 * w1; acc[0][2] += a0 * w2; acc[0][3] += a0 * w3;
            acc[1][0] += a1 * w0; acc[1][1] += a1 * w1; acc[1][2] += a1 * w2; acc[1][3] += a1 * w3;
            acc[2][0] += a2 * w0; acc[2][1] += a2 * w1; acc[2][2] += a2 * w2; acc[2][3] += a2 * w3;
            acc[3][0] += a3 * w0; acc[3][1] += a3 * w1; acc[3][2] += a3 * w2; acc[3][3] += a3 * w3;
        }
        __syncthreads();
    }

#pragma unroll
    for (int i = 0; i < 4; ++i) {
        const int row = bm + ty * 4 + i;
        if (row >= M) continue;
#pragma unroll
        for (int j = 0; j < 4; ++j) {
            const int col = bn + tx * 4 + j;
            if (col >= N) continue;
            float v = acc[i][j];
            if (bias1) v += bias1[col];
            if (bias2) v += bias2[col];
            if (act == 1) v = tanhf(v);
            if (Ch) Ch[(size_t)row * N + col] = f2bf(v);
            else    Cf[(size_t)row * N + col] = v;
        }
    }
}

// ---------------------------------------------------------------------------
// Persistent cooperative LSTM. Grid = 3 LSTMs x 48 blocks, 256 threads.
// Block owns h-slice [s, s+16); wave g holds gate g's 16x768 W rows as 24
// persistent bf16 MFMA A-fragments (96 VGPRs). h exchanged via global
// double-buffer; per-LSTM monotone counter barrier per step.
// ---------------------------------------------------------------------------
__global__ __launch_bounds__(256) void lstm_mfma_kernel(
    const bf16* __restrict__ pxe, const bf16* __restrict__ pxa, const bf16* __restrict__ pxw,
    const float* __restrict__ We, const float* __restrict__ Wa, const float* __restrict__ Ww,
    bf16* __restrict__ oute, bf16* __restrict__ outa, bf16* __restrict__ outw,
    unsigned short* __restrict__ hbuf, int* __restrict__ cnts)
{
    const int which = blockIdx.x / NB_;
    const int nb = blockIdx.x % NB_;
    const bf16* px; const float* W; bf16* out; int Tn;
    if (which == 0)      { px = pxe; W = We; out = oute; Tn = T_; }
    else if (which == 1) { px = pxa; W = Wa; out = outa; Tn = T_; }
    else                 { px = pxw; W = Ww; out = outw; Tn = S_; }
    unsigned short* hG = hbuf + (size_t)which * (2 * B_ * H_);
    int* cnt = cnts + which * 16;   // 64B apart

    const int tid = threadIdx.x;
    const int wv = tid >> 6;        // wave index = gate (i,f,g,o)
    const int lane = tid & 63;
    const int s = nb * HSL_;

    __shared__ unsigned short hL[16][776];   // h (bf16 bits), row-padded +8
    __shared__ float gS[4][16][17];          // gate exchange [gate][hl][batch]

    // --- persistent A-fragments: lane l -> row (l&15), k = kb*32 + (l>>4)*8 + i
    bf16x8_t Afrag[24];
    {
        const int m = lane & 15;
        const int kb8 = (lane >> 4) * 8;
        const float* wrow = W + (size_t)(wv * H_ + s + m) * H_ + kb8;
#pragma unroll
        for (int kb = 0; kb < 24; ++kb) {
            float4 f0 = *(const float4*)(wrow + kb * 32);
            float4 f1 = *(const float4*)(wrow + kb * 32 + 4);
            bf16x8_t a;
            a[0] = (short)f2us(f0.x); a[1] = (short)f2us(f0.y);
            a[2] = (short)f2us(f0.z); a[3] = (short)f2us(f0.w);
            a[4] = (short)f2us(f1.x); a[5] = (short)f2us(f1.y);
            a[6] = (short)f2us(f1.z); a[7] = (short)f2us(f1.w);
            Afrag[kb] = a;
        }
    }

    // h_0 = 0
    for (int i = tid; i < 16 * 776; i += 256) ((unsigned short*)hL)[i] = 0;

    // cell-thread mapping: b = tid>>4, hl = tid&15 ; c persists in register
    const int cb = tid >> 4;
    const int chl = tid & 15;
    float c = 0.f;

    const int bn = lane & 15;        // B-frag col = batch
    const int bk = (lane >> 4) * 8;  // B-frag k sub-offset

    int cur = 0;
    for (int step = 0; step < Tn; ++step) {
        if (step > 0) {
            const unsigned short* hsrc = hG + cur * (B_ * H_);
            for (int i = tid; i < B_ * H_ / 8; i += 256) {
                const int bb = i / 96;
                const int c8 = i - bb * 96;
                *(uint4*)&hL[bb][c8 * 8] = *(const uint4*)&hsrc[bb * H_ + c8 * 8];
            }
        }
        __syncthreads();

        f32x4_t acc = {0.f, 0.f, 0.f, 0.f};
#pragma unroll
        for (int kb = 0; kb < 24; ++kb) {
            bf16x8_t bfr = *(const bf16x8_t*)&hL[bn][kb * 32 + bk];
            acc = __builtin_amdgcn_mfma_f32_16x16x32_bf16(Afrag[kb], bfr, acc, 0, 0, 0);
        }
        {
            const int m0 = (lane >> 4) * 4;
#pragma unroll
            for (int j = 0; j < 4; ++j) gS[wv][m0 + j][bn] = acc[j];
        }
        __syncthreads();

        // cell update
        {
            const bf16* pxt = px + ((size_t)cb * Tn + step) * G4_ + s + chl;
            const float gi = gS[0][chl][cb] + bf2f(pxt[0]);
            const float gf = gS[1][chl][cb] + bf2f(pxt[H_]);
            const float gg = gS[2][chl][cb] + bf2f(pxt[2 * H_]);
            const float go = gS[3][chl][cb] + bf2f(pxt[3 * H_]);
            const float cn = sigm(gf) * c + sigm(gi) * tanhf(gg);
            const float hn = sigm(go) * tanhf(cn);
            c = cn;
            out[((size_t)cb * Tn + step) * H_ + s + chl] = f2bf(hn);
            hG[(size_t)(cur ^ 1) * (B_ * H_) + cb * H_ + s + chl] = f2us(hn);
        }
        __threadfence();              // release our h-slice (agent scope)
        __syncthreads();
        if (tid == 0) {
            atomicAdd(cnt, 1);
            const int target = NB_ * (step + 1);
            long guard = 0;
            while (__hip_atomic_load(cnt, __ATOMIC_ACQUIRE, __HIP_MEMORY_SCOPE_AGENT) < target) {
                if (++guard > 100000000L) break;   // liveness guard (never hit in practice)
            }
        }
        __syncthreads();
        cur ^= 1;
    }
}

// ---------------------------------------------------------------------------
// Row gather + convert: out[r][:] = bf16(emb[ids[r]][:])
// ---------------------------------------------------------------------------
__global__ void gather_rows_kernel(const int* __restrict__ ids,
                                   const float* __restrict__ emb,
                                   bf16* __restrict__ out)
{
    const int r = blockIdx.x;
    const float4* src = (const float4*)(emb + (size_t)ids[r] * H_);
    ushort4* dst = (ushort4*)(out + (size_t)r * H_);
    for (int h = threadIdx.x; h < H_ / 4; h += 256) {
        float4 v = src[h];
        ushort4 o;
        o.x = f2us(v.x); o.y = f2us(v.y); o.z = f2us(v.z); o.w = f2us(v.w);
        dst[h] = o;
    }
}

// ---------------------------------------------------------------------------
// Counters scan
// ---------------------------------------------------------------------------
__global__ void counters_kernel(const int* __restrict__ edits, const int* __restrict__ org,
                                int* __restrict__ cd, int* __restrict__ ci, int* __restrict__ ca)
{
    const int b = threadIdx.x;
    if (b >= B_) return;
    int vd = 0, vi = 0, va = 0;
    for (int t = 0; t < TM1_; ++t) {
        cd[b * TM1_ + t] = vd; ci[b * TM1_ + t] = vi; ca[b * TM1_ + t] = va;
        const int g = edits[b * T_ + t + 1];
        const int vd2 = vd + ((g == 3 || g == 4) ? 1 : 0);
        const int alive = (g != 4 && g != 2 && g != 0) ? 1 : 0;
        const int vi2 = vi + alive;
        int nxt = va + 1; if (nxt > L_ - 1) nxt = L_ - 1;
        const int tok = org[b * L_ + nxt];
        const bool cond = alive && (g != 3) && (va + 1 < L_) && (tok == 103 || tok == 3 || tok == 4);
        const int va2 = cond ? (va + 1) : max(vd2, va);
        vd = vd2; vi = vi2; va = va2;
    }
}

// c_word[r][:] = out_w[b][ci[r]][:]
__global__ void gather_cword_kernel(const bf16* __restrict__ outw, const int* __restrict__ ci,
                                    bf16* __restrict__ cw)
{
    const int r = blockIdx.x;
    const int b = r / TM1_;
    const unsigned* src = (const unsigned*)(outw + ((size_t)b * S_ + ci[r]) * H_);
    unsigned* dst = (unsigned*)(cw + (size_t)r * H_);
    for (int h = threadIdx.x; h < H_ / 2; h += 256) dst[h] = src[h];
}

// ---------------------------------------------------------------------------
// wref softmax (2-way) + mix c_input/c_anno
// ---------------------------------------------------------------------------
__global__ __launch_bounds__(256) void ref_combine_kernel(
    const bf16* __restrict__ oute, const bf16* __restrict__ outa, const bf16* __restrict__ enc,
    const float* __restrict__ Wref, const float* __restrict__ bref,
    const int* __restrict__ cd, const int* __restrict__ ca,
    bf16* __restrict__ ced, bf16* __restrict__ cac)
{
    const int r = blockIdx.x;
    const int b = r / TM1_;
    const int t = r % TM1_;
    const bf16* de = oute + ((size_t)b * T_ + t) * H_;
    const bf16* da = outa + ((size_t)b * T_ + t) * H_;
    const int tid = threadIdx.x;
    __shared__ float red[256][4];
    float s0 = 0.f, s1 = 0.f, s2 = 0.f, s3 = 0.f;
    for (int k = tid; k < H_; k += 256) {
        const float w0 = Wref[k];
        const float w1 = Wref[H_ + k];
        const float e = bf2f(de[k]);
        const float a = bf2f(da[k]);
        s0 += e * w0; s1 += e * w1; s2 += a * w0; s3 += a * w1;
    }
    red[tid][0] = s0; red[tid][1] = s1; red[tid][2] = s2; red[tid][3] = s3;
    __syncthreads();
    for (int off = 128; off > 0; off >>= 1) {
        if (tid < off) {
            red[tid][0] += red[tid + off][0];
            red[tid][1] += red[tid + off][1];
            red[tid][2] += red[tid + off][2];
            red[tid][3] += red[tid + off][3];
        }
        __syncthreads();
    }
    const float br0 = bref[0], br1 = bref[1];
    const float xe0 = red[0][0] + br0, xe1 = red[0][1] + br1;
    const float xa0 = red[0][2] + br0, xa1 = red[0][3] + br1;
    const float me = fmaxf(xe0, xe1);
    const float ee0 = expf(xe0 - me), ee1 = expf(xe1 - me);
    const float pe0 = ee0 / (ee0 + ee1), pe1 = ee1 / (ee0 + ee1);
    const float ma = fmaxf(xa0, xa1);
    const float ea0 = expf(xa0 - ma), ea1 = expf(xa1 - ma);
    const float pa0 = ea0 / (ea0 + ea1), pa1 = ea1 / (ea0 + ea1);

    const bf16* ei = enc + ((size_t)b * L_ + cd[r]) * H_;
    const bf16* ea = enc + ((size_t)b * L_ + ca[r]) * H_;
    for (int h = tid; h < H_; h += 256) {
        const float vi = bf2f(ei[h]);
        const float va = bf2f(ea[h]);
        ced[(size_t)r * H_ + h] = f2bf(pe0 * vi + pe1 * va);
        cac[(size_t)r * H_ + h] = f2bf(pa0 * vi + pa1 * va);
    }
}

// ---------------------------------------------------------------------------
// Attention over L=191
// ---------------------------------------------------------------------------
__global__ __launch_bounds__(256) void attn_kernel(const bf16* __restrict__ q,
                                                   const bf16* __restrict__ enc,
                                                   bf16* __restrict__ app)
{
    const int r = blockIdx.x;
    const int b = r / TM1_;
    const int tid = threadIdx.x;
    __shared__ float qs[H_];
    __shared__ float p[L_ + 1];
    __shared__ float red[256];
    const bf16* qrow = q + (size_t)r * H_;
    for (int h = tid; h < H_; h += 256) qs[h] = bf2f(qrow[h]);
    __syncthreads();
    const bf16* eb = enc + (size_t)b * L_ * H_;
    float myv = -1e30f;
    if (tid < L_) {
        const unsigned* er = (const unsigned*)(eb + (size_t)tid * H_);
        float s = 0.f;
        for (int k2 = 0; k2 < H_ / 2; ++k2) {
            const unsigned u = er[k2];
            s += qs[2 * k2] * uslo(u) + qs[2 * k2 + 1] * ushi(u);
        }
        p[tid] = s;
        myv = s;
    }
    red[tid] = myv;
    __syncthreads();
    for (int off = 128; off > 0; off >>= 1) {
        if (tid < off) red[tid] = fmaxf(red[tid], red[tid + off]);
        __syncthreads();
    }
    const float m = red[0];
    __syncthreads();
    float e = 0.f;
    if (tid < L_) e = expf(p[tid] - m);
    red[tid] = e;
    __syncthreads();
    for (int off = 128; off > 0; off >>= 1) {
        if (tid < off) red[tid] += red[tid + off];
        __syncthreads();
    }
    const float invZ = 1.f / red[0];
    __syncthreads();
    if (tid < L_) p[tid] = e * invZ;
    __syncthreads();
    for (int h = tid; h < H_; h += 256) {
        float s = 0.f;
        for (int l = 0; l < L_; ++l) s += p[l] * bf2f(eb[(size_t)l * H_ + h]);
        app[(size_t)r * H_ + h] = f2bf(s);
    }
}

// feat_e = [dec_e, dec_a, app, ced, cw]; feat_a = [dec_a, dec_e, app, cac, cw]
__global__ void feat_kernel(const bf16* __restrict__ oute, const bf16* __restrict__ outa,
                            const bf16* __restrict__ app, const bf16* __restrict__ ced,
                            const bf16* __restrict__ cac, const bf16* __restrict__ cw,
                            bf16* __restrict__ fe, bf16* __restrict__ fa)
{
    const int r = blockIdx.x;
    const int b = r / TM1_;
    const int t = r % TM1_;
    const unsigned* de  = (const unsigned*)(oute + ((size_t)b * T_ + t) * H_);
    const unsigned* da  = (const unsigned*)(outa + ((size_t)b * T_ + t) * H_);
    const unsigned* ap  = (const unsigned*)(app + (size_t)r * H_);
    const unsigned* ce  = (const unsigned*)(ced + (size_t)r * H_);
    const unsigned* cA  = (const unsigned*)(cac + (size_t)r * H_);
    const unsigned* cwp = (const unsigned*)(cw + (size_t)r * H_);
    unsigned* pfe = (unsigned*)(fe + (size_t)r * K5_);
    unsigned* pfa = (unsigned*)(fa + (size_t)r * K5_);
    const int HW = H_ / 2;
    for (int h = threadIdx.x; h < HW; h += 256) {
        const unsigned ve = de[h], va = da[h], vap = ap[h], vce = ce[h], vca = cA[h], vcw = cwp[h];
        pfe[h] = ve;  pfe[HW + h] = va;  pfe[2 * HW + h] = vap; pfe[3 * HW + h] = vce; pfe[4 * HW + h] = vcw;
        pfa[h] = va;  pfa[HW + h] = ve;  pfa[2 * HW + h] = vap; pfa[3 * HW + h] = vca; pfa[4 * HW + h] = vcw;
    }
}

// In-place log-softmax over f32 rows (edit head, N=30522)
__global__ __launch_bounds__(1024) void logsoftmax_edit_kernel(float* __restrict__ out)
{
    float* row = out + (size_t)blockIdx.x * V_;
    const int tid = threadIdx.x;
    __shared__ float red[1024];
    float m = -1e30f;
    for (int i = tid; i < V_; i += 1024) m = fmaxf(m, row[i]);
    red[tid] = m;
    __syncthreads();
    for (int off = 512; off > 0; off >>= 1) {
        if (tid < off) red[tid] = fmaxf(red[tid], red[tid + off]);
        __syncthreads();
    }
    m = red[0];
    __syncthreads();
    float s = 0.f;
    for (int i = tid; i < V_; i += 1024) s += expf(row[i] - m);
    red[tid] = s;
    __syncthreads();
    for (int off = 512; off > 0; off >>= 1) {
        if (tid < off) red[tid] += red[tid + off];
        __syncthreads();
    }
    const float lz = m + logf(red[0]);
    __syncthreads();
    for (int i = tid; i < V_; i += 1024) row[i] = row[i] - lz;
}

// Act head log-softmax: f32 in -> f32 out
__global__ __launch_bounds__(256) void logsoftmax_act_kernel(const float* __restrict__ in,
                                                             float* __restrict__ out)
{
    const float* row = in + (size_t)blockIdx.x * AV_;
    float* orow = out + (size_t)blockIdx.x * AV_;
    const int tid = threadIdx.x;
    __shared__ float red[256];
    float m = -1e30f;
    if (tid < AV_) m = row[tid];
    red[tid] = m;
    __syncthreads();
    for (int off = 128; off > 0; off >>= 1) {
        if (tid < off) red[tid] = fmaxf(red[tid], red[tid + off]);
        __syncthreads();
    }
    m = red[0];
    __syncthreads();
    float s = 0.f;
    if (tid < AV_) s = expf(row[tid] - m);
    red[tid] = s;
    __syncthreads();
    for (int off = 128; off > 0; off >>= 1) {
        if (tid < off) red[tid] += red[tid + off];
        __syncthreads();
    }
    const float lz = m + logf(red[0]);
    if (tid < AV_) orow[tid] = row[tid] - lz;
}

// ---------------------------------------------------------------------------
extern "C" void kernel_launch(void* const* d_in, const int* in_sizes, int n_in,
                              void* d_out, int out_size, void* d_ws, size_t ws_size,
                              hipStream_t stream)
{
    const int* input_edits   = (const int*)d_in[0];
    const int* input_actions = (const int*)d_in[1];
    const int* simp_sent     = (const int*)d_in[2];
    const int* org_ids       = (const int*)d_in[3];
    const float* enc_org     = (const float*)d_in[4];
    const float* emb         = (const float*)d_in[5];
    const float* Wih_e = (const float*)d_in[6];
    const float* Whh_e = (const float*)d_in[7];
    const float* bih_e = (const float*)d_in[8];
    const float* bhh_e = (const float*)d_in[9];
    const float* Wih_a = (const float*)d_in[10];
    const float* Whh_a = (const float*)d_in[11];
    const float* bih_a = (const float*)d_in[12];
    const float* bhh_a = (const float*)d_in[13];
    const float* Wih_w = (const float*)d_in[14];
    const float* Whh_w = (const float*)d_in[15];
    const float* bih_w = (const float*)d_in[16];
    const float* bhh_w = (const float*)d_in[17];
    const float* W_align = (const float*)d_in[18];
    const float* W_proj  = (const float*)d_in[19];
    const float* W_ref   = (const float*)d_in[20];
    const float* b_ref   = (const float*)d_in[21];
    const float* W_mlp   = (const float*)d_in[22];
    const float* b_mlp   = (const float*)d_in[23];
    const float* W_act   = (const float*)d_in[24];
    const float* b_act   = (const float*)d_in[25];
    const float* W_out   = (const float*)d_in[26];
    const float* b_out   = (const float*)d_in[27];
    const float* W_outact = (const float*)d_in[28];
    const float* b_outact = (const float*)d_in[29];
    const float* action_mask = (const float*)d_in[30];

    float* out = (float*)d_out;
    float* edit_out = out;                               // (2032, 30522) f32
    float* act_out  = out + (size_t)R_ * V_;             // (2032, 200)   f32

    // Workspace layout
    char* p = (char*)d_ws;
    auto take = [&](size_t bytes) { void* q = (void*)p; p += ((bytes + 255) / 256) * 256; return q; };
    int* cnts = (int*)take(256);                                  // barrier counters (3 x 64B)
    unsigned short* hbuf = (unsigned short*)take((size_t)3 * 2 * B_ * H_ * 2);  // h double-buffers
    bf16* xe   = (bf16*)take((size_t)B_ * T_ * H_ * 2);
    bf16* xa   = (bf16*)take((size_t)B_ * T_ * H_ * 2);
    bf16* xw   = (bf16*)take((size_t)B_ * S_ * H_ * 2);
    bf16* pxe  = (bf16*)take((size_t)B_ * T_ * G4_ * 2);
    bf16* pxa  = (bf16*)take((size_t)B_ * T_ * G4_ * 2);
    bf16* pxw  = (bf16*)take((size_t)B_ * S_ * G4_ * 2);
    bf16* oute = (bf16*)take((size_t)B_ * T_ * H_ * 2);
    bf16* outa = (bf16*)take((size_t)B_ * T_ * H_ * 2);
    bf16* outw = (bf16*)take((size_t)B_ * S_ * H_ * 2);
    bf16* enc  = (bf16*)take((size_t)B_ * L_ * H_ * 2);
    bf16* cw   = (bf16*)take((size_t)R_ * H_ * 2);
    bf16* ced  = (bf16*)take((size_t)R_ * H_ * 2);
    bf16* cac  = (bf16*)take((size_t)R_ * H_ * 2);
    bf16* qb   = (bf16*)take((size_t)R_ * H_ * 2);
    bf16* app  = (bf16*)take((size_t)R_ * H_ * 2);
    bf16* fe   = (bf16*)take((size_t)R_ * K5_ * 2);
    bf16* fa   = (bf16*)take((size_t)R_ * K5_ * 2);
    bf16* he   = (bf16*)take((size_t)R_ * H_ * 2);
    bf16* ha   = (bf16*)take((size_t)R_ * H_ * 2);
    int*  cd   = (int*)take((size_t)R_ * 4);
    int*  ci   = (int*)take((size_t)R_ * 4);
    int*  ca   = (int*)take((size_t)R_ * 4);
    float* actbuf = (float*)take((size_t)R_ * AV_ * 4);

    // 0. Zero barrier counters (graph-capturable, per-launch deterministic)
    hipMemsetAsync(cnts, 0, 256, stream);

    // 1. Embedding gathers (f32 emb -> bf16 rows)
    gather_rows_kernel<<<B_ * T_, 256, 0, stream>>>(input_edits, emb, xe);
    gather_rows_kernel<<<B_ * T_, 256, 0, stream>>>(input_actions, emb, xa);
    gather_rows_kernel<<<B_ * S_, 256, 0, stream>>>(simp_sent, emb, xw);

    // 2. Precompute x@Wih^T + bih + bhh for all timesteps
    dim3 g1((B_ * T_ + 63) / 64, (G4_ + 63) / 64);
    gemm_bt<bf16, float><<<g1, 256, 0, stream>>>(xe, Wih_e, bih_e, bhh_e, pxe, nullptr, B_ * T_, G4_, H_, 0, 0, H_);
    gemm_bt<bf16, float><<<g1, 256, 0, stream>>>(xa, Wih_a, bih_a, bhh_a, pxa, nullptr, B_ * T_, G4_, H_, 0, 0, H_);
    dim3 g1w((B_ * S_ + 63) / 64, (G4_ + 63) / 64);
    gemm_bt<bf16, float><<<g1w, 256, 0, stream>>>(xw, Wih_w, bih_w, bhh_w, pxw, nullptr, B_ * S_, G4_, H_, 0, 0, H_);

    // 3. enc = tanh(enc_org @ W_align^T)[:, 1:]
    dim3 g2((B_ * L_ + 63) / 64, (H_ + 63) / 64);
    gemm_bt<float, float><<<g2, 256, 0, stream>>>(enc_org, W_align, nullptr, nullptr, enc, nullptr, B_ * L_, H_, H_, 1, L_, H_);

    // 4. Counters scan
    counters_kernel<<<1, 64, 0, stream>>>(input_edits, org_ids, cd, ci, ca);

    // 5. Persistent cooperative LSTMs (144 blocks, all co-resident)
    lstm_mfma_kernel<<<3 * NB_, 256, 0, stream>>>(pxe, pxa, pxw, Whh_e, Whh_a, Whh_w,
                                                  oute, outa, outw, hbuf, cnts);

    // 6. c_word gather
    gather_cword_kernel<<<R_, 256, 0, stream>>>(outw, ci, cw);

    // 7. wref mixing -> c_edit, c_action
    ref_combine_kernel<<<R_, 256, 0, stream>>>(oute, outa, enc, W_ref, b_ref, cd, ca, ced, cac);

    // 8. q = c_word @ W_proj^T
    dim3 g3((R_ + 63) / 64, (H_ + 63) / 64);
    gemm_bt<bf16, float><<<g3, 256, 0, stream>>>(cw, W_proj, nullptr, nullptr, qb, nullptr, R_, H_, H_, 0, 0, H_);

    // 9. attention -> applied
    attn_kernel<<<R_, 256, 0, stream>>>(qb, enc, app);

    // 10. feature concat
    feat_kernel<<<R_, 256, 0, stream>>>(oute, outa, app, ced, cac, cw, fe, fa);

    // 11. hidden layers (tanh)
    gemm_bt<bf16, float><<<g3, 256, 0, stream>>>(fe, W_mlp, b_mlp, nullptr, he, nullptr, R_, H_, K5_, 1, 0, K5_);
    gemm_bt<bf16, float><<<g3, 256, 0, stream>>>(fa, W_act, b_act, nullptr, ha, nullptr, R_, H_, K5_, 1, 0, K5_);

    // 12. act head
    dim3 g4((R_ + 63) / 64, (AV_ + 63) / 64);
    gemm_bt<bf16, float><<<g4, 256, 0, stream>>>(ha, W_outact, b_outact, action_mask, nullptr, actbuf, R_, AV_, H_, 0, 0, H_);
    logsoftmax_act_kernel<<<R_, 256, 0, stream>>>(actbuf, act_out);

    // 13. edit head: logits f32 straight into d_out, in-place log-softmax
    dim3 g5((R_ + 63) / 64, (V_ + 63) / 64);
    gemm_bt<bf16, float><<<g5, 256, 0, stream>>>(he, W_out, b_out, nullptr, nullptr, edit_out, R_, V_, H_, 0, 0, H_);
    logsoftmax_edit_kernel<<<R_, 1024, 0, stream>>>(edit_out);
}

// Round 7
// 3143.390 us; speedup vs baseline: 10.2737x; 1.9458x over previous
//
#include <hip/hip_runtime.h>
#include <hip/hip_bf16.h>

typedef __hip_bfloat16 bf16;

// Problem dims
#define B_    16
#define T_    128
#define S_    192
#define H_    768
#define G4_   3072      // 4*H
#define V_    30522
#define AV_   200
#define L_    191       // L_SRC-1
#define TM1_  127       // T-1
#define R_    2032      // B*(T-1)
#define K5_   3840      // 5*H
#define NB_   48        // blocks per LSTM (persistent)
#define HSL_  16        // h-slice per block (768/48)

typedef short bf16x8_t __attribute__((ext_vector_type(8)));
typedef float f32x4_t  __attribute__((ext_vector_type(4)));

__device__ __forceinline__ float bf2f(bf16 v) { return __bfloat162float(v); }
__device__ __forceinline__ bf16  f2bf(float v) { return __float2bfloat16(v); }
__device__ __forceinline__ unsigned short f2us(float v) { bf16 h = f2bf(v); return *reinterpret_cast<unsigned short*>(&h); }
__device__ __forceinline__ float uslo(unsigned u) { union { unsigned i; float f; } x; x.i = u << 16; return x.f; }
__device__ __forceinline__ float ushi(unsigned u) { union { unsigned i; float f; } x; x.i = u & 0xffff0000u; return x.f; }
__device__ __forceinline__ float us2f(unsigned short u) { union { unsigned i; float f; } x; x.i = ((unsigned)u) << 16; return x.f; }
__device__ __forceinline__ float sigm(float x) { return 1.0f / (1.0f + expf(-x)); }

// 8-element bf16 fragment loads (optionally converting from f32)
__device__ __forceinline__ bf16x8_t ld8bf(const bf16* p) { return *(const bf16x8_t*)p; }
__device__ __forceinline__ bf16x8_t ld8bf(const float* p) {
    float4 a = *(const float4*)p;
    float4 b = *(const float4*)(p + 4);
    bf16x8_t r;
    r[0] = (short)f2us(a.x); r[1] = (short)f2us(a.y); r[2] = (short)f2us(a.z); r[3] = (short)f2us(a.w);
    r[4] = (short)f2us(b.x); r[5] = (short)f2us(b.y); r[6] = (short)f2us(b.z); r[7] = (short)f2us(b.w);
    return r;
}

// ---------------------------------------------------------------------------
// MFMA GEMM: C[M,N] = act( A[M,K] * W[N,K]^T + bias1 + bias2 )
// 128x128 tile, 256 threads (4 waves in 2x2), K-step 32, bf16 staging in LDS
// (inline f32->bf16 conversion during staging). rowdiv>0 remaps A row
// r -> r + r/rowdiv + 1 (the enc [:,1:] slice).
// Fragment mapping (HW-verified in this session's round-6 LSTM):
//   A/W frag: row = lane&15 of the 16-row subtile, k = (lane>>4)*8 + i
//   C/D:      col = lane&15, row = (lane>>4)*4 + j
// ---------------------------------------------------------------------------
template <typename TA, typename TW>
__global__ __launch_bounds__(256) void gemm_mfma(
    const TA* __restrict__ A, const TW* __restrict__ W,
    const float* __restrict__ bias1, const float* __restrict__ bias2,
    bf16* __restrict__ Ch, float* __restrict__ Cf,
    int M, int N, int K, int act, int rowdiv, int lda)
{
    __shared__ short As[128][40];   // +8 pad: row stride 80B -> conflict-free-ish
    __shared__ short Ws[128][40];
    const int tid = threadIdx.x;
    const int wave = tid >> 6, lane = tid & 63;
    const int mw = (wave >> 1) * 64, nw = (wave & 1) * 64;
    const int bm = blockIdx.x * 128, bn = blockIdx.y * 128;

    const int sr = tid >> 2;          // staging row 0..63 (+64 for chunk 1)
    const int sc = (tid & 3) * 8;     // staging col 0,8,16,24

    f32x4_t acc[4][4];
#pragma unroll
    for (int mi = 0; mi < 4; ++mi)
#pragma unroll
        for (int ni = 0; ni < 4; ++ni) acc[mi][ni] = (f32x4_t){0.f, 0.f, 0.f, 0.f};

    const int fr = lane & 15;
    const int fk = (lane >> 4) * 8;

    for (int k0 = 0; k0 < K; k0 += 32) {
#pragma unroll
        for (int c = 0; c < 2; ++c) {
            const int row = sr + c * 64;
            int ga = bm + row; if (ga > M - 1) ga = M - 1;           // clamp (stores guarded)
            const int ra = (rowdiv > 0) ? (ga + ga / rowdiv + 1) : ga;
            *(bf16x8_t*)&As[row][sc] = ld8bf(A + (size_t)ra * lda + k0 + sc);
            int gw = bn + row; if (gw > N - 1) gw = N - 1;
            *(bf16x8_t*)&Ws[row][sc] = ld8bf(W + (size_t)gw * K + k0 + sc);
        }
        __syncthreads();
        bf16x8_t af[4], wf[4];
#pragma unroll
        for (int i = 0; i < 4; ++i) af[i] = *(const bf16x8_t*)&As[mw + i * 16 + fr][fk];
#pragma unroll
        for (int i = 0; i < 4; ++i) wf[i] = *(const bf16x8_t*)&Ws[nw + i * 16 + fr][fk];
#pragma unroll
        for (int mi = 0; mi < 4; ++mi)
#pragma unroll
            for (int ni = 0; ni < 4; ++ni)
                acc[mi][ni] = __builtin_amdgcn_mfma_f32_16x16x32_bf16(af[mi], wf[ni], acc[mi][ni], 0, 0, 0);
        __syncthreads();
    }

    const int cl = lane & 15;
    const int rg = (lane >> 4) * 4;
#pragma unroll
    for (int mi = 0; mi < 4; ++mi) {
#pragma unroll
        for (int ni = 0; ni < 4; ++ni) {
            const int col = bn + nw + ni * 16 + cl;
            if (col >= N) continue;
#pragma unroll
            for (int j = 0; j < 4; ++j) {
                const int row = bm + mw + mi * 16 + rg + j;
                if (row >= M) continue;
                float v = acc[mi][ni][j];
                if (bias1) v += bias1[col];
                if (bias2) v += bias2[col];
                if (act == 1) v = tanhf(v);
                if (Ch) Ch[(size_t)row * N + col] = f2bf(v);
                else    Cf[(size_t)row * N + col] = v;
            }
        }
    }
}

// ---------------------------------------------------------------------------
// Persistent cooperative LSTM. Grid = 3 LSTMs x 48 blocks, 256 threads.
// Block owns h-slice [so, so+16); wave g holds gate g's 16x768 W rows as 24
// persistent bf16 MFMA A-fragments. h exchanged via global double-buffer;
// per-LSTM release-RMW + relaxed-poll barrier per step; out buffered in a
// 8-step LDS ring (small per-step dirty set for the release writeback).
// ---------------------------------------------------------------------------
__global__ __launch_bounds__(256) void lstm_mfma_kernel(
    const bf16* __restrict__ pxe, const bf16* __restrict__ pxa, const bf16* __restrict__ pxw,
    const float* __restrict__ We, const float* __restrict__ Wa, const float* __restrict__ Ww,
    bf16* __restrict__ oute, bf16* __restrict__ outa, bf16* __restrict__ outw,
    unsigned short* __restrict__ hbuf, int* __restrict__ cnts)
{
    const int which = blockIdx.x / NB_;
    const int nb = blockIdx.x % NB_;
    const bf16* px; const float* W; bf16* out; int Tn;
    if (which == 0)      { px = pxe; W = We; out = oute; Tn = T_; }
    else if (which == 1) { px = pxa; W = Wa; out = outa; Tn = T_; }
    else                 { px = pxw; W = Ww; out = outw; Tn = S_; }
    unsigned short* hG = hbuf + (size_t)which * (2 * B_ * H_);
    int* cnt = cnts + which * 16;   // 64B apart

    const int tid = threadIdx.x;
    const int wv = tid >> 6;        // wave index = gate (i,f,g,o)
    const int lane = tid & 63;
    const int so = nb * HSL_;

    __shared__ unsigned short hL[16][776];        // h (bf16 bits), row-padded +8
    __shared__ float gS[4][16][17];               // gate exchange [gate][hl][batch]
    __shared__ unsigned short oring[8][16][16];   // out ring [step&7][batch][hl]

    // --- persistent A-fragments: lane l -> row (l&15), k = kb*32 + (l>>4)*8 + i
    bf16x8_t Afrag[24];
    {
        const int m = lane & 15;
        const int kb8 = (lane >> 4) * 8;
        const float* wrow = W + (size_t)(wv * H_ + so + m) * H_ + kb8;
#pragma unroll
        for (int kb = 0; kb < 24; ++kb) {
            float4 f0 = *(const float4*)(wrow + kb * 32);
            float4 f1 = *(const float4*)(wrow + kb * 32 + 4);
            bf16x8_t a;
            a[0] = (short)f2us(f0.x); a[1] = (short)f2us(f0.y);
            a[2] = (short)f2us(f0.z); a[3] = (short)f2us(f0.w);
            a[4] = (short)f2us(f1.x); a[5] = (short)f2us(f1.y);
            a[6] = (short)f2us(f1.z); a[7] = (short)f2us(f1.w);
            Afrag[kb] = a;
        }
    }

    // h_0 = 0
    for (int i = tid; i < 16 * 776; i += 256) ((unsigned short*)hL)[i] = 0;

    // cell-thread mapping: b = tid>>4, hl = tid&15 ; c persists in register
    const int cb = tid >> 4;
    const int chl = tid & 15;
    float c = 0.f;

    const int bn = lane & 15;        // B-frag col = batch
    const int bk = (lane >> 4) * 8;  // B-frag k sub-offset

    int cur = 0;
    for (int step = 0; step < Tn; ++step) {
        if (step > 0) {
            const unsigned short* hsrc = hG + cur * (B_ * H_);
            for (int i = tid; i < B_ * H_ / 8; i += 256) {
                const int bb = i / 96;
                const int c8 = i - bb * 96;
                *(uint4*)&hL[bb][c8 * 8] = *(const uint4*)&hsrc[bb * H_ + c8 * 8];
            }
        }
        __syncthreads();

        f32x4_t acc = {0.f, 0.f, 0.f, 0.f};
#pragma unroll
        for (int kb = 0; kb < 24; ++kb) {
            bf16x8_t bfr = *(const bf16x8_t*)&hL[bn][kb * 32 + bk];
            acc = __builtin_amdgcn_mfma_f32_16x16x32_bf16(Afrag[kb], bfr, acc, 0, 0, 0);
        }
        {
            const int m0 = (lane >> 4) * 4;
#pragma unroll
            for (int j = 0; j < 4; ++j) gS[wv][m0 + j][bn] = acc[j];
        }
        __syncthreads();

        // cell update
        {
            const bf16* pxt = px + ((size_t)cb * Tn + step) * G4_ + so + chl;
            const float gi = gS[0][chl][cb] + bf2f(pxt[0]);
            const float gf = gS[1][chl][cb] + bf2f(pxt[H_]);
            const float gg = gS[2][chl][cb] + bf2f(pxt[2 * H_]);
            const float go = gS[3][chl][cb] + bf2f(pxt[3 * H_]);
            const float cn = sigm(gf) * c + sigm(gi) * tanhf(gg);
            const float hn = sigm(go) * tanhf(cn);
            c = cn;
            oring[step & 7][cb][chl] = f2us(hn);          // buffered out (self-owned slot)
            hG[(size_t)(cur ^ 1) * (B_ * H_) + cb * H_ + cb * 0 + cb * 0 + cb * 0 + so + chl] = f2us(hn);
        }
        // flush out ring every 8 steps (or at end) — batches the dirty set
        if ((step & 7) == 7 || step == Tn - 1) {
            const int base = step & ~7;
            const int cnt8 = (step & 7) + 1;
            for (int s2 = 0; s2 < cnt8; ++s2)
                out[((size_t)cb * Tn + base + s2) * H_ + so + chl] =
                    *reinterpret_cast<const bf16*>(&oring[s2][cb][chl]);
        }
        __syncthreads();
        if (tid == 0) {
            __hip_atomic_fetch_add(cnt, 1, __ATOMIC_RELEASE, __HIP_MEMORY_SCOPE_AGENT);
            const int target = NB_ * (step + 1);
            long guard = 0;
            while (__hip_atomic_load(cnt, __ATOMIC_RELAXED, __HIP_MEMORY_SCOPE_AGENT) < target) {
                __builtin_amdgcn_s_sleep(2);
                if (++guard > 50000000L) break;   // liveness guard (never hit in practice)
            }
        }
        __syncthreads();
        __builtin_amdgcn_fence(__ATOMIC_ACQUIRE, "agent");   // invalidate stale h lines
        cur ^= 1;
    }
}

// ---------------------------------------------------------------------------
// Row gather + convert: out[r][:] = bf16(emb[ids[r]][:])
// ---------------------------------------------------------------------------
__global__ void gather_rows_kernel(const int* __restrict__ ids,
                                   const float* __restrict__ emb,
                                   bf16* __restrict__ out)
{
    const int r = blockIdx.x;
    const float4* src = (const float4*)(emb + (size_t)ids[r] * H_);
    ushort4* dst = (ushort4*)(out + (size_t)r * H_);
    for (int h = threadIdx.x; h < H_ / 4; h += 256) {
        float4 v = src[h];
        ushort4 o;
        o.x = f2us(v.x); o.y = f2us(v.y); o.z = f2us(v.z); o.w = f2us(v.w);
        dst[h] = o;
    }
}

// ---------------------------------------------------------------------------
// Counters scan
// ---------------------------------------------------------------------------
__global__ void counters_kernel(const int* __restrict__ edits, const int* __restrict__ org,
                                int* __restrict__ cd, int* __restrict__ ci, int* __restrict__ ca)
{
    const int b = threadIdx.x;
    if (b >= B_) return;
    int vd = 0, vi = 0, va = 0;
    for (int t = 0; t < TM1_; ++t) {
        cd[b * TM1_ + t] = vd; ci[b * TM1_ + t] = vi; ca[b * TM1_ + t] = va;
        const int g = edits[b * T_ + t + 1];
        const int vd2 = vd + ((g == 3 || g == 4) ? 1 : 0);
        const int alive = (g != 4 && g != 2 && g != 0) ? 1 : 0;
        const int vi2 = vi + alive;
        int nxt = va + 1; if (nxt > L_ - 1) nxt = L_ - 1;
        const int tok = org[b * L_ + nxt];
        const bool cond = alive && (g != 3) && (va + 1 < L_) && (tok == 103 || tok == 3 || tok == 4);
        const int va2 = cond ? (va + 1) : max(vd2, va);
        vd = vd2; vi = vi2; va = va2;
    }
}

// c_word[r][:] = out_w[b][ci[r]][:]
__global__ void gather_cword_kernel(const bf16* __restrict__ outw, const int* __restrict__ ci,
                                    bf16* __restrict__ cw)
{
    const int r = blockIdx.x;
    const int b = r / TM1_;
    const unsigned* src = (const unsigned*)(outw + ((size_t)b * S_ + ci[r]) * H_);
    unsigned* dst = (unsigned*)(cw + (size_t)r * H_);
    for (int h = threadIdx.x; h < H_ / 2; h += 256) dst[h] = src[h];
}

// ---------------------------------------------------------------------------
// wref softmax (2-way) + mix c_input/c_anno
// ---------------------------------------------------------------------------
__global__ __launch_bounds__(256) void ref_combine_kernel(
    const bf16* __restrict__ oute, const bf16* __restrict__ outa, const bf16* __restrict__ enc,
    const float* __restrict__ Wref, const float* __restrict__ bref,
    const int* __restrict__ cd, const int* __restrict__ ca,
    bf16* __restrict__ ced, bf16* __restrict__ cac)
{
    const int r = blockIdx.x;
    const int b = r / TM1_;
    const int t = r % TM1_;
    const bf16* de = oute + ((size_t)b * T_ + t) * H_;
    const bf16* da = outa + ((size_t)b * T_ + t) * H_;
    const int tid = threadIdx.x;
    __shared__ float red[256][4];
    float s0 = 0.f, s1 = 0.f, s2 = 0.f, s3 = 0.f;
    for (int k = tid; k < H_; k += 256) {
        const float w0 = Wref[k];
        const float w1 = Wref[H_ + k];
        const float e = bf2f(de[k]);
        const float a = bf2f(da[k]);
        s0 += e * w0; s1 += e * w1; s2 += a * w0; s3 += a * w1;
    }
    red[tid][0] = s0; red[tid][1] = s1; red[tid][2] = s2; red[tid][3] = s3;
    __syncthreads();
    for (int off = 128; off > 0; off >>= 1) {
        if (tid < off) {
            red[tid][0] += red[tid + off][0];
            red[tid][1] += red[tid + off][1];
            red[tid][2] += red[tid + off][2];
            red[tid][3] += red[tid + off][3];
        }
        __syncthreads();
    }
    const float br0 = bref[0], br1 = bref[1];
    const float xe0 = red[0][0] + br0, xe1 = red[0][1] + br1;
    const float xa0 = red[0][2] + br0, xa1 = red[0][3] + br1;
    const float me = fmaxf(xe0, xe1);
    const float ee0 = expf(xe0 - me), ee1 = expf(xe1 - me);
    const float pe0 = ee0 / (ee0 + ee1), pe1 = ee1 / (ee0 + ee1);
    const float ma = fmaxf(xa0, xa1);
    const float ea0 = expf(xa0 - ma), ea1 = expf(xa1 - ma);
    const float pa0 = ea0 / (ea0 + ea1), pa1 = ea1 / (ea0 + ea1);

    const bf16* ei = enc + ((size_t)b * L_ + cd[r]) * H_;
    const bf16* ea = enc + ((size_t)b * L_ + ca[r]) * H_;
    for (int h = tid; h < H_; h += 256) {
        const float vi = bf2f(ei[h]);
        const float va = bf2f(ea[h]);
        ced[(size_t)r * H_ + h] = f2bf(pe0 * vi + pe1 * va);
        cac[(size_t)r * H_ + h] = f2bf(pa0 * vi + pa1 * va);
    }
}

// ---------------------------------------------------------------------------
// Attention over L=191
// ---------------------------------------------------------------------------
__global__ __launch_bounds__(256) void attn_kernel(const bf16* __restrict__ q,
                                                   const bf16* __restrict__ enc,
                                                   bf16* __restrict__ app)
{
    const int r = blockIdx.x;
    const int b = r / TM1_;
    const int tid = threadIdx.x;
    __shared__ float qs[H_];
    __shared__ float p[L_ + 1];
    __shared__ float red[256];
    const bf16* qrow = q + (size_t)r * H_;
    for (int h = tid; h < H_; h += 256) qs[h] = bf2f(qrow[h]);
    __syncthreads();
    const bf16* eb = enc + (size_t)b * L_ * H_;
    float myv = -1e30f;
    if (tid < L_) {
        const unsigned* er = (const unsigned*)(eb + (size_t)tid * H_);
        float s = 0.f;
        for (int k2 = 0; k2 < H_ / 2; ++k2) {
            const unsigned u = er[k2];
            s += qs[2 * k2] * uslo(u) + qs[2 * k2 + 1] * ushi(u);
        }
        p[tid] = s;
        myv = s;
    }
    red[tid] = myv;
    __syncthreads();
    for (int off = 128; off > 0; off >>= 1) {
        if (tid < off) red[tid] = fmaxf(red[tid], red[tid + off]);
        __syncthreads();
    }
    const float m = red[0];
    __syncthreads();
    float e = 0.f;
    if (tid < L_) e = expf(p[tid] - m);
    red[tid] = e;
    __syncthreads();
    for (int off = 128; off > 0; off >>= 1) {
        if (tid < off) red[tid] += red[tid + off];
        __syncthreads();
    }
    const float invZ = 1.f / red[0];
    __syncthreads();
    if (tid < L_) p[tid] = e * invZ;
    __syncthreads();
    for (int h = tid; h < H_; h += 256) {
        float s = 0.f;
        for (int l = 0; l < L_; ++l) s += p[l] * bf2f(eb[(size_t)l * H_ + h]);
        app[(size_t)r * H_ + h] = f2bf(s);
    }
}

// feat_e = [dec_e, dec_a, app, ced, cw]; feat_a = [dec_a, dec_e, app, cac, cw]
__global__ void feat_kernel(const bf16* __restrict__ oute, const bf16* __restrict__ outa,
                            const bf16* __restrict__ app, const bf16* __restrict__ ced,
                            const bf16* __restrict__ cac, const bf16* __restrict__ cw,
                            bf16* __restrict__ fe, bf16* __restrict__ fa)
{
    const int r = blockIdx.x;
    const int b = r / TM1_;
    const int t = r % TM1_;
    const unsigned* de  = (const unsigned*)(oute + ((size_t)b * T_ + t) * H_);
    const unsigned* da  = (const unsigned*)(outa + ((size_t)b * T_ + t) * H_);
    const unsigned* ap  = (const unsigned*)(app + (size_t)r * H_);
    const unsigned* ce  = (const unsigned*)(ced + (size_t)r * H_);
    const unsigned* cA  = (const unsigned*)(cac + (size_t)r * H_);
    const unsigned* cwp = (const unsigned*)(cw + (size_t)r * H_);
    unsigned* pfe = (unsigned*)(fe + (size_t)r * K5_);
    unsigned* pfa = (unsigned*)(fa + (size_t)r * K5_);
    const int HW = H_ / 2;
    for (int h = threadIdx.x; h < HW; h += 256) {
        const unsigned ve = de[h], va = da[h], vap = ap[h], vce = ce[h], vca = cA[h], vcw = cwp[h];
        pfe[h] = ve;  pfe[HW + h] = va;  pfe[2 * HW + h] = vap; pfe[3 * HW + h] = vce; pfe[4 * HW + h] = vcw;
        pfa[h] = va;  pfa[HW + h] = ve;  pfa[2 * HW + h] = vap; pfa[3 * HW + h] = vca; pfa[4 * HW + h] = vcw;
    }
}

// In-place log-softmax over f32 rows (edit head, N=30522)
__global__ __launch_bounds__(1024) void logsoftmax_edit_kernel(float* __restrict__ out)
{
    float* row = out + (size_t)blockIdx.x * V_;
    const int tid = threadIdx.x;
    __shared__ float red[1024];
    float m = -1e30f;
    for (int i = tid; i < V_; i += 1024) m = fmaxf(m, row[i]);
    red[tid] = m;
    __syncthreads();
    for (int off = 512; off > 0; off >>= 1) {
        if (tid < off) red[tid] = fmaxf(red[tid], red[tid + off]);
        __syncthreads();
    }
    m = red[0];
    __syncthreads();
    float s = 0.f;
    for (int i = tid; i < V_; i += 1024) s += expf(row[i] - m);
    red[tid] = s;
    __syncthreads();
    for (int off = 512; off > 0; off >>= 1) {
        if (tid < off) red[tid] += red[tid + off];
        __syncthreads();
    }
    const float lz = m + logf(red[0]);
    __syncthreads();
    for (int i = tid; i < V_; i += 1024) row[i] = row[i] - lz;
}

// Act head log-softmax: f32 in -> f32 out
__global__ __launch_bounds__(256) void logsoftmax_act_kernel(const float* __restrict__ in,
                                                             float* __restrict__ out)
{
    const float* row = in + (size_t)blockIdx.x * AV_;
    float* orow = out + (size_t)blockIdx.x * AV_;
    const int tid = threadIdx.x;
    __shared__ float red[256];
    float m = -1e30f;
    if (tid < AV_) m = row[tid];
    red[tid] = m;
    __syncthreads();
    for (int off = 128; off > 0; off >>= 1) {
        if (tid < off) red[tid] = fmaxf(red[tid], red[tid + off]);
        __syncthreads();
    }
    m = red[0];
    __syncthreads();
    float s = 0.f;
    if (tid < AV_) s = expf(row[tid] - m);
    red[tid] = s;
    __syncthreads();
    for (int off = 128; off > 0; off >>= 1) {
        if (tid < off) red[tid] += red[tid + off];
        __syncthreads();
    }
    const float lz = m + logf(red[0]);
    if (tid < AV_) orow[tid] = row[tid] - lz;
}

// ---------------------------------------------------------------------------
extern "C" void kernel_launch(void* const* d_in, const int* in_sizes, int n_in,
                              void* d_out, int out_size, void* d_ws, size_t ws_size,
                              hipStream_t stream)
{
    const int* input_edits   = (const int*)d_in[0];
    const int* input_actions = (const int*)d_in[1];
    const int* simp_sent     = (const int*)d_in[2];
    const int* org_ids       = (const int*)d_in[3];
    const float* enc_org     = (const float*)d_in[4];
    const float* emb         = (const float*)d_in[5];
    const float* Wih_e = (const float*)d_in[6];
    const float* Whh_e = (const float*)d_in[7];
    const float* bih_e = (const float*)d_in[8];
    const float* bhh_e = (const float*)d_in[9];
    const float* Wih_a = (const float*)d_in[10];
    const float* Whh_a = (const float*)d_in[11];
    const float* bih_a = (const float*)d_in[12];
    const float* bhh_a = (const float*)d_in[13];
    const float* Wih_w = (const float*)d_in[14];
    const float* Whh_w = (const float*)d_in[15];
    const float* bih_w = (const float*)d_in[16];
    const float* bhh_w = (const float*)d_in[17];
    const float* W_align = (const float*)d_in[18];
    const float* W_proj  = (const float*)d_in[19];
    const float* W_ref   = (const float*)d_in[20];
    const float* b_ref   = (const float*)d_in[21];
    const float* W_mlp   = (const float*)d_in[22];
    const float* b_mlp   = (const float*)d_in[23];
    const float* W_act   = (const float*)d_in[24];
    const float* b_act   = (const float*)d_in[25];
    const float* W_out   = (const float*)d_in[26];
    const float* b_out   = (const float*)d_in[27];
    const float* W_outact = (const float*)d_in[28];
    const float* b_outact = (const float*)d_in[29];
    const float* action_mask = (const float*)d_in[30];

    float* out = (float*)d_out;
    float* edit_out = out;                               // (2032, 30522) f32
    float* act_out  = out + (size_t)R_ * V_;             // (2032, 200)   f32

    // Workspace layout
    char* p = (char*)d_ws;
    auto take = [&](size_t bytes) { void* q = (void*)p; p += ((bytes + 255) / 256) * 256; return q; };
    int* cnts = (int*)take(256);                                  // barrier counters (3 x 64B)
    unsigned short* hbuf = (unsigned short*)take((size_t)3 * 2 * B_ * H_ * 2);  // h double-buffers
    bf16* xe   = (bf16*)take((size_t)B_ * T_ * H_ * 2);
    bf16* xa   = (bf16*)take((size_t)B_ * T_ * H_ * 2);
    bf16* xw   = (bf16*)take((size_t)B_ * S_ * H_ * 2);
    bf16* pxe  = (bf16*)take((size_t)B_ * T_ * G4_ * 2);
    bf16* pxa  = (bf16*)take((size_t)B_ * T_ * G4_ * 2);
    bf16* pxw  = (bf16*)take((size_t)B_ * S_ * G4_ * 2);
    bf16* oute = (bf16*)take((size_t)B_ * T_ * H_ * 2);
    bf16* outa = (bf16*)take((size_t)B_ * T_ * H_ * 2);
    bf16* outw = (bf16*)take((size_t)B_ * S_ * H_ * 2);
    bf16* enc  = (bf16*)take((size_t)B_ * L_ * H_ * 2);
    bf16* cw   = (bf16*)take((size_t)R_ * H_ * 2);
    bf16* ced  = (bf16*)take((size_t)R_ * H_ * 2);
    bf16* cac  = (bf16*)take((size_t)R_ * H_ * 2);
    bf16* qb   = (bf16*)take((size_t)R_ * H_ * 2);
    bf16* app  = (bf16*)take((size_t)R_ * H_ * 2);
    bf16* fe   = (bf16*)take((size_t)R_ * K5_ * 2);
    bf16* fa   = (bf16*)take((size_t)R_ * K5_ * 2);
    bf16* he   = (bf16*)take((size_t)R_ * H_ * 2);
    bf16* ha   = (bf16*)take((size_t)R_ * H_ * 2);
    int*  cd   = (int*)take((size_t)R_ * 4);
    int*  ci   = (int*)take((size_t)R_ * 4);
    int*  ca   = (int*)take((size_t)R_ * 4);
    float* actbuf = (float*)take((size_t)R_ * AV_ * 4);

    // 0. Zero barrier counters (graph-capturable, per-launch deterministic)
    hipMemsetAsync(cnts, 0, 256, stream);

    // 1. Embedding gathers (f32 emb -> bf16 rows)
    gather_rows_kernel<<<B_ * T_, 256, 0, stream>>>(input_edits, emb, xe);
    gather_rows_kernel<<<B_ * T_, 256, 0, stream>>>(input_actions, emb, xa);
    gather_rows_kernel<<<B_ * S_, 256, 0, stream>>>(simp_sent, emb, xw);

    // 2. Precompute x@Wih^T + bih + bhh (MFMA)
    dim3 gpx((B_ * T_ + 127) / 128, (G4_ + 127) / 128);
    gemm_mfma<bf16, float><<<gpx, 256, 0, stream>>>(xe, Wih_e, bih_e, bhh_e, pxe, nullptr, B_ * T_, G4_, H_, 0, 0, H_);
    gemm_mfma<bf16, float><<<gpx, 256, 0, stream>>>(xa, Wih_a, bih_a, bhh_a, pxa, nullptr, B_ * T_, G4_, H_, 0, 0, H_);
    dim3 gpxw((B_ * S_ + 127) / 128, (G4_ + 127) / 128);
    gemm_mfma<bf16, float><<<gpxw, 256, 0, stream>>>(xw, Wih_w, bih_w, bhh_w, pxw, nullptr, B_ * S_, G4_, H_, 0, 0, H_);

    // 3. enc = tanh(enc_org @ W_align^T)[:, 1:]  (row remap via rowdiv)
    dim3 genc((B_ * L_ + 127) / 128, (H_ + 127) / 128);
    gemm_mfma<float, float><<<genc, 256, 0, stream>>>(enc_org, W_align, nullptr, nullptr, enc, nullptr, B_ * L_, H_, H_, 1, L_, H_);

    // 4. Counters scan
    counters_kernel<<<1, 64, 0, stream>>>(input_edits, org_ids, cd, ci, ca);

    // 5. Persistent cooperative LSTMs (144 blocks, all co-resident)
    lstm_mfma_kernel<<<3 * NB_, 256, 0, stream>>>(pxe, pxa, pxw, Whh_e, Whh_a, Whh_w,
                                                  oute, outa, outw, hbuf, cnts);

    // 6. c_word gather
    gather_cword_kernel<<<R_, 256, 0, stream>>>(outw, ci, cw);

    // 7. wref mixing -> c_edit, c_action
    ref_combine_kernel<<<R_, 256, 0, stream>>>(oute, outa, enc, W_ref, b_ref, cd, ca, ced, cac);

    // 8. q = c_word @ W_proj^T (MFMA)
    dim3 gproj((R_ + 127) / 128, (H_ + 127) / 128);
    gemm_mfma<bf16, float><<<gproj, 256, 0, stream>>>(cw, W_proj, nullptr, nullptr, qb, nullptr, R_, H_, H_, 0, 0, H_);

    // 9. attention -> applied
    attn_kernel<<<R_, 256, 0, stream>>>(qb, enc, app);

    // 10. feature concat
    feat_kernel<<<R_, 256, 0, stream>>>(oute, outa, app, ced, cac, cw, fe, fa);

    // 11. hidden layers (tanh, MFMA, K=3840)
    gemm_mfma<bf16, float><<<gproj, 256, 0, stream>>>(fe, W_mlp, b_mlp, nullptr, he, nullptr, R_, H_, K5_, 1, 0, K5_);
    gemm_mfma<bf16, float><<<gproj, 256, 0, stream>>>(fa, W_act, b_act, nullptr, ha, nullptr, R_, H_, K5_, 1, 0, K5_);

    // 12. act head (MFMA) + log-softmax
    dim3 gact((R_ + 127) / 128, (AV_ + 127) / 128);
    gemm_mfma<bf16, float><<<gact, 256, 0, stream>>>(ha, W_outact, b_outact, action_mask, nullptr, actbuf, R_, AV_, H_, 0, 0, H_);
    logsoftmax_act_kernel<<<R_, 256, 0, stream>>>(actbuf, act_out);

    // 13. edit head (MFMA, f32 straight into d_out) + in-place log-softmax
    dim3 gedit((R_ + 127) / 128, (V_ + 127) / 128);
    gemm_mfma<bf16, float><<<gedit, 256, 0, stream>>>(he, W_out, b_out, nullptr, nullptr, edit_out, R_, V_, H_, 0, 0, H_);
    logsoftmax_edit_kernel<<<R_, 1024, 0, stream>>>(edit_out);
}

// Round 8
// 2985.149 us; speedup vs baseline: 10.8183x; 1.0530x over previous
//
#include <hip/hip_runtime.h>
#include <hip/hip_bf16.h>

typedef __hip_bfloat16 bf16;

// Problem dims
#define B_    16
#define T_    128
#define S_    192
#define H_    768
#define G4_   3072      // 4*H
#define V_    30522
#define AV_   200
#define L_    191       // L_SRC-1
#define TM1_  127       // T-1
#define R_    2032      // B*(T-1)
#define K5_   3840      // 5*H
#define NB_   48        // blocks per LSTM (persistent)
#define HSL_  16        // h-slice per block (768/48)

typedef short bf16x8_t __attribute__((ext_vector_type(8)));
typedef float f32x4_t  __attribute__((ext_vector_type(4)));

__device__ __forceinline__ float bf2f(bf16 v) { return __bfloat162float(v); }
__device__ __forceinline__ bf16  f2bf(float v) { return __float2bfloat16(v); }
__device__ __forceinline__ unsigned short f2us(float v) { bf16 h = f2bf(v); return *reinterpret_cast<unsigned short*>(&h); }
__device__ __forceinline__ float uslo(unsigned u) { union { unsigned i; float f; } x; x.i = u << 16; return x.f; }
__device__ __forceinline__ float ushi(unsigned u) { union { unsigned i; float f; } x; x.i = u & 0xffff0000u; return x.f; }
__device__ __forceinline__ float us2f(unsigned short u) { union { unsigned i; float f; } x; x.i = ((unsigned)u) << 16; return x.f; }
__device__ __forceinline__ float sigm(float x) { return 1.0f / (1.0f + expf(-x)); }

// 8-element bf16 fragment loads (optionally converting from f32)
__device__ __forceinline__ bf16x8_t ld8bf(const bf16* p) { return *(const bf16x8_t*)p; }
__device__ __forceinline__ bf16x8_t ld8bf(const float* p) {
    float4 a = *(const float4*)p;
    float4 b = *(const float4*)(p + 4);
    bf16x8_t r;
    r[0] = (short)f2us(a.x); r[1] = (short)f2us(a.y); r[2] = (short)f2us(a.z); r[3] = (short)f2us(a.w);
    r[4] = (short)f2us(b.x); r[5] = (short)f2us(b.y); r[6] = (short)f2us(b.z); r[7] = (short)f2us(b.w);
    return r;
}

// ---------------------------------------------------------------------------
// MFMA GEMM: C[M,N] = act( A[M,K] * W[N,K]^T + bias1 + bias2 )
// 128x128 tile, 256 threads (4 waves in 2x2), K-step 32, bf16 staging in LDS.
// ---------------------------------------------------------------------------
template <typename TA, typename TW>
__global__ __launch_bounds__(256) void gemm_mfma(
    const TA* __restrict__ A, const TW* __restrict__ W,
    const float* __restrict__ bias1, const float* __restrict__ bias2,
    bf16* __restrict__ Ch, float* __restrict__ Cf,
    int M, int N, int K, int act, int rowdiv, int lda)
{
    __shared__ short As[128][40];
    __shared__ short Ws[128][40];
    const int tid = threadIdx.x;
    const int wave = tid >> 6, lane = tid & 63;
    const int mw = (wave >> 1) * 64, nw = (wave & 1) * 64;
    const int bm = blockIdx.x * 128, bn = blockIdx.y * 128;

    const int sr = tid >> 2;
    const int sc = (tid & 3) * 8;

    f32x4_t acc[4][4];
#pragma unroll
    for (int mi = 0; mi < 4; ++mi)
#pragma unroll
        for (int ni = 0; ni < 4; ++ni) acc[mi][ni] = (f32x4_t){0.f, 0.f, 0.f, 0.f};

    const int fr = lane & 15;
    const int fk = (lane >> 4) * 8;

    for (int k0 = 0; k0 < K; k0 += 32) {
#pragma unroll
        for (int c = 0; c < 2; ++c) {
            const int row = sr + c * 64;
            int ga = bm + row; if (ga > M - 1) ga = M - 1;
            const int ra = (rowdiv > 0) ? (ga + ga / rowdiv + 1) : ga;
            *(bf16x8_t*)&As[row][sc] = ld8bf(A + (size_t)ra * lda + k0 + sc);
            int gw = bn + row; if (gw > N - 1) gw = N - 1;
            *(bf16x8_t*)&Ws[row][sc] = ld8bf(W + (size_t)gw * K + k0 + sc);
        }
        __syncthreads();
        bf16x8_t af[4], wf[4];
#pragma unroll
        for (int i = 0; i < 4; ++i) af[i] = *(const bf16x8_t*)&As[mw + i * 16 + fr][fk];
#pragma unroll
        for (int i = 0; i < 4; ++i) wf[i] = *(const bf16x8_t*)&Ws[nw + i * 16 + fr][fk];
#pragma unroll
        for (int mi = 0; mi < 4; ++mi)
#pragma unroll
            for (int ni = 0; ni < 4; ++ni)
                acc[mi][ni] = __builtin_amdgcn_mfma_f32_16x16x32_bf16(af[mi], wf[ni], acc[mi][ni], 0, 0, 0);
        __syncthreads();
    }

    const int cl = lane & 15;
    const int rg = (lane >> 4) * 4;
#pragma unroll
    for (int mi = 0; mi < 4; ++mi) {
#pragma unroll
        for (int ni = 0; ni < 4; ++ni) {
            const int col = bn + nw + ni * 16 + cl;
            if (col >= N) continue;
#pragma unroll
            for (int j = 0; j < 4; ++j) {
                const int row = bm + mw + mi * 16 + rg + j;
                if (row >= M) continue;
                float v = acc[mi][ni][j];
                if (bias1) v += bias1[col];
                if (bias2) v += bias2[col];
                if (act == 1) v = tanhf(v);
                if (Ch) Ch[(size_t)row * N + col] = f2bf(v);
                else    Cf[(size_t)row * N + col] = v;
            }
        }
    }
}

// ---------------------------------------------------------------------------
// Persistent cooperative LSTM. Grid = 3 LSTMs x 48 blocks, 256 threads.
// h exchange + barrier use device-coherent (agent-scope relaxed) accesses so
// NO agent fences are needed -> no per-step L2 writeback/invalidate.
// ---------------------------------------------------------------------------
__global__ __launch_bounds__(256) void lstm_mfma_kernel(
    const bf16* __restrict__ pxe, const bf16* __restrict__ pxa, const bf16* __restrict__ pxw,
    const float* __restrict__ We, const float* __restrict__ Wa, const float* __restrict__ Ww,
    bf16* __restrict__ oute, bf16* __restrict__ outa, bf16* __restrict__ outw,
    unsigned short* __restrict__ hbuf, int* __restrict__ cnts)
{
    const int which = blockIdx.x / NB_;
    const int nb = blockIdx.x % NB_;
    const bf16* px; const float* W; bf16* out; int Tn;
    if (which == 0)      { px = pxe; W = We; out = oute; Tn = T_; }
    else if (which == 1) { px = pxa; W = Wa; out = outa; Tn = T_; }
    else                 { px = pxw; W = Ww; out = outw; Tn = S_; }
    unsigned short* hG = hbuf + (size_t)which * (2 * B_ * H_);
    int* cnt = cnts + which * 16;   // 64B apart

    const int tid = threadIdx.x;
    const int wv = tid >> 6;        // wave index = gate (i,f,g,o)
    const int lane = tid & 63;
    const int so = nb * HSL_;

    __shared__ unsigned short hL[16][776];        // h (bf16 bits), row-padded +8
    __shared__ float gS[4][16][17];               // gate exchange [gate][hl][batch]
    __shared__ unsigned short oring[8][16][16];   // out ring [step&7][batch][hl]

    // persistent A-fragments: lane l -> row (l&15), k = kb*32 + (l>>4)*8 + i
    bf16x8_t Afrag[24];
    {
        const int m = lane & 15;
        const int kb8 = (lane >> 4) * 8;
        const float* wrow = W + (size_t)(wv * H_ + so + m) * H_ + kb8;
#pragma unroll
        for (int kb = 0; kb < 24; ++kb) {
            float4 f0 = *(const float4*)(wrow + kb * 32);
            float4 f1 = *(const float4*)(wrow + kb * 32 + 4);
            bf16x8_t a;
            a[0] = (short)f2us(f0.x); a[1] = (short)f2us(f0.y);
            a[2] = (short)f2us(f0.z); a[3] = (short)f2us(f0.w);
            a[4] = (short)f2us(f1.x); a[5] = (short)f2us(f1.y);
            a[6] = (short)f2us(f1.z); a[7] = (short)f2us(f1.w);
            Afrag[kb] = a;
        }
    }

    // h_0 = 0
    for (int i = tid; i < 16 * 776; i += 256) ((unsigned short*)hL)[i] = 0;

    const int cb = tid >> 4;
    const int chl = tid & 15;
    float c = 0.f;

    const int bn = lane & 15;        // B-frag col = batch
    const int bk = (lane >> 4) * 8;  // B-frag k sub-offset

    int cur = 0;
    for (int step = 0; step < Tn; ++step) {
        if (step > 0) {
            // device-coherent h read (bypasses stale L1/L2)
            const unsigned* hsrc = (const unsigned*)(hG + (size_t)cur * (B_ * H_));
            for (int i = tid; i < B_ * H_ / 2; i += 256) {
                const unsigned v = __hip_atomic_load(hsrc + i, __ATOMIC_RELAXED, __HIP_MEMORY_SCOPE_AGENT);
                const int bb = i / 384;
                const int cc = i - bb * 384;
                ((unsigned*)&hL[bb][0])[cc] = v;
            }
        }
        __syncthreads();

        f32x4_t acc = {0.f, 0.f, 0.f, 0.f};
#pragma unroll
        for (int kb = 0; kb < 24; ++kb) {
            bf16x8_t bfr = *(const bf16x8_t*)&hL[bn][kb * 32 + bk];
            acc = __builtin_amdgcn_mfma_f32_16x16x32_bf16(Afrag[kb], bfr, acc, 0, 0, 0);
        }
        {
            const int m0 = (lane >> 4) * 4;
#pragma unroll
            for (int j = 0; j < 4; ++j) gS[wv][m0 + j][bn] = acc[j];
        }
        __syncthreads();

        // cell update
        {
            const bf16* pxt = px + ((size_t)cb * Tn + step) * G4_ + so + chl;
            const float gi = gS[0][chl][cb] + bf2f(pxt[0]);
            const float gf = gS[1][chl][cb] + bf2f(pxt[H_]);
            const float gg = gS[2][chl][cb] + bf2f(pxt[2 * H_]);
            const float go = gS[3][chl][cb] + bf2f(pxt[3 * H_]);
            const float cn = sigm(gf) * c + sigm(gi) * tanhf(gg);
            const float hn = sigm(go) * tanhf(cn);
            c = cn;
            oring[step & 7][cb][chl] = f2us(hn);
            // device-coherent h write (write-through to coherence point)
            __hip_atomic_store(&hG[(size_t)(cur ^ 1) * (B_ * H_) + cb * H_ + so + chl],
                               f2us(hn), __ATOMIC_RELAXED, __HIP_MEMORY_SCOPE_AGENT);
        }
        // flush out ring every 8 steps (plain cached stores; visible at kernel end)
        if ((step & 7) == 7 || step == Tn - 1) {
            const int base = step & ~7;
            const int cnt8 = (step & 7) + 1;
            for (int s2 = 0; s2 < cnt8; ++s2)
                out[((size_t)cb * Tn + base + s2) * H_ + so + chl] =
                    *reinterpret_cast<const bf16*>(&oring[s2][cb][chl]);
        }
        __syncthreads();   // drains vmcnt -> h stores globally complete before the add
        if (tid == 0) {
            __hip_atomic_fetch_add(cnt, 1, __ATOMIC_RELAXED, __HIP_MEMORY_SCOPE_AGENT);
            const int target = NB_ * (step + 1);
            long guard = 0;
            while (__hip_atomic_load(cnt, __ATOMIC_RELAXED, __HIP_MEMORY_SCOPE_AGENT) < target) {
                __builtin_amdgcn_s_sleep(1);
                if (++guard > 50000000L) break;   // liveness guard
            }
        }
        __syncthreads();
        cur ^= 1;
    }
}

// ---------------------------------------------------------------------------
// Row gather + convert: out[r][:] = bf16(emb[ids[r]][:])
// ---------------------------------------------------------------------------
__global__ void gather_rows_kernel(const int* __restrict__ ids,
                                   const float* __restrict__ emb,
                                   bf16* __restrict__ out)
{
    const int r = blockIdx.x;
    const float4* src = (const float4*)(emb + (size_t)ids[r] * H_);
    ushort4* dst = (ushort4*)(out + (size_t)r * H_);
    for (int h = threadIdx.x; h < H_ / 4; h += 256) {
        float4 v = src[h];
        ushort4 o;
        o.x = f2us(v.x); o.y = f2us(v.y); o.z = f2us(v.z); o.w = f2us(v.w);
        dst[h] = o;
    }
}

// ---------------------------------------------------------------------------
// Counters scan
// ---------------------------------------------------------------------------
__global__ void counters_kernel(const int* __restrict__ edits, const int* __restrict__ org,
                                int* __restrict__ cd, int* __restrict__ ci, int* __restrict__ ca)
{
    const int b = threadIdx.x;
    if (b >= B_) return;
    int vd = 0, vi = 0, va = 0;
    for (int t = 0; t < TM1_; ++t) {
        cd[b * TM1_ + t] = vd; ci[b * TM1_ + t] = vi; ca[b * TM1_ + t] = va;
        const int g = edits[b * T_ + t + 1];
        const int vd2 = vd + ((g == 3 || g == 4) ? 1 : 0);
        const int alive = (g != 4 && g != 2 && g != 0) ? 1 : 0;
        const int vi2 = vi + alive;
        int nxt = va + 1; if (nxt > L_ - 1) nxt = L_ - 1;
        const int tok = org[b * L_ + nxt];
        const bool cond = alive && (g != 3) && (va + 1 < L_) && (tok == 103 || tok == 3 || tok == 4);
        const int va2 = cond ? (va + 1) : max(vd2, va);
        vd = vd2; vi = vi2; va = va2;
    }
}

// c_word[r][:] = out_w[b][ci[r]][:]
__global__ void gather_cword_kernel(const bf16* __restrict__ outw, const int* __restrict__ ci,
                                    bf16* __restrict__ cw)
{
    const int r = blockIdx.x;
    const int b = r / TM1_;
    const unsigned* src = (const unsigned*)(outw + ((size_t)b * S_ + ci[r]) * H_);
    unsigned* dst = (unsigned*)(cw + (size_t)r * H_);
    for (int h = threadIdx.x; h < H_ / 2; h += 256) dst[h] = src[h];
}

// ---------------------------------------------------------------------------
// wref softmax (2-way) + mix c_input/c_anno
// ---------------------------------------------------------------------------
__global__ __launch_bounds__(256) void ref_combine_kernel(
    const bf16* __restrict__ oute, const bf16* __restrict__ outa, const bf16* __restrict__ enc,
    const float* __restrict__ Wref, const float* __restrict__ bref,
    const int* __restrict__ cd, const int* __restrict__ ca,
    bf16* __restrict__ ced, bf16* __restrict__ cac)
{
    const int r = blockIdx.x;
    const int b = r / TM1_;
    const int t = r % TM1_;
    const bf16* de = oute + ((size_t)b * T_ + t) * H_;
    const bf16* da = outa + ((size_t)b * T_ + t) * H_;
    const int tid = threadIdx.x;
    __shared__ float red[256][4];
    float s0 = 0.f, s1 = 0.f, s2 = 0.f, s3 = 0.f;
    for (int k = tid; k < H_; k += 256) {
        const float w0 = Wref[k];
        const float w1 = Wref[H_ + k];
        const float e = bf2f(de[k]);
        const float a = bf2f(da[k]);
        s0 += e * w0; s1 += e * w1; s2 += a * w0; s3 += a * w1;
    }
    red[tid][0] = s0; red[tid][1] = s1; red[tid][2] = s2; red[tid][3] = s3;
    __syncthreads();
    for (int off = 128; off > 0; off >>= 1) {
        if (tid < off) {
            red[tid][0] += red[tid + off][0];
            red[tid][1] += red[tid + off][1];
            red[tid][2] += red[tid + off][2];
            red[tid][3] += red[tid + off][3];
        }
        __syncthreads();
    }
    const float br0 = bref[0], br1 = bref[1];
    const float xe0 = red[0][0] + br0, xe1 = red[0][1] + br1;
    const float xa0 = red[0][2] + br0, xa1 = red[0][3] + br1;
    const float me = fmaxf(xe0, xe1);
    const float ee0 = expf(xe0 - me), ee1 = expf(xe1 - me);
    const float pe0 = ee0 / (ee0 + ee1), pe1 = ee1 / (ee0 + ee1);
    const float ma = fmaxf(xa0, xa1);
    const float ea0 = expf(xa0 - ma), ea1 = expf(xa1 - ma);
    const float pa0 = ea0 / (ea0 + ea1), pa1 = ea1 / (ea0 + ea1);

    const bf16* ei = enc + ((size_t)b * L_ + cd[r]) * H_;
    const bf16* ea = enc + ((size_t)b * L_ + ca[r]) * H_;
    for (int h = tid; h < H_; h += 256) {
        const float vi = bf2f(ei[h]);
        const float va = bf2f(ea[h]);
        ced[(size_t)r * H_ + h] = f2bf(pe0 * vi + pe1 * va);
        cac[(size_t)r * H_ + h] = f2bf(pa0 * vi + pa1 * va);
    }
}

// ---------------------------------------------------------------------------
// Attention over L=191
// ---------------------------------------------------------------------------
__global__ __launch_bounds__(256) void attn_kernel(const bf16* __restrict__ q,
                                                   const bf16* __restrict__ enc,
                                                   bf16* __restrict__ app)
{
    const int r = blockIdx.x;
    const int b = r / TM1_;
    const int tid = threadIdx.x;
    __shared__ float qs[H_];
    __shared__ float p[L_ + 1];
    __shared__ float red[256];
    const bf16* qrow = q + (size_t)r * H_;
    for (int h = tid; h < H_; h += 256) qs[h] = bf2f(qrow[h]);
    __syncthreads();
    const bf16* eb = enc + (size_t)b * L_ * H_;
    float myv = -1e30f;
    if (tid < L_) {
        const unsigned* er = (const unsigned*)(eb + (size_t)tid * H_);
        float s = 0.f;
        for (int k2 = 0; k2 < H_ / 2; ++k2) {
            const unsigned u = er[k2];
            s += qs[2 * k2] * uslo(u) + qs[2 * k2 + 1] * ushi(u);
        }
        p[tid] = s;
        myv = s;
    }
    red[tid] = myv;
    __syncthreads();
    for (int off = 128; off > 0; off >>= 1) {
        if (tid < off) red[tid] = fmaxf(red[tid], red[tid + off]);
        __syncthreads();
    }
    const float m = red[0];
    __syncthreads();
    float e = 0.f;
    if (tid < L_) e = expf(p[tid] - m);
    red[tid] = e;
    __syncthreads();
    for (int off = 128; off > 0; off >>= 1) {
        if (tid < off) red[tid] += red[tid + off];
        __syncthreads();
    }
    const float invZ = 1.f / red[0];
    __syncthreads();
    if (tid < L_) p[tid] = e * invZ;
    __syncthreads();
    for (int h = tid; h < H_; h += 256) {
        float s = 0.f;
        for (int l = 0; l < L_; ++l) s += p[l] * bf2f(eb[(size_t)l * H_ + h]);
        app[(size_t)r * H_ + h] = f2bf(s);
    }
}

// feat_e = [dec_e, dec_a, app, ced, cw]; feat_a = [dec_a, dec_e, app, cac, cw]
__global__ void feat_kernel(const bf16* __restrict__ oute, const bf16* __restrict__ outa,
                            const bf16* __restrict__ app, const bf16* __restrict__ ced,
                            const bf16* __restrict__ cac, const bf16* __restrict__ cw,
                            bf16* __restrict__ fe, bf16* __restrict__ fa)
{
    const int r = blockIdx.x;
    const int b = r / TM1_;
    const int t = r % TM1_;
    const unsigned* de  = (const unsigned*)(oute + ((size_t)b * T_ + t) * H_);
    const unsigned* da  = (const unsigned*)(outa + ((size_t)b * T_ + t) * H_);
    const unsigned* ap  = (const unsigned*)(app + (size_t)r * H_);
    const unsigned* ce  = (const unsigned*)(ced + (size_t)r * H_);
    const unsigned* cA  = (const unsigned*)(cac + (size_t)r * H_);
    const unsigned* cwp = (const unsigned*)(cw + (size_t)r * H_);
    unsigned* pfe = (unsigned*)(fe + (size_t)r * K5_);
    unsigned* pfa = (unsigned*)(fa + (size_t)r * K5_);
    const int HW = H_ / 2;
    for (int h = threadIdx.x; h < HW; h += 256) {
        const unsigned ve = de[h], va = da[h], vap = ap[h], vce = ce[h], vca = cA[h], vcw = cwp[h];
        pfe[h] = ve;  pfe[HW + h] = va;  pfe[2 * HW + h] = vap; pfe[3 * HW + h] = vce; pfe[4 * HW + h] = vcw;
        pfa[h] = va;  pfa[HW + h] = ve;  pfa[2 * HW + h] = vap; pfa[3 * HW + h] = vca; pfa[4 * HW + h] = vcw;
    }
}

// In-place log-softmax over f32 rows (edit head, N=30522), online max+sum pass
__global__ __launch_bounds__(1024) void logsoftmax_edit_kernel(float* __restrict__ out)
{
    float* row = out + (size_t)blockIdx.x * V_;
    const int tid = threadIdx.x;
    __shared__ float redm[1024];
    __shared__ float reds[1024];
    float m = -1e30f, s = 0.f;
    for (int i = tid; i < V_; i += 1024) {
        const float x = row[i];
        if (x > m) { s = s * expf(m - x) + 1.f; m = x; }
        else s += expf(x - m);
    }
    redm[tid] = m; reds[tid] = s;
    __syncthreads();
    for (int off = 512; off > 0; off >>= 1) {
        if (tid < off) {
            const float m2 = redm[tid + off], s2 = reds[tid + off];
            const float mn = fmaxf(redm[tid], m2);
            reds[tid] = reds[tid] * expf(redm[tid] - mn) + s2 * expf(m2 - mn);
            redm[tid] = mn;
        }
        __syncthreads();
    }
    const float lz = redm[0] + logf(reds[0]);
    __syncthreads();
    for (int i = tid; i < V_; i += 1024) row[i] = row[i] - lz;
}

// Act head log-softmax: f32 in -> f32 out
__global__ __launch_bounds__(256) void logsoftmax_act_kernel(const float* __restrict__ in,
                                                             float* __restrict__ out)
{
    const float* row = in + (size_t)blockIdx.x * AV_;
    float* orow = out + (size_t)blockIdx.x * AV_;
    const int tid = threadIdx.x;
    __shared__ float red[256];
    float m = -1e30f;
    if (tid < AV_) m = row[tid];
    red[tid] = m;
    __syncthreads();
    for (int off = 128; off > 0; off >>= 1) {
        if (tid < off) red[tid] = fmaxf(red[tid], red[tid + off]);
        __syncthreads();
    }
    m = red[0];
    __syncthreads();
    float s = 0.f;
    if (tid < AV_) s = expf(row[tid] - m);
    red[tid] = s;
    __syncthreads();
    for (int off = 128; off > 0; off >>= 1) {
        if (tid < off) red[tid] += red[tid + off];
        __syncthreads();
    }
    const float lz = m + logf(red[0]);
    if (tid < AV_) orow[tid] = row[tid] - lz;
}

// ---------------------------------------------------------------------------
extern "C" void kernel_launch(void* const* d_in, const int* in_sizes, int n_in,
                              void* d_out, int out_size, void* d_ws, size_t ws_size,
                              hipStream_t stream)
{
    const int* input_edits   = (const int*)d_in[0];
    const int* input_actions = (const int*)d_in[1];
    const int* simp_sent     = (const int*)d_in[2];
    const int* org_ids       = (const int*)d_in[3];
    const float* enc_org     = (const float*)d_in[4];
    const float* emb         = (const float*)d_in[5];
    const float* Wih_e = (const float*)d_in[6];
    const float* Whh_e = (const float*)d_in[7];
    const float* bih_e = (const float*)d_in[8];
    const float* bhh_e = (const float*)d_in[9];
    const float* Wih_a = (const float*)d_in[10];
    const float* Whh_a = (const float*)d_in[11];
    const float* bih_a = (const float*)d_in[12];
    const float* bhh_a = (const float*)d_in[13];
    const float* Wih_w = (const float*)d_in[14];
    const float* Whh_w = (const float*)d_in[15];
    const float* bih_w = (const float*)d_in[16];
    const float* bhh_w = (const float*)d_in[17];
    const float* W_align = (const float*)d_in[18];
    const float* W_proj  = (const float*)d_in[19];
    const float* W_ref   = (const float*)d_in[20];
    const float* b_ref   = (const float*)d_in[21];
    const float* W_mlp   = (const float*)d_in[22];
    const float* b_mlp   = (const float*)d_in[23];
    const float* W_act   = (const float*)d_in[24];
    const float* b_act   = (const float*)d_in[25];
    const float* W_out   = (const float*)d_in[26];
    const float* b_out   = (const float*)d_in[27];
    const float* W_outact = (const float*)d_in[28];
    const float* b_outact = (const float*)d_in[29];
    const float* action_mask = (const float*)d_in[30];

    float* out = (float*)d_out;
    float* edit_out = out;                               // (2032, 30522) f32
    float* act_out  = out + (size_t)R_ * V_;             // (2032, 200)   f32

    // Workspace layout
    char* p = (char*)d_ws;
    auto take = [&](size_t bytes) { void* q = (void*)p; p += ((bytes + 255) / 256) * 256; return q; };
    int* cnts = (int*)take(256);
    unsigned short* hbuf = (unsigned short*)take((size_t)3 * 2 * B_ * H_ * 2);
    bf16* xe   = (bf16*)take((size_t)B_ * T_ * H_ * 2);
    bf16* xa   = (bf16*)take((size_t)B_ * T_ * H_ * 2);
    bf16* xw   = (bf16*)take((size_t)B_ * S_ * H_ * 2);
    bf16* pxe  = (bf16*)take((size_t)B_ * T_ * G4_ * 2);
    bf16* pxa  = (bf16*)take((size_t)B_ * T_ * G4_ * 2);
    bf16* pxw  = (bf16*)take((size_t)B_ * S_ * G4_ * 2);
    bf16* oute = (bf16*)take((size_t)B_ * T_ * H_ * 2);
    bf16* outa = (bf16*)take((size_t)B_ * T_ * H_ * 2);
    bf16* outw = (bf16*)take((size_t)B_ * S_ * H_ * 2);
    bf16* enc  = (bf16*)take((size_t)B_ * L_ * H_ * 2);
    bf16* cw   = (bf16*)take((size_t)R_ * H_ * 2);
    bf16* ced  = (bf16*)take((size_t)R_ * H_ * 2);
    bf16* cac  = (bf16*)take((size_t)R_ * H_ * 2);
    bf16* qb   = (bf16*)take((size_t)R_ * H_ * 2);
    bf16* app  = (bf16*)take((size_t)R_ * H_ * 2);
    bf16* fe   = (bf16*)take((size_t)R_ * K5_ * 2);
    bf16* fa   = (bf16*)take((size_t)R_ * K5_ * 2);
    bf16* he   = (bf16*)take((size_t)R_ * H_ * 2);
    bf16* ha   = (bf16*)take((size_t)R_ * H_ * 2);
    int*  cd   = (int*)take((size_t)R_ * 4);
    int*  ci   = (int*)take((size_t)R_ * 4);
    int*  ca   = (int*)take((size_t)R_ * 4);
    float* actbuf = (float*)take((size_t)R_ * AV_ * 4);

    // 0. Zero barrier counters
    hipMemsetAsync(cnts, 0, 256, stream);

    // 1. Embedding gathers
    gather_rows_kernel<<<B_ * T_, 256, 0, stream>>>(input_edits, emb, xe);
    gather_rows_kernel<<<B_ * T_, 256, 0, stream>>>(input_actions, emb, xa);
    gather_rows_kernel<<<B_ * S_, 256, 0, stream>>>(simp_sent, emb, xw);

    // 2. px = x@Wih^T + bih + bhh (MFMA)
    dim3 gpx((B_ * T_ + 127) / 128, (G4_ + 127) / 128);
    gemm_mfma<bf16, float><<<gpx, 256, 0, stream>>>(xe, Wih_e, bih_e, bhh_e, pxe, nullptr, B_ * T_, G4_, H_, 0, 0, H_);
    gemm_mfma<bf16, float><<<gpx, 256, 0, stream>>>(xa, Wih_a, bih_a, bhh_a, pxa, nullptr, B_ * T_, G4_, H_, 0, 0, H_);
    dim3 gpxw((B_ * S_ + 127) / 128, (G4_ + 127) / 128);
    gemm_mfma<bf16, float><<<gpxw, 256, 0, stream>>>(xw, Wih_w, bih_w, bhh_w, pxw, nullptr, B_ * S_, G4_, H_, 0, 0, H_);

    // 3. enc = tanh(enc_org @ W_align^T)[:, 1:]
    dim3 genc((B_ * L_ + 127) / 128, (H_ + 127) / 128);
    gemm_mfma<float, float><<<genc, 256, 0, stream>>>(enc_org, W_align, nullptr, nullptr, enc, nullptr, B_ * L_, H_, H_, 1, L_, H_);

    // 4. Counters scan
    counters_kernel<<<1, 64, 0, stream>>>(input_edits, org_ids, cd, ci, ca);

    // 5. Persistent cooperative LSTMs
    lstm_mfma_kernel<<<3 * NB_, 256, 0, stream>>>(pxe, pxa, pxw, Whh_e, Whh_a, Whh_w,
                                                  oute, outa, outw, hbuf, cnts);

    // 6. c_word gather
    gather_cword_kernel<<<R_, 256, 0, stream>>>(outw, ci, cw);

    // 7. wref mixing
    ref_combine_kernel<<<R_, 256, 0, stream>>>(oute, outa, enc, W_ref, b_ref, cd, ca, ced, cac);

    // 8. q = c_word @ W_proj^T
    dim3 gproj((R_ + 127) / 128, (H_ + 127) / 128);
    gemm_mfma<bf16, float><<<gproj, 256, 0, stream>>>(cw, W_proj, nullptr, nullptr, qb, nullptr, R_, H_, H_, 0, 0, H_);

    // 9. attention
    attn_kernel<<<R_, 256, 0, stream>>>(qb, enc, app);

    // 10. feature concat
    feat_kernel<<<R_, 256, 0, stream>>>(oute, outa, app, ced, cac, cw, fe, fa);

    // 11. hidden layers (tanh, MFMA, K=3840)
    gemm_mfma<bf16, float><<<gproj, 256, 0, stream>>>(fe, W_mlp, b_mlp, nullptr, he, nullptr, R_, H_, K5_, 1, 0, K5_);
    gemm_mfma<bf16, float><<<gproj, 256, 0, stream>>>(fa, W_act, b_act, nullptr, ha, nullptr, R_, H_, K5_, 1, 0, K5_);

    // 12. act head + log-softmax
    dim3 gact((R_ + 127) / 128, (AV_ + 127) / 128);
    gemm_mfma<bf16, float><<<gact, 256, 0, stream>>>(ha, W_outact, b_outact, action_mask, nullptr, actbuf, R_, AV_, H_, 0, 0, H_);
    logsoftmax_act_kernel<<<R_, 256, 0, stream>>>(actbuf, act_out);

    // 13. edit head + in-place log-softmax
    dim3 gedit((R_ + 127) / 128, (V_ + 127) / 128);
    gemm_mfma<bf16, float><<<gedit, 256, 0, stream>>>(he, W_out, b_out, nullptr, nullptr, edit_out, R_, V_, H_, 0, 0, H_);
    logsoftmax_edit_kernel<<<R_, 1024, 0, stream>>>(edit_out);
}

// Round 9
// 2610.794 us; speedup vs baseline: 12.3695x; 1.1434x over previous
//
#include <hip/hip_runtime.h>
#include <hip/hip_bf16.h>

typedef __hip_bfloat16 bf16;

// Problem dims
#define B_    16
#define T_    128
#define S_    192
#define H_    768
#define G4_   3072      // 4*H
#define V_    30522
#define AV_   200
#define L_    191       // L_SRC-1
#define TM1_  127       // T-1
#define R_    2032      // B*(T-1)
#define K5_   3840      // 5*H
#define NB_   48        // blocks per LSTM (persistent)
#define HSL_  16        // h-slice per block (768/48)

typedef short bf16x8_t __attribute__((ext_vector_type(8)));
typedef float f32x4_t  __attribute__((ext_vector_type(4)));

__device__ __forceinline__ float bf2f(bf16 v) { return __bfloat162float(v); }
__device__ __forceinline__ bf16  f2bf(float v) { return __float2bfloat16(v); }
__device__ __forceinline__ unsigned short f2us(float v) { bf16 h = f2bf(v); return *reinterpret_cast<unsigned short*>(&h); }
__device__ __forceinline__ float uslo(unsigned u) { union { unsigned i; float f; } x; x.i = u << 16; return x.f; }
__device__ __forceinline__ float ushi(unsigned u) { union { unsigned i; float f; } x; x.i = u & 0xffff0000u; return x.f; }
__device__ __forceinline__ float us2f(unsigned short u) { union { unsigned i; float f; } x; x.i = ((unsigned)u) << 16; return x.f; }
__device__ __forceinline__ float sigm(float x) { return 1.0f / (1.0f + expf(-x)); }

// 8-element bf16 fragment loads (optionally converting from f32)
__device__ __forceinline__ bf16x8_t ld8bf(const bf16* p) { return *(const bf16x8_t*)p; }
__device__ __forceinline__ bf16x8_t ld8bf(const float* p) {
    float4 a = *(const float4*)p;
    float4 b = *(const float4*)(p + 4);
    bf16x8_t r;
    r[0] = (short)f2us(a.x); r[1] = (short)f2us(a.y); r[2] = (short)f2us(a.z); r[3] = (short)f2us(a.w);
    r[4] = (short)f2us(b.x); r[5] = (short)f2us(b.y); r[6] = (short)f2us(b.z); r[7] = (short)f2us(b.w);
    return r;
}

// ---------------------------------------------------------------------------
// MFMA GEMM: C[M,N] = act( A[M,K] * W[N,K]^T + bias1 + bias2 )
// 128x128 tile, 256 threads (4 waves in 2x2), K-step 32, bf16 staging in LDS.
// ---------------------------------------------------------------------------
template <typename TA, typename TW>
__global__ __launch_bounds__(256) void gemm_mfma(
    const TA* __restrict__ A, const TW* __restrict__ W,
    const float* __restrict__ bias1, const float* __restrict__ bias2,
    bf16* __restrict__ Ch, float* __restrict__ Cf,
    int M, int N, int K, int act, int rowdiv, int lda)
{
    __shared__ short As[128][40];
    __shared__ short Ws[128][40];
    const int tid = threadIdx.x;
    const int wave = tid >> 6, lane = tid & 63;
    const int mw = (wave >> 1) * 64, nw = (wave & 1) * 64;
    const int bm = blockIdx.x * 128, bn = blockIdx.y * 128;

    const int sr = tid >> 2;
    const int sc = (tid & 3) * 8;

    f32x4_t acc[4][4];
#pragma unroll
    for (int mi = 0; mi < 4; ++mi)
#pragma unroll
        for (int ni = 0; ni < 4; ++ni) acc[mi][ni] = (f32x4_t){0.f, 0.f, 0.f, 0.f};

    const int fr = lane & 15;
    const int fk = (lane >> 4) * 8;

    for (int k0 = 0; k0 < K; k0 += 32) {
#pragma unroll
        for (int c = 0; c < 2; ++c) {
            const int row = sr + c * 64;
            int ga = bm + row; if (ga > M - 1) ga = M - 1;
            const int ra = (rowdiv > 0) ? (ga + ga / rowdiv + 1) : ga;
            *(bf16x8_t*)&As[row][sc] = ld8bf(A + (size_t)ra * lda + k0 + sc);
            int gw = bn + row; if (gw > N - 1) gw = N - 1;
            *(bf16x8_t*)&Ws[row][sc] = ld8bf(W + (size_t)gw * K + k0 + sc);
        }
        __syncthreads();
        bf16x8_t af[4], wf[4];
#pragma unroll
        for (int i = 0; i < 4; ++i) af[i] = *(const bf16x8_t*)&As[mw + i * 16 + fr][fk];
#pragma unroll
        for (int i = 0; i < 4; ++i) wf[i] = *(const bf16x8_t*)&Ws[nw + i * 16 + fr][fk];
#pragma unroll
        for (int mi = 0; mi < 4; ++mi)
#pragma unroll
            for (int ni = 0; ni < 4; ++ni)
                acc[mi][ni] = __builtin_amdgcn_mfma_f32_16x16x32_bf16(af[mi], wf[ni], acc[mi][ni], 0, 0, 0);
        __syncthreads();
    }

    const int cl = lane & 15;
    const int rg = (lane >> 4) * 4;
#pragma unroll
    for (int mi = 0; mi < 4; ++mi) {
#pragma unroll
        for (int ni = 0; ni < 4; ++ni) {
            const int col = bn + nw + ni * 16 + cl;
            if (col >= N) continue;
#pragma unroll
            for (int j = 0; j < 4; ++j) {
                const int row = bm + mw + mi * 16 + rg + j;
                if (row >= M) continue;
                float v = acc[mi][ni][j];
                if (bias1) v += bias1[col];
                if (bias2) v += bias2[col];
                if (act == 1) v = tanhf(v);
                if (Ch) Ch[(size_t)row * N + col] = f2bf(v);
                else    Cf[(size_t)row * N + col] = v;
            }
        }
    }
}

// ---------------------------------------------------------------------------
// Persistent cooperative LSTM. Grid = 3 LSTMs x 48 blocks, 256 threads.
// h exchange via device-coherent (agent-scope relaxed) accesses; per-step
// barrier = per-block FLAG STORES (no RMW contention) + parallel wave poll.
// ---------------------------------------------------------------------------
__global__ __launch_bounds__(256) void lstm_mfma_kernel(
    const bf16* __restrict__ pxe, const bf16* __restrict__ pxa, const bf16* __restrict__ pxw,
    const float* __restrict__ We, const float* __restrict__ Wa, const float* __restrict__ Ww,
    bf16* __restrict__ oute, bf16* __restrict__ outa, bf16* __restrict__ outw,
    unsigned short* __restrict__ hbuf, int* __restrict__ flags)
{
    const int which = blockIdx.x / NB_;
    const int nb = blockIdx.x % NB_;
    const bf16* px; const float* W; bf16* out; int Tn;
    if (which == 0)      { px = pxe; W = We; out = oute; Tn = T_; }
    else if (which == 1) { px = pxa; W = Wa; out = outa; Tn = T_; }
    else                 { px = pxw; W = Ww; out = outw; Tn = S_; }
    unsigned short* hG = hbuf + (size_t)which * (2 * B_ * H_);
    int* flg = flags + which * 64;   // 48 packed flags per LSTM (256B region)

    const int tid = threadIdx.x;
    const int wv = tid >> 6;        // wave index = gate (i,f,g,o)
    const int lane = tid & 63;
    const int so = nb * HSL_;

    __shared__ unsigned short hL[16][776];        // h (bf16 bits), row-padded +8
    __shared__ float gS[4][16][17];               // gate exchange [gate][hl][batch]
    __shared__ unsigned short oring[8][16][16];   // out ring [step&7][batch][hl]

    // persistent A-fragments: lane l -> row (l&15), k = kb*32 + (l>>4)*8 + i
    bf16x8_t Afrag[24];
    {
        const int m = lane & 15;
        const int kb8 = (lane >> 4) * 8;
        const float* wrow = W + (size_t)(wv * H_ + so + m) * H_ + kb8;
#pragma unroll
        for (int kb = 0; kb < 24; ++kb) {
            float4 f0 = *(const float4*)(wrow + kb * 32);
            float4 f1 = *(const float4*)(wrow + kb * 32 + 4);
            bf16x8_t a;
            a[0] = (short)f2us(f0.x); a[1] = (short)f2us(f0.y);
            a[2] = (short)f2us(f0.z); a[3] = (short)f2us(f0.w);
            a[4] = (short)f2us(f1.x); a[5] = (short)f2us(f1.y);
            a[6] = (short)f2us(f1.z); a[7] = (short)f2us(f1.w);
            Afrag[kb] = a;
        }
    }

    // h_0 = 0
    for (int i = tid; i < 16 * 776; i += 256) ((unsigned short*)hL)[i] = 0;

    const int cb = tid >> 4;
    const int chl = tid & 15;
    float c = 0.f;

    const int bn = lane & 15;        // B-frag col = batch
    const int bk = (lane >> 4) * 8;  // B-frag k sub-offset

    int cur = 0;
    for (int step = 0; step < Tn; ++step) {
        if (step > 0) {
            // device-coherent h read, 8B-wide (bypasses stale L1/L2)
            const unsigned long long* hsrc =
                (const unsigned long long*)(hG + (size_t)cur * (B_ * H_));
            for (int i = tid; i < B_ * H_ / 4; i += 256) {
                const unsigned long long v =
                    __hip_atomic_load(hsrc + i, __ATOMIC_RELAXED, __HIP_MEMORY_SCOPE_AGENT);
                const int bb = i / (H_ / 4);
                const int cc = i - bb * (H_ / 4);
                ((unsigned long long*)&hL[bb][0])[cc] = v;
            }
        }
        __syncthreads();

        f32x4_t acc = {0.f, 0.f, 0.f, 0.f};
#pragma unroll
        for (int kb = 0; kb < 24; ++kb) {
            bf16x8_t bfr = *(const bf16x8_t*)&hL[bn][kb * 32 + bk];
            acc = __builtin_amdgcn_mfma_f32_16x16x32_bf16(Afrag[kb], bfr, acc, 0, 0, 0);
        }
        {
            const int m0 = (lane >> 4) * 4;
#pragma unroll
            for (int j = 0; j < 4; ++j) gS[wv][m0 + j][bn] = acc[j];
        }
        __syncthreads();

        // cell update
        {
            const bf16* pxt = px + ((size_t)cb * Tn + step) * G4_ + so + chl;
            const float gi = gS[0][chl][cb] + bf2f(pxt[0]);
            const float gf = gS[1][chl][cb] + bf2f(pxt[H_]);
            const float gg = gS[2][chl][cb] + bf2f(pxt[2 * H_]);
            const float go = gS[3][chl][cb] + bf2f(pxt[3 * H_]);
            const float cn = sigm(gf) * c + sigm(gi) * tanhf(gg);
            const float hn = sigm(go) * tanhf(cn);
            c = cn;
            oring[step & 7][cb][chl] = f2us(hn);
            // device-coherent h write (write-through to coherence point)
            __hip_atomic_store(&hG[(size_t)(cur ^ 1) * (B_ * H_) + cb * H_ + so + chl],
                               f2us(hn), __ATOMIC_RELAXED, __HIP_MEMORY_SCOPE_AGENT);
        }
        // flush out ring every 8 steps (plain cached stores; visible at kernel end)
        if ((step & 7) == 7 || step == Tn - 1) {
            const int base = step & ~7;
            const int cnt8 = (step & 7) + 1;
            for (int s2 = 0; s2 < cnt8; ++s2)
                out[((size_t)cb * Tn + base + s2) * H_ + so + chl] =
                    *reinterpret_cast<const bf16*>(&oring[s2][cb][chl]);
        }

        if (step + 1 < Tn) {
            __syncthreads();   // drains vmcnt -> h stores globally complete
            const int target = step + 1;
            if (tid == 0)
                __hip_atomic_store(&flg[nb], target, __ATOMIC_RELAXED, __HIP_MEMORY_SCOPE_AGENT);
            if (tid < 64 && lane < NB_) {
                long guard = 0;
                while (__hip_atomic_load(&flg[lane], __ATOMIC_RELAXED, __HIP_MEMORY_SCOPE_AGENT) < target) {
                    __builtin_amdgcn_s_sleep(1);
                    if (++guard > 50000000L) break;   // liveness guard
                }
            }
            __syncthreads();
        }
        cur ^= 1;
    }
}

// ---------------------------------------------------------------------------
// Row gather + convert: out[r][:] = bf16(emb[ids[r]][:])
// ---------------------------------------------------------------------------
__global__ void gather_rows_kernel(const int* __restrict__ ids,
                                   const float* __restrict__ emb,
                                   bf16* __restrict__ out)
{
    const int r = blockIdx.x;
    const float4* src = (const float4*)(emb + (size_t)ids[r] * H_);
    ushort4* dst = (ushort4*)(out + (size_t)r * H_);
    for (int h = threadIdx.x; h < H_ / 4; h += 256) {
        float4 v = src[h];
        ushort4 o;
        o.x = f2us(v.x); o.y = f2us(v.y); o.z = f2us(v.z); o.w = f2us(v.w);
        dst[h] = o;
    }
}

// ---------------------------------------------------------------------------
// Counters scan
// ---------------------------------------------------------------------------
__global__ void counters_kernel(const int* __restrict__ edits, const int* __restrict__ org,
                                int* __restrict__ cd, int* __restrict__ ci, int* __restrict__ ca)
{
    const int b = threadIdx.x;
    if (b >= B_) return;
    int vd = 0, vi = 0, va = 0;
    for (int t = 0; t < TM1_; ++t) {
        cd[b * TM1_ + t] = vd; ci[b * TM1_ + t] = vi; ca[b * TM1_ + t] = va;
        const int g = edits[b * T_ + t + 1];
        const int vd2 = vd + ((g == 3 || g == 4) ? 1 : 0);
        const int alive = (g != 4 && g != 2 && g != 0) ? 1 : 0;
        const int vi2 = vi + alive;
        int nxt = va + 1; if (nxt > L_ - 1) nxt = L_ - 1;
        const int tok = org[b * L_ + nxt];
        const bool cond = alive && (g != 3) && (va + 1 < L_) && (tok == 103 || tok == 3 || tok == 4);
        const int va2 = cond ? (va + 1) : max(vd2, va);
        vd = vd2; vi = vi2; va = va2;
    }
}

// c_word[r][:] = out_w[b][ci[r]][:]
__global__ void gather_cword_kernel(const bf16* __restrict__ outw, const int* __restrict__ ci,
                                    bf16* __restrict__ cw)
{
    const int r = blockIdx.x;
    const int b = r / TM1_;
    const unsigned* src = (const unsigned*)(outw + ((size_t)b * S_ + ci[r]) * H_);
    unsigned* dst = (unsigned*)(cw + (size_t)r * H_);
    for (int h = threadIdx.x; h < H_ / 2; h += 256) dst[h] = src[h];
}

// ---------------------------------------------------------------------------
// wref softmax (2-way) + mix c_input/c_anno
// ---------------------------------------------------------------------------
__global__ __launch_bounds__(256) void ref_combine_kernel(
    const bf16* __restrict__ oute, const bf16* __restrict__ outa, const bf16* __restrict__ enc,
    const float* __restrict__ Wref, const float* __restrict__ bref,
    const int* __restrict__ cd, const int* __restrict__ ca,
    bf16* __restrict__ ced, bf16* __restrict__ cac)
{
    const int r = blockIdx.x;
    const int b = r / TM1_;
    const int t = r % TM1_;
    const bf16* de = oute + ((size_t)b * T_ + t) * H_;
    const bf16* da = outa + ((size_t)b * T_ + t) * H_;
    const int tid = threadIdx.x;
    __shared__ float red[256][4];
    float s0 = 0.f, s1 = 0.f, s2 = 0.f, s3 = 0.f;
    for (int k = tid; k < H_; k += 256) {
        const float w0 = Wref[k];
        const float w1 = Wref[H_ + k];
        const float e = bf2f(de[k]);
        const float a = bf2f(da[k]);
        s0 += e * w0; s1 += e * w1; s2 += a * w0; s3 += a * w1;
    }
    red[tid][0] = s0; red[tid][1] = s1; red[tid][2] = s2; red[tid][3] = s3;
    __syncthreads();
    for (int off = 128; off > 0; off >>= 1) {
        if (tid < off) {
            red[tid][0] += red[tid + off][0];
            red[tid][1] += red[tid + off][1];
            red[tid][2] += red[tid + off][2];
            red[tid][3] += red[tid + off][3];
        }
        __syncthreads();
    }
    const float br0 = bref[0], br1 = bref[1];
    const float xe0 = red[0][0] + br0, xe1 = red[0][1] + br1;
    const float xa0 = red[0][2] + br0, xa1 = red[0][3] + br1;
    const float me = fmaxf(xe0, xe1);
    const float ee0 = expf(xe0 - me), ee1 = expf(xe1 - me);
    const float pe0 = ee0 / (ee0 + ee1), pe1 = ee1 / (ee0 + ee1);
    const float ma = fmaxf(xa0, xa1);
    const float ea0 = expf(xa0 - ma), ea1 = expf(xa1 - ma);
    const float pa0 = ea0 / (ea0 + ea1), pa1 = ea1 / (ea0 + ea1);

    const bf16* ei = enc + ((size_t)b * L_ + cd[r]) * H_;
    const bf16* ea = enc + ((size_t)b * L_ + ca[r]) * H_;
    for (int h = tid; h < H_; h += 256) {
        const float vi = bf2f(ei[h]);
        const float va = bf2f(ea[h]);
        ced[(size_t)r * H_ + h] = f2bf(pe0 * vi + pe1 * va);
        cac[(size_t)r * H_ + h] = f2bf(pa0 * vi + pa1 * va);
    }
}

// ---------------------------------------------------------------------------
// Attention over L=191
// ---------------------------------------------------------------------------
__global__ __launch_bounds__(256) void attn_kernel(const bf16* __restrict__ q,
                                                   const bf16* __restrict__ enc,
                                                   bf16* __restrict__ app)
{
    const int r = blockIdx.x;
    const int b = r / TM1_;
    const int tid = threadIdx.x;
    __shared__ float qs[H_];
    __shared__ float p[L_ + 1];
    __shared__ float red[256];
    const bf16* qrow = q + (size_t)r * H_;
    for (int h = tid; h < H_; h += 256) qs[h] = bf2f(qrow[h]);
    __syncthreads();
    const bf16* eb = enc + (size_t)b * L_ * H_;
    float myv = -1e30f;
    if (tid < L_) {
        const unsigned* er = (const unsigned*)(eb + (size_t)tid * H_);
        float s = 0.f;
        for (int k2 = 0; k2 < H_ / 2; ++k2) {
            const unsigned u = er[k2];
            s += qs[2 * k2] * uslo(u) + qs[2 * k2 + 1] * ushi(u);
        }
        p[tid] = s;
        myv = s;
    }
    red[tid] = myv;
    __syncthreads();
    for (int off = 128; off > 0; off >>= 1) {
        if (tid < off) red[tid] = fmaxf(red[tid], red[tid + off]);
        __syncthreads();
    }
    const float m = red[0];
    __syncthreads();
    float e = 0.f;
    if (tid < L_) e = expf(p[tid] - m);
    red[tid] = e;
    __syncthreads();
    for (int off = 128; off > 0; off >>= 1) {
        if (tid < off) red[tid] += red[tid + off];
        __syncthreads();
    }
    const float invZ = 1.f / red[0];
    __syncthreads();
    if (tid < L_) p[tid] = e * invZ;
    __syncthreads();
    for (int h = tid; h < H_; h += 256) {
        float s = 0.f;
        for (int l = 0; l < L_; ++l) s += p[l] * bf2f(eb[(size_t)l * H_ + h]);
        app[(size_t)r * H_ + h] = f2bf(s);
    }
}

// feat_e = [dec_e, dec_a, app, ced, cw]; feat_a = [dec_a, dec_e, app, cac, cw]
__global__ void feat_kernel(const bf16* __restrict__ oute, const bf16* __restrict__ outa,
                            const bf16* __restrict__ app, const bf16* __restrict__ ced,
                            const bf16* __restrict__ cac, const bf16* __restrict__ cw,
                            bf16* __restrict__ fe, bf16* __restrict__ fa)
{
    const int r = blockIdx.x;
    const int b = r / TM1_;
    const int t = r % TM1_;
    const unsigned* de  = (const unsigned*)(oute + ((size_t)b * T_ + t) * H_);
    const unsigned* da  = (const unsigned*)(outa + ((size_t)b * T_ + t) * H_);
    const unsigned* ap  = (const unsigned*)(app + (size_t)r * H_);
    const unsigned* ce  = (const unsigned*)(ced + (size_t)r * H_);
    const unsigned* cA  = (const unsigned*)(cac + (size_t)r * H_);
    const unsigned* cwp = (const unsigned*)(cw + (size_t)r * H_);
    unsigned* pfe = (unsigned*)(fe + (size_t)r * K5_);
    unsigned* pfa = (unsigned*)(fa + (size_t)r * K5_);
    const int HW = H_ / 2;
    for (int h = threadIdx.x; h < HW; h += 256) {
        const unsigned ve = de[h], va = da[h], vap = ap[h], vce = ce[h], vca = cA[h], vcw = cwp[h];
        pfe[h] = ve;  pfe[HW + h] = va;  pfe[2 * HW + h] = vap; pfe[3 * HW + h] = vce; pfe[4 * HW + h] = vcw;
        pfa[h] = va;  pfa[HW + h] = ve;  pfa[2 * HW + h] = vap; pfa[3 * HW + h] = vca; pfa[4 * HW + h] = vcw;
    }
}

// In-place log-softmax over f32 rows (edit head, N=30522), online max+sum pass
__global__ __launch_bounds__(1024) void logsoftmax_edit_kernel(float* __restrict__ out)
{
    float* row = out + (size_t)blockIdx.x * V_;
    const int tid = threadIdx.x;
    __shared__ float redm[1024];
    __shared__ float reds[1024];
    float m = -1e30f, s = 0.f;
    for (int i = tid; i < V_; i += 1024) {
        const float x = row[i];
        if (x > m) { s = s * expf(m - x) + 1.f; m = x; }
        else s += expf(x - m);
    }
    redm[tid] = m; reds[tid] = s;
    __syncthreads();
    for (int off = 512; off > 0; off >>= 1) {
        if (tid < off) {
            const float m2 = redm[tid + off], s2 = reds[tid + off];
            const float mn = fmaxf(redm[tid], m2);
            reds[tid] = reds[tid] * expf(redm[tid] - mn) + s2 * expf(m2 - mn);
            redm[tid] = mn;
        }
        __syncthreads();
    }
    const float lz = redm[0] + logf(reds[0]);
    __syncthreads();
    for (int i = tid; i < V_; i += 1024) row[i] = row[i] - lz;
}

// Act head log-softmax: f32 in -> f32 out
__global__ __launch_bounds__(256) void logsoftmax_act_kernel(const float* __restrict__ in,
                                                             float* __restrict__ out)
{
    const float* row = in + (size_t)blockIdx.x * AV_;
    float* orow = out + (size_t)blockIdx.x * AV_;
    const int tid = threadIdx.x;
    __shared__ float red[256];
    float m = -1e30f;
    if (tid < AV_) m = row[tid];
    red[tid] = m;
    __syncthreads();
    for (int off = 128; off > 0; off >>= 1) {
        if (tid < off) red[tid] = fmaxf(red[tid], red[tid + off]);
        __syncthreads();
    }
    m = red[0];
    __syncthreads();
    float s = 0.f;
    if (tid < AV_) s = expf(row[tid] - m);
    red[tid] = s;
    __syncthreads();
    for (int off = 128; off > 0; off >>= 1) {
        if (tid < off) red[tid] += red[tid + off];
        __syncthreads();
    }
    const float lz = m + logf(red[0]);
    if (tid < AV_) orow[tid] = row[tid] - lz;
}

// ---------------------------------------------------------------------------
extern "C" void kernel_launch(void* const* d_in, const int* in_sizes, int n_in,
                              void* d_out, int out_size, void* d_ws, size_t ws_size,
                              hipStream_t stream)
{
    const int* input_edits   = (const int*)d_in[0];
    const int* input_actions = (const int*)d_in[1];
    const int* simp_sent     = (const int*)d_in[2];
    const int* org_ids       = (const int*)d_in[3];
    const float* enc_org     = (const float*)d_in[4];
    const float* emb         = (const float*)d_in[5];
    const float* Wih_e = (const float*)d_in[6];
    const float* Whh_e = (const float*)d_in[7];
    const float* bih_e = (const float*)d_in[8];
    const float* bhh_e = (const float*)d_in[9];
    const float* Wih_a = (const float*)d_in[10];
    const float* Whh_a = (const float*)d_in[11];
    const float* bih_a = (const float*)d_in[12];
    const float* bhh_a = (const float*)d_in[13];
    const float* Wih_w = (const float*)d_in[14];
    const float* Whh_w = (const float*)d_in[15];
    const float* bih_w = (const float*)d_in[16];
    const float* bhh_w = (const float*)d_in[17];
    const float* W_align = (const float*)d_in[18];
    const float* W_proj  = (const float*)d_in[19];
    const float* W_ref   = (const float*)d_in[20];
    const float* b_ref   = (const float*)d_in[21];
    const float* W_mlp   = (const float*)d_in[22];
    const float* b_mlp   = (const float*)d_in[23];
    const float* W_act   = (const float*)d_in[24];
    const float* b_act   = (const float*)d_in[25];
    const float* W_out   = (const float*)d_in[26];
    const float* b_out   = (const float*)d_in[27];
    const float* W_outact = (const float*)d_in[28];
    const float* b_outact = (const float*)d_in[29];
    const float* action_mask = (const float*)d_in[30];

    float* out = (float*)d_out;
    float* edit_out = out;                               // (2032, 30522) f32
    float* act_out  = out + (size_t)R_ * V_;             // (2032, 200)   f32

    // Workspace layout
    char* p = (char*)d_ws;
    auto take = [&](size_t bytes) { void* q = (void*)p; p += ((bytes + 255) / 256) * 256; return q; };
    int* flags = (int*)take(3 * 256);                    // 3 x 64-int flag arrays
    unsigned short* hbuf = (unsigned short*)take((size_t)3 * 2 * B_ * H_ * 2);
    bf16* xe   = (bf16*)take((size_t)B_ * T_ * H_ * 2);
    bf16* xa   = (bf16*)take((size_t)B_ * T_ * H_ * 2);
    bf16* xw   = (bf16*)take((size_t)B_ * S_ * H_ * 2);
    bf16* pxe  = (bf16*)take((size_t)B_ * T_ * G4_ * 2);
    bf16* pxa  = (bf16*)take((size_t)B_ * T_ * G4_ * 2);
    bf16* pxw  = (bf16*)take((size_t)B_ * S_ * G4_ * 2);
    bf16* oute = (bf16*)take((size_t)B_ * T_ * H_ * 2);
    bf16* outa = (bf16*)take((size_t)B_ * T_ * H_ * 2);
    bf16* outw = (bf16*)take((size_t)B_ * S_ * H_ * 2);
    bf16* enc  = (bf16*)take((size_t)B_ * L_ * H_ * 2);
    bf16* cw   = (bf16*)take((size_t)R_ * H_ * 2);
    bf16* ced  = (bf16*)take((size_t)R_ * H_ * 2);
    bf16* cac  = (bf16*)take((size_t)R_ * H_ * 2);
    bf16* qb   = (bf16*)take((size_t)R_ * H_ * 2);
    bf16* app  = (bf16*)take((size_t)R_ * H_ * 2);
    bf16* fe   = (bf16*)take((size_t)R_ * K5_ * 2);
    bf16* fa   = (bf16*)take((size_t)R_ * K5_ * 2);
    bf16* he   = (bf16*)take((size_t)R_ * H_ * 2);
    bf16* ha   = (bf16*)take((size_t)R_ * H_ * 2);
    int*  cd   = (int*)take((size_t)R_ * 4);
    int*  ci   = (int*)take((size_t)R_ * 4);
    int*  ca   = (int*)take((size_t)R_ * 4);
    float* actbuf = (float*)take((size_t)R_ * AV_ * 4);

    // 0. Zero barrier flags
    hipMemsetAsync(flags, 0, 3 * 256, stream);

    // 1. Embedding gathers
    gather_rows_kernel<<<B_ * T_, 256, 0, stream>>>(input_edits, emb, xe);
    gather_rows_kernel<<<B_ * T_, 256, 0, stream>>>(input_actions, emb, xa);
    gather_rows_kernel<<<B_ * S_, 256, 0, stream>>>(simp_sent, emb, xw);

    // 2. px = x@Wih^T + bih + bhh (MFMA)
    dim3 gpx((B_ * T_ + 127) / 128, (G4_ + 127) / 128);
    gemm_mfma<bf16, float><<<gpx, 256, 0, stream>>>(xe, Wih_e, bih_e, bhh_e, pxe, nullptr, B_ * T_, G4_, H_, 0, 0, H_);
    gemm_mfma<bf16, float><<<gpx, 256, 0, stream>>>(xa, Wih_a, bih_a, bhh_a, pxa, nullptr, B_ * T_, G4_, H_, 0, 0, H_);
    dim3 gpxw((B_ * S_ + 127) / 128, (G4_ + 127) / 128);
    gemm_mfma<bf16, float><<<gpxw, 256, 0, stream>>>(xw, Wih_w, bih_w, bhh_w, pxw, nullptr, B_ * S_, G4_, H_, 0, 0, H_);

    // 3. enc = tanh(enc_org @ W_align^T)[:, 1:]
    dim3 genc((B_ * L_ + 127) / 128, (H_ + 127) / 128);
    gemm_mfma<float, float><<<genc, 256, 0, stream>>>(enc_org, W_align, nullptr, nullptr, enc, nullptr, B_ * L_, H_, H_, 1, L_, H_);

    // 4. Counters scan
    counters_kernel<<<1, 64, 0, stream>>>(input_edits, org_ids, cd, ci, ca);

    // 5. Persistent cooperative LSTMs
    lstm_mfma_kernel<<<3 * NB_, 256, 0, stream>>>(pxe, pxa, pxw, Whh_e, Whh_a, Whh_w,
                                                  oute, outa, outw, hbuf, flags);

    // 6. c_word gather
    gather_cword_kernel<<<R_, 256, 0, stream>>>(outw, ci, cw);

    // 7. wref mixing
    ref_combine_kernel<<<R_, 256, 0, stream>>>(oute, outa, enc, W_ref, b_ref, cd, ca, ced, cac);

    // 8. q = c_word @ W_proj^T
    dim3 gproj((R_ + 127) / 128, (H_ + 127) / 128);
    gemm_mfma<bf16, float><<<gproj, 256, 0, stream>>>(cw, W_proj, nullptr, nullptr, qb, nullptr, R_, H_, H_, 0, 0, H_);

    // 9. attention
    attn_kernel<<<R_, 256, 0, stream>>>(qb, enc, app);

    // 10. feature concat
    feat_kernel<<<R_, 256, 0, stream>>>(oute, outa, app, ced, cac, cw, fe, fa);

    // 11. hidden layers (tanh, MFMA, K=3840)
    gemm_mfma<bf16, float><<<gproj, 256, 0, stream>>>(fe, W_mlp, b_mlp, nullptr, he, nullptr, R_, H_, K5_, 1, 0, K5_);
    gemm_mfma<bf16, float><<<gproj, 256, 0, stream>>>(fa, W_act, b_act, nullptr, ha, nullptr, R_, H_, K5_, 1, 0, K5_);

    // 12. act head + log-softmax
    dim3 gact((R_ + 127) / 128, (AV_ + 127) / 128);
    gemm_mfma<bf16, float><<<gact, 256, 0, stream>>>(ha, W_outact, b_outact, action_mask, nullptr, actbuf, R_, AV_, H_, 0, 0, H_);
    logsoftmax_act_kernel<<<R_, 256, 0, stream>>>(actbuf, act_out);

    // 13. edit head + in-place log-softmax
    dim3 gedit((R_ + 127) / 128, (V_ + 127) / 128);
    gemm_mfma<bf16, float><<<gedit, 256, 0, stream>>>(he, W_out, b_out, nullptr, nullptr, edit_out, R_, V_, H_, 0, 0, H_);
    logsoftmax_edit_kernel<<<R_, 1024, 0, stream>>>(edit_out);
}

// Round 10
// 2522.876 us; speedup vs baseline: 12.8005x; 1.0348x over previous
//
#include <hip/hip_runtime.h>
#include <hip/hip_bf16.h>

typedef __hip_bfloat16 bf16;

// Problem dims
#define B_    16
#define T_    128
#define S_    192
#define H_    768
#define G4_   3072      // 4*H
#define V_    30522
#define AV_   200
#define L_    191       // L_SRC-1
#define TM1_  127       // T-1
#define R_    2032      // B*(T-1)
#define K5_   3840      // 5*H
#define NB_   48        // blocks per LSTM (persistent)
#define HSL_  16        // h-slice per block (768/48)

typedef short bf16x8_t __attribute__((ext_vector_type(8)));
typedef float f32x4_t  __attribute__((ext_vector_type(4)));

__device__ __forceinline__ float bf2f(bf16 v) { return __bfloat162float(v); }
__device__ __forceinline__ bf16  f2bf(float v) { return __float2bfloat16(v); }
__device__ __forceinline__ unsigned short f2us(float v) { bf16 h = f2bf(v); return *reinterpret_cast<unsigned short*>(&h); }
__device__ __forceinline__ float uslo(unsigned u) { union { unsigned i; float f; } x; x.i = u << 16; return x.f; }
__device__ __forceinline__ float ushi(unsigned u) { union { unsigned i; float f; } x; x.i = u & 0xffff0000u; return x.f; }
__device__ __forceinline__ float us2f(unsigned short u) { union { unsigned i; float f; } x; x.i = ((unsigned)u) << 16; return x.f; }
__device__ __forceinline__ float sigm(float x) { return 1.0f / (1.0f + expf(-x)); }

// 8-element bf16 fragment loads (optionally converting from f32)
__device__ __forceinline__ bf16x8_t ld8bf(const bf16* p) { return *(const bf16x8_t*)p; }
__device__ __forceinline__ bf16x8_t ld8bf(const float* p) {
    float4 a = *(const float4*)p;
    float4 b = *(const float4*)(p + 4);
    bf16x8_t r;
    r[0] = (short)f2us(a.x); r[1] = (short)f2us(a.y); r[2] = (short)f2us(a.z); r[3] = (short)f2us(a.w);
    r[4] = (short)f2us(b.x); r[5] = (short)f2us(b.y); r[6] = (short)f2us(b.z); r[7] = (short)f2us(b.w);
    return r;
}

// ---------------------------------------------------------------------------
// MFMA GEMM: C[M,N] = act( A[M,K] * W[N,K]^T + bias1 + bias2 )
// 128x128 tile, 256 threads (4 waves in 2x2), K-step 32, bf16 staging in LDS.
// ---------------------------------------------------------------------------
template <typename TA, typename TW>
__global__ __launch_bounds__(256) void gemm_mfma(
    const TA* __restrict__ A, const TW* __restrict__ W,
    const float* __restrict__ bias1, const float* __restrict__ bias2,
    bf16* __restrict__ Ch, float* __restrict__ Cf,
    int M, int N, int K, int act, int rowdiv, int lda)
{
    __shared__ short As[128][40];
    __shared__ short Ws[128][40];
    const int tid = threadIdx.x;
    const int wave = tid >> 6, lane = tid & 63;
    const int mw = (wave >> 1) * 64, nw = (wave & 1) * 64;
    const int bm = blockIdx.x * 128, bn = blockIdx.y * 128;

    const int sr = tid >> 2;
    const int sc = (tid & 3) * 8;

    f32x4_t acc[4][4];
#pragma unroll
    for (int mi = 0; mi < 4; ++mi)
#pragma unroll
        for (int ni = 0; ni < 4; ++ni) acc[mi][ni] = (f32x4_t){0.f, 0.f, 0.f, 0.f};

    const int fr = lane & 15;
    const int fk = (lane >> 4) * 8;

    for (int k0 = 0; k0 < K; k0 += 32) {
#pragma unroll
        for (int c = 0; c < 2; ++c) {
            const int row = sr + c * 64;
            int ga = bm + row; if (ga > M - 1) ga = M - 1;
            const int ra = (rowdiv > 0) ? (ga + ga / rowdiv + 1) : ga;
            *(bf16x8_t*)&As[row][sc] = ld8bf(A + (size_t)ra * lda + k0 + sc);
            int gw = bn + row; if (gw > N - 1) gw = N - 1;
            *(bf16x8_t*)&Ws[row][sc] = ld8bf(W + (size_t)gw * K + k0 + sc);
        }
        __syncthreads();
        bf16x8_t af[4], wf[4];
#pragma unroll
        for (int i = 0; i < 4; ++i) af[i] = *(const bf16x8_t*)&As[mw + i * 16 + fr][fk];
#pragma unroll
        for (int i = 0; i < 4; ++i) wf[i] = *(const bf16x8_t*)&Ws[nw + i * 16 + fr][fk];
#pragma unroll
        for (int mi = 0; mi < 4; ++mi)
#pragma unroll
            for (int ni = 0; ni < 4; ++ni)
                acc[mi][ni] = __builtin_amdgcn_mfma_f32_16x16x32_bf16(af[mi], wf[ni], acc[mi][ni], 0, 0, 0);
        __syncthreads();
    }

    const int cl = lane & 15;
    const int rg = (lane >> 4) * 4;
#pragma unroll
    for (int mi = 0; mi < 4; ++mi) {
#pragma unroll
        for (int ni = 0; ni < 4; ++ni) {
            const int col = bn + nw + ni * 16 + cl;
            if (col >= N) continue;
#pragma unroll
            for (int j = 0; j < 4; ++j) {
                const int row = bm + mw + mi * 16 + rg + j;
                if (row >= M) continue;
                float v = acc[mi][ni][j];
                if (bias1) v += bias1[col];
                if (bias2) v += bias2[col];
                if (act == 1) v = tanhf(v);
                if (Ch) Ch[(size_t)row * N + col] = f2bf(v);
                else    Cf[(size_t)row * N + col] = v;
            }
        }
    }
}

// ---------------------------------------------------------------------------
// f32 -> bf16 bulk convert (for W_out)
// ---------------------------------------------------------------------------
__global__ void f2b_kernel(const float* __restrict__ in, bf16* __restrict__ out, int n4)
{
    const int i = blockIdx.x * 256 + threadIdx.x;
    if (i >= n4) return;
    float4 v = *(const float4*)(in + (size_t)i * 4);
    ushort4 o;
    o.x = f2us(v.x); o.y = f2us(v.y); o.z = f2us(v.z); o.w = f2us(v.w);
    *(ushort4*)(out + (size_t)i * 4) = o;
}

// ---------------------------------------------------------------------------
// Persistent cooperative LSTM. Grid = 3 LSTMs x 48 blocks, 256 threads.
// h exchange via device-coherent (agent-scope relaxed) accesses; per-step
// barrier = per-block flag stores + per-wave independent parallel poll.
// px for step t+1 prefetched into registers during the poll.
// ---------------------------------------------------------------------------
__global__ __launch_bounds__(256) void lstm_mfma_kernel(
    const bf16* __restrict__ pxe, const bf16* __restrict__ pxa, const bf16* __restrict__ pxw,
    const float* __restrict__ We, const float* __restrict__ Wa, const float* __restrict__ Ww,
    bf16* __restrict__ oute, bf16* __restrict__ outa, bf16* __restrict__ outw,
    unsigned short* __restrict__ hbuf, int* __restrict__ flags)
{
    const int which = blockIdx.x / NB_;
    const int nb = blockIdx.x % NB_;
    const bf16* px; const float* W; bf16* out; int Tn;
    if (which == 0)      { px = pxe; W = We; out = oute; Tn = T_; }
    else if (which == 1) { px = pxa; W = Wa; out = outa; Tn = T_; }
    else                 { px = pxw; W = Ww; out = outw; Tn = S_; }
    unsigned short* hG = hbuf + (size_t)which * (2 * B_ * H_);
    int* flg = flags + which * 64;   // 48 packed flags per LSTM

    const int tid = threadIdx.x;
    const int wv = tid >> 6;        // wave index = gate (i,f,g,o)
    const int lane = tid & 63;
    const int so = nb * HSL_;

    __shared__ unsigned short hL[16][776];        // h (bf16 bits), row-padded +8
    __shared__ float gS[4][16][17];               // gate exchange [gate][hl][batch]
    __shared__ unsigned short oring[8][16][16];   // out ring [step&7][batch][hl]

    // persistent A-fragments: lane l -> row (l&15), k = kb*32 + (l>>4)*8 + i
    bf16x8_t Afrag[24];
    {
        const int m = lane & 15;
        const int kb8 = (lane >> 4) * 8;
        const float* wrow = W + (size_t)(wv * H_ + so + m) * H_ + kb8;
#pragma unroll
        for (int kb = 0; kb < 24; ++kb) {
            float4 f0 = *(const float4*)(wrow + kb * 32);
            float4 f1 = *(const float4*)(wrow + kb * 32 + 4);
            bf16x8_t a;
            a[0] = (short)f2us(f0.x); a[1] = (short)f2us(f0.y);
            a[2] = (short)f2us(f0.z); a[3] = (short)f2us(f0.w);
            a[4] = (short)f2us(f1.x); a[5] = (short)f2us(f1.y);
            a[6] = (short)f2us(f1.z); a[7] = (short)f2us(f1.w);
            Afrag[kb] = a;
        }
    }

    // h_0 = 0
    for (int i = tid; i < 16 * 776; i += 256) ((unsigned short*)hL)[i] = 0;

    const int cb = tid >> 4;
    const int chl = tid & 15;
    float c = 0.f;

    const int bn = lane & 15;        // B-frag col = batch
    const int bk = (lane >> 4) * 8;  // B-frag k sub-offset

    // px prefetch for step 0 (raw bits; convert at use)
    unsigned short pxr0, pxr1, pxr2, pxr3;
    {
        const bf16* q = px + ((size_t)cb * Tn + 0) * G4_ + so + chl;
        pxr0 = *(const unsigned short*)(q);
        pxr1 = *(const unsigned short*)(q + H_);
        pxr2 = *(const unsigned short*)(q + 2 * H_);
        pxr3 = *(const unsigned short*)(q + 3 * H_);
    }

    int cur = 0;
    for (int step = 0; step < Tn; ++step) {
        if (step > 0) {
            // device-coherent h read, 8B-wide (bypasses stale L1/L2)
            const unsigned long long* hsrc =
                (const unsigned long long*)(hG + (size_t)cur * (B_ * H_));
            for (int i = tid; i < B_ * H_ / 4; i += 256) {
                const unsigned long long v =
                    __hip_atomic_load(hsrc + i, __ATOMIC_RELAXED, __HIP_MEMORY_SCOPE_AGENT);
                const int bb = i / (H_ / 4);
                const int cc = i - bb * (H_ / 4);
                ((unsigned long long*)&hL[bb][0])[cc] = v;
            }
        }
        __syncthreads();

        f32x4_t acc = {0.f, 0.f, 0.f, 0.f};
#pragma unroll
        for (int kb = 0; kb < 24; ++kb) {
            bf16x8_t bfr = *(const bf16x8_t*)&hL[bn][kb * 32 + bk];
            acc = __builtin_amdgcn_mfma_f32_16x16x32_bf16(Afrag[kb], bfr, acc, 0, 0, 0);
        }
        {
            const int m0 = (lane >> 4) * 4;
#pragma unroll
            for (int j = 0; j < 4; ++j) gS[wv][m0 + j][bn] = acc[j];
        }
        __syncthreads();

        // cell update (px from prefetched registers)
        {
            const float gi = gS[0][chl][cb] + us2f(pxr0);
            const float gf = gS[1][chl][cb] + us2f(pxr1);
            const float gg = gS[2][chl][cb] + us2f(pxr2);
            const float go = gS[3][chl][cb] + us2f(pxr3);
            const float cn = sigm(gf) * c + sigm(gi) * tanhf(gg);
            const float hn = sigm(go) * tanhf(cn);
            c = cn;
            oring[step & 7][cb][chl] = f2us(hn);
            // device-coherent h write (write-through to coherence point)
            __hip_atomic_store(&hG[(size_t)(cur ^ 1) * (B_ * H_) + cb * H_ + so + chl],
                               f2us(hn), __ATOMIC_RELAXED, __HIP_MEMORY_SCOPE_AGENT);
        }
        // flush out ring every 8 steps (plain cached stores; visible at kernel end)
        if ((step & 7) == 7 || step == Tn - 1) {
            const int base = step & ~7;
            const int cnt8 = (step & 7) + 1;
            for (int s2 = 0; s2 < cnt8; ++s2)
                out[((size_t)cb * Tn + base + s2) * H_ + so + chl] =
                    *reinterpret_cast<const bf16*>(&oring[s2][cb][chl]);
        }

        if (step + 1 < Tn) {
            __syncthreads();   // drains vmcnt -> h stores globally complete
            const int target = step + 1;
            if (tid == 0)
                __hip_atomic_store(&flg[nb], target, __ATOMIC_RELAXED, __HIP_MEMORY_SCOPE_AGENT);
            // prefetch next step's px (loads in flight during the poll)
            {
                const bf16* q = px + ((size_t)cb * Tn + target) * G4_ + so + chl;
                pxr0 = *(const unsigned short*)(q);
                pxr1 = *(const unsigned short*)(q + H_);
                pxr2 = *(const unsigned short*)(q + 2 * H_);
                pxr3 = *(const unsigned short*)(q + 3 * H_);
            }
            // every wave polls independently (lanes 0..47 each own one flag);
            // no sync after — waves proceed straight into next step's staging.
            if (lane < NB_) {
                long guard = 0;
                while (__hip_atomic_load(&flg[lane], __ATOMIC_RELAXED, __HIP_MEMORY_SCOPE_AGENT) < target) {
                    __builtin_amdgcn_s_sleep(1);
                    if (++guard > 50000000L) break;   // liveness guard
                }
            }
        }
        cur ^= 1;
    }
}

// ---------------------------------------------------------------------------
// Row gather + convert: out[r][:] = bf16(emb[ids[r]][:])
// ---------------------------------------------------------------------------
__global__ void gather_rows_kernel(const int* __restrict__ ids,
                                   const float* __restrict__ emb,
                                   bf16* __restrict__ out)
{
    const int r = blockIdx.x;
    const float4* src = (const float4*)(emb + (size_t)ids[r] * H_);
    ushort4* dst = (ushort4*)(out + (size_t)r * H_);
    for (int h = threadIdx.x; h < H_ / 4; h += 256) {
        float4 v = src[h];
        ushort4 o;
        o.x = f2us(v.x); o.y = f2us(v.y); o.z = f2us(v.z); o.w = f2us(v.w);
        dst[h] = o;
    }
}

// ---------------------------------------------------------------------------
// Counters scan
// ---------------------------------------------------------------------------
__global__ void counters_kernel(const int* __restrict__ edits, const int* __restrict__ org,
                                int* __restrict__ cd, int* __restrict__ ci, int* __restrict__ ca)
{
    const int b = threadIdx.x;
    if (b >= B_) return;
    int vd = 0, vi = 0, va = 0;
    for (int t = 0; t < TM1_; ++t) {
        cd[b * TM1_ + t] = vd; ci[b * TM1_ + t] = vi; ca[b * TM1_ + t] = va;
        const int g = edits[b * T_ + t + 1];
        const int vd2 = vd + ((g == 3 || g == 4) ? 1 : 0);
        const int alive = (g != 4 && g != 2 && g != 0) ? 1 : 0;
        const int vi2 = vi + alive;
        int nxt = va + 1; if (nxt > L_ - 1) nxt = L_ - 1;
        const int tok = org[b * L_ + nxt];
        const bool cond = alive && (g != 3) && (va + 1 < L_) && (tok == 103 || tok == 3 || tok == 4);
        const int va2 = cond ? (va + 1) : max(vd2, va);
        vd = vd2; vi = vi2; va = va2;
    }
}

// c_word[r][:] = out_w[b][ci[r]][:]
__global__ void gather_cword_kernel(const bf16* __restrict__ outw, const int* __restrict__ ci,
                                    bf16* __restrict__ cw)
{
    const int r = blockIdx.x;
    const int b = r / TM1_;
    const unsigned* src = (const unsigned*)(outw + ((size_t)b * S_ + ci[r]) * H_);
    unsigned* dst = (unsigned*)(cw + (size_t)r * H_);
    for (int h = threadIdx.x; h < H_ / 2; h += 256) dst[h] = src[h];
}

// ---------------------------------------------------------------------------
// wref softmax (2-way) + mix c_input/c_anno
// ---------------------------------------------------------------------------
__global__ __launch_bounds__(256) void ref_combine_kernel(
    const bf16* __restrict__ oute, const bf16* __restrict__ outa, const bf16* __restrict__ enc,
    const float* __restrict__ Wref, const float* __restrict__ bref,
    const int* __restrict__ cd, const int* __restrict__ ca,
    bf16* __restrict__ ced, bf16* __restrict__ cac)
{
    const int r = blockIdx.x;
    const int b = r / TM1_;
    const int t = r % TM1_;
    const bf16* de = oute + ((size_t)b * T_ + t) * H_;
    const bf16* da = outa + ((size_t)b * T_ + t) * H_;
    const int tid = threadIdx.x;
    __shared__ float red[256][4];
    float s0 = 0.f, s1 = 0.f, s2 = 0.f, s3 = 0.f;
    for (int k = tid; k < H_; k += 256) {
        const float w0 = Wref[k];
        const float w1 = Wref[H_ + k];
        const float e = bf2f(de[k]);
        const float a = bf2f(da[k]);
        s0 += e * w0; s1 += e * w1; s2 += a * w0; s3 += a * w1;
    }
    red[tid][0] = s0; red[tid][1] = s1; red[tid][2] = s2; red[tid][3] = s3;
    __syncthreads();
    for (int off = 128; off > 0; off >>= 1) {
        if (tid < off) {
            red[tid][0] += red[tid + off][0];
            red[tid][1] += red[tid + off][1];
            red[tid][2] += red[tid + off][2];
            red[tid][3] += red[tid + off][3];
        }
        __syncthreads();
    }
    const float br0 = bref[0], br1 = bref[1];
    const float xe0 = red[0][0] + br0, xe1 = red[0][1] + br1;
    const float xa0 = red[0][2] + br0, xa1 = red[0][3] + br1;
    const float me = fmaxf(xe0, xe1);
    const float ee0 = expf(xe0 - me), ee1 = expf(xe1 - me);
    const float pe0 = ee0 / (ee0 + ee1), pe1 = ee1 / (ee0 + ee1);
    const float ma = fmaxf(xa0, xa1);
    const float ea0 = expf(xa0 - ma), ea1 = expf(xa1 - ma);
    const float pa0 = ea0 / (ea0 + ea1), pa1 = ea1 / (ea0 + ea1);

    const bf16* ei = enc + ((size_t)b * L_ + cd[r]) * H_;
    const bf16* ea = enc + ((size_t)b * L_ + ca[r]) * H_;
    for (int h = tid; h < H_; h += 256) {
        const float vi = bf2f(ei[h]);
        const float va = bf2f(ea[h]);
        ced[(size_t)r * H_ + h] = f2bf(pe0 * vi + pe1 * va);
        cac[(size_t)r * H_ + h] = f2bf(pa0 * vi + pa1 * va);
    }
}

// ---------------------------------------------------------------------------
// Attention over L=191
// ---------------------------------------------------------------------------
__global__ __launch_bounds__(256) void attn_kernel(const bf16* __restrict__ q,
                                                   const bf16* __restrict__ enc,
                                                   bf16* __restrict__ app)
{
    const int r = blockIdx.x;
    const int b = r / TM1_;
    const int tid = threadIdx.x;
    __shared__ float qs[H_];
    __shared__ float p[L_ + 1];
    __shared__ float red[256];
    const bf16* qrow = q + (size_t)r * H_;
    for (int h = tid; h < H_; h += 256) qs[h] = bf2f(qrow[h]);
    __syncthreads();
    const bf16* eb = enc + (size_t)b * L_ * H_;
    float myv = -1e30f;
    if (tid < L_) {
        const unsigned* er = (const unsigned*)(eb + (size_t)tid * H_);
        float s = 0.f;
        for (int k2 = 0; k2 < H_ / 2; ++k2) {
            const unsigned u = er[k2];
            s += qs[2 * k2] * uslo(u) + qs[2 * k2 + 1] * ushi(u);
        }
        p[tid] = s;
        myv = s;
    }
    red[tid] = myv;
    __syncthreads();
    for (int off = 128; off > 0; off >>= 1) {
        if (tid < off) red[tid] = fmaxf(red[tid], red[tid + off]);
        __syncthreads();
    }
    const float m = red[0];
    __syncthreads();
    float e = 0.f;
    if (tid < L_) e = expf(p[tid] - m);
    red[tid] = e;
    __syncthreads();
    for (int off = 128; off > 0; off >>= 1) {
        if (tid < off) red[tid] += red[tid + off];
        __syncthreads();
    }
    const float invZ = 1.f / red[0];
    __syncthreads();
    if (tid < L_) p[tid] = e * invZ;
    __syncthreads();
    for (int h = tid; h < H_; h += 256) {
        float s = 0.f;
        for (int l = 0; l < L_; ++l) s += p[l] * bf2f(eb[(size_t)l * H_ + h]);
        app[(size_t)r * H_ + h] = f2bf(s);
    }
}

// feat_e = [dec_e, dec_a, app, ced, cw]; feat_a = [dec_a, dec_e, app, cac, cw]
__global__ void feat_kernel(const bf16* __restrict__ oute, const bf16* __restrict__ outa,
                            const bf16* __restrict__ app, const bf16* __restrict__ ced,
                            const bf16* __restrict__ cac, const bf16* __restrict__ cw,
                            bf16* __restrict__ fe, bf16* __restrict__ fa)
{
    const int r = blockIdx.x;
    const int b = r / TM1_;
    const int t = r % TM1_;
    const unsigned* de  = (const unsigned*)(oute + ((size_t)b * T_ + t) * H_);
    const unsigned* da  = (const unsigned*)(outa + ((size_t)b * T_ + t) * H_);
    const unsigned* ap  = (const unsigned*)(app + (size_t)r * H_);
    const unsigned* ce  = (const unsigned*)(ced + (size_t)r * H_);
    const unsigned* cA  = (const unsigned*)(cac + (size_t)r * H_);
    const unsigned* cwp = (const unsigned*)(cw + (size_t)r * H_);
    unsigned* pfe = (unsigned*)(fe + (size_t)r * K5_);
    unsigned* pfa = (unsigned*)(fa + (size_t)r * K5_);
    const int HW = H_ / 2;
    for (int h = threadIdx.x; h < HW; h += 256) {
        const unsigned ve = de[h], va = da[h], vap = ap[h], vce = ce[h], vca = cA[h], vcw = cwp[h];
        pfe[h] = ve;  pfe[HW + h] = va;  pfe[2 * HW + h] = vap; pfe[3 * HW + h] = vce; pfe[4 * HW + h] = vcw;
        pfa[h] = va;  pfa[HW + h] = ve;  pfa[2 * HW + h] = vap; pfa[3 * HW + h] = vca; pfa[4 * HW + h] = vcw;
    }
}

// In-place log-softmax over f32 rows (edit head, N=30522).
// Single global read: row cached as bf16 in LDS; shuffle-based reduction.
__global__ __launch_bounds__(1024) void logsoftmax_edit_kernel(float* __restrict__ out)
{
    float* row = out + (size_t)blockIdx.x * V_;
    const int tid = threadIdx.x;
    const int lane = tid & 63;
    const int wid = tid >> 6;
    __shared__ unsigned short rowb[V_];   // 61,044 B
    __shared__ float wredm[16], wreds[16];
    __shared__ float fin;

    float m = -1e30f, s = 0.f;
    for (int i = tid; i < V_; i += 1024) {
        const float x = row[i];
        rowb[i] = f2us(x);
        if (x > m) { s = s * expf(m - x) + 1.f; m = x; }
        else s += expf(x - m);
    }
    // wave reduction
#pragma unroll
    for (int off = 32; off > 0; off >>= 1) {
        const float m2 = __shfl_down(m, off);
        const float s2 = __shfl_down(s, off);
        const float mn = fmaxf(m, m2);
        s = s * expf(m - mn) + s2 * expf(m2 - mn);
        m = mn;
    }
    if (lane == 0) { wredm[wid] = m; wreds[wid] = s; }
    __syncthreads();
    if (wid == 0) {
        m = (lane < 16) ? wredm[lane] : -1e30f;
        s = (lane < 16) ? wreds[lane] : 0.f;
#pragma unroll
        for (int off = 8; off > 0; off >>= 1) {
            const float m2 = __shfl_down(m, off);
            const float s2 = __shfl_down(s, off);
            const float mn = fmaxf(m, m2);
            s = s * expf(m - mn) + s2 * expf(m2 - mn);
            m = mn;
        }
        if (lane == 0) fin = m + logf(s);
    }
    __syncthreads();
    const float lz = fin;
    for (int i = tid; i < V_; i += 1024) row[i] = us2f(rowb[i]) - lz;
}

// Act head log-softmax: f32 in -> f32 out
__global__ __launch_bounds__(256) void logsoftmax_act_kernel(const float* __restrict__ in,
                                                             float* __restrict__ out)
{
    const float* row = in + (size_t)blockIdx.x * AV_;
    float* orow = out + (size_t)blockIdx.x * AV_;
    const int tid = threadIdx.x;
    __shared__ float red[256];
    float m = -1e30f;
    if (tid < AV_) m = row[tid];
    red[tid] = m;
    __syncthreads();
    for (int off = 128; off > 0; off >>= 1) {
        if (tid < off) red[tid] = fmaxf(red[tid], red[tid + off]);
        __syncthreads();
    }
    m = red[0];
    __syncthreads();
    float s = 0.f;
    if (tid < AV_) s = expf(row[tid] - m);
    red[tid] = s;
    __syncthreads();
    for (int off = 128; off > 0; off >>= 1) {
        if (tid < off) red[tid] += red[tid + off];
        __syncthreads();
    }
    const float lz = m + logf(red[0]);
    if (tid < AV_) orow[tid] = row[tid] - lz;
}

// ---------------------------------------------------------------------------
extern "C" void kernel_launch(void* const* d_in, const int* in_sizes, int n_in,
                              void* d_out, int out_size, void* d_ws, size_t ws_size,
                              hipStream_t stream)
{
    const int* input_edits   = (const int*)d_in[0];
    const int* input_actions = (const int*)d_in[1];
    const int* simp_sent     = (const int*)d_in[2];
    const int* org_ids       = (const int*)d_in[3];
    const float* enc_org     = (const float*)d_in[4];
    const float* emb         = (const float*)d_in[5];
    const float* Wih_e = (const float*)d_in[6];
    const float* Whh_e = (const float*)d_in[7];
    const float* bih_e = (const float*)d_in[8];
    const float* bhh_e = (const float*)d_in[9];
    const float* Wih_a = (const float*)d_in[10];
    const float* Whh_a = (const float*)d_in[11];
    const float* bih_a = (const float*)d_in[12];
    const float* bhh_a = (const float*)d_in[13];
    const float* Wih_w = (const float*)d_in[14];
    const float* Whh_w = (const float*)d_in[15];
    const float* bih_w = (const float*)d_in[16];
    const float* bhh_w = (const float*)d_in[17];
    const float* W_align = (const float*)d_in[18];
    const float* W_proj  = (const float*)d_in[19];
    const float* W_ref   = (const float*)d_in[20];
    const float* b_ref   = (const float*)d_in[21];
    const float* W_mlp   = (const float*)d_in[22];
    const float* b_mlp   = (const float*)d_in[23];
    const float* W_act   = (const float*)d_in[24];
    const float* b_act   = (const float*)d_in[25];
    const float* W_out   = (const float*)d_in[26];
    const float* b_out   = (const float*)d_in[27];
    const float* W_outact = (const float*)d_in[28];
    const float* b_outact = (const float*)d_in[29];
    const float* action_mask = (const float*)d_in[30];

    float* out = (float*)d_out;
    float* edit_out = out;                               // (2032, 30522) f32
    float* act_out  = out + (size_t)R_ * V_;             // (2032, 200)   f32

    // Workspace layout
    char* p = (char*)d_ws;
    auto take = [&](size_t bytes) { void* q = (void*)p; p += ((bytes + 255) / 256) * 256; return q; };
    int* flags = (int*)take(3 * 256);                    // 3 x 64-int flag arrays
    unsigned short* hbuf = (unsigned short*)take((size_t)3 * 2 * B_ * H_ * 2);
    char* alias_base = p;                                // xe..pxw region (dead after LSTM)
    bf16* xe   = (bf16*)take((size_t)B_ * T_ * H_ * 2);
    bf16* xa   = (bf16*)take((size_t)B_ * T_ * H_ * 2);
    bf16* xw   = (bf16*)take((size_t)B_ * S_ * H_ * 2);
    bf16* pxe  = (bf16*)take((size_t)B_ * T_ * G4_ * 2);
    bf16* pxa  = (bf16*)take((size_t)B_ * T_ * G4_ * 2);
    bf16* pxw  = (bf16*)take((size_t)B_ * S_ * G4_ * 2);
    bf16* oute = (bf16*)take((size_t)B_ * T_ * H_ * 2);
    bf16* outa = (bf16*)take((size_t)B_ * T_ * H_ * 2);
    bf16* outw = (bf16*)take((size_t)B_ * S_ * H_ * 2);
    bf16* enc  = (bf16*)take((size_t)B_ * L_ * H_ * 2);
    bf16* cw   = (bf16*)take((size_t)R_ * H_ * 2);
    bf16* ced  = (bf16*)take((size_t)R_ * H_ * 2);
    bf16* cac  = (bf16*)take((size_t)R_ * H_ * 2);
    bf16* qb   = (bf16*)take((size_t)R_ * H_ * 2);
    bf16* app  = (bf16*)take((size_t)R_ * H_ * 2);
    bf16* fe   = (bf16*)take((size_t)R_ * K5_ * 2);
    bf16* fa   = (bf16*)take((size_t)R_ * K5_ * 2);
    bf16* he   = (bf16*)take((size_t)R_ * H_ * 2);
    bf16* ha   = (bf16*)take((size_t)R_ * H_ * 2);
    int*  cd   = (int*)take((size_t)R_ * 4);
    int*  ci   = (int*)take((size_t)R_ * 4);
    int*  ca   = (int*)take((size_t)R_ * 4);
    float* actbuf = (float*)take((size_t)R_ * AV_ * 4);
    // W_out in bf16, aliased over the xe..pxw region (55 MB >= 46.9 MB needed).
    bf16* Wob = (bf16*)alias_base;

    // 0. Zero barrier flags
    hipMemsetAsync(flags, 0, 3 * 256, stream);

    // 1. Embedding gathers
    gather_rows_kernel<<<B_ * T_, 256, 0, stream>>>(input_edits, emb, xe);
    gather_rows_kernel<<<B_ * T_, 256, 0, stream>>>(input_actions, emb, xa);
    gather_rows_kernel<<<B_ * S_, 256, 0, stream>>>(simp_sent, emb, xw);

    // 2. px = x@Wih^T + bih + bhh (MFMA)
    dim3 gpx((B_ * T_ + 127) / 128, (G4_ + 127) / 128);
    gemm_mfma<bf16, float><<<gpx, 256, 0, stream>>>(xe, Wih_e, bih_e, bhh_e, pxe, nullptr, B_ * T_, G4_, H_, 0, 0, H_);
    gemm_mfma<bf16, float><<<gpx, 256, 0, stream>>>(xa, Wih_a, bih_a, bhh_a, pxa, nullptr, B_ * T_, G4_, H_, 0, 0, H_);
    dim3 gpxw((B_ * S_ + 127) / 128, (G4_ + 127) / 128);
    gemm_mfma<bf16, float><<<gpxw, 256, 0, stream>>>(xw, Wih_w, bih_w, bhh_w, pxw, nullptr, B_ * S_, G4_, H_, 0, 0, H_);

    // 3. enc = tanh(enc_org @ W_align^T)[:, 1:]
    dim3 genc((B_ * L_ + 127) / 128, (H_ + 127) / 128);
    gemm_mfma<float, float><<<genc, 256, 0, stream>>>(enc_org, W_align, nullptr, nullptr, enc, nullptr, B_ * L_, H_, H_, 1, L_, H_);

    // 4. Counters scan
    counters_kernel<<<1, 64, 0, stream>>>(input_edits, org_ids, cd, ci, ca);

    // 5. Persistent cooperative LSTMs
    lstm_mfma_kernel<<<3 * NB_, 256, 0, stream>>>(pxe, pxa, pxw, Whh_e, Whh_a, Whh_w,
                                                  oute, outa, outw, hbuf, flags);

    // 5.5 W_out -> bf16 (px/x buffers dead now; Wob aliases them)
    const int nW4 = V_ * H_ / 4;
    f2b_kernel<<<(nW4 + 255) / 256, 256, 0, stream>>>(W_out, Wob, nW4);

    // 6. c_word gather
    gather_cword_kernel<<<R_, 256, 0, stream>>>(outw, ci, cw);

    // 7. wref mixing
    ref_combine_kernel<<<R_, 256, 0, stream>>>(oute, outa, enc, W_ref, b_ref, cd, ca, ced, cac);

    // 8. q = c_word @ W_proj^T
    dim3 gproj((R_ + 127) / 128, (H_ + 127) / 128);
    gemm_mfma<bf16, float><<<gproj, 256, 0, stream>>>(cw, W_proj, nullptr, nullptr, qb, nullptr, R_, H_, H_, 0, 0, H_);

    // 9. attention
    attn_kernel<<<R_, 256, 0, stream>>>(qb, enc, app);

    // 10. feature concat
    feat_kernel<<<R_, 256, 0, stream>>>(oute, outa, app, ced, cac, cw, fe, fa);

    // 11. hidden layers (tanh, MFMA, K=3840)
    gemm_mfma<bf16, float><<<gproj, 256, 0, stream>>>(fe, W_mlp, b_mlp, nullptr, he, nullptr, R_, H_, K5_, 1, 0, K5_);
    gemm_mfma<bf16, float><<<gproj, 256, 0, stream>>>(fa, W_act, b_act, nullptr, ha, nullptr, R_, H_, K5_, 1, 0, K5_);

    // 12. act head + log-softmax
    dim3 gact((R_ + 127) / 128, (AV_ + 127) / 128);
    gemm_mfma<bf16, float><<<gact, 256, 0, stream>>>(ha, W_outact, b_outact, action_mask, nullptr, actbuf, R_, AV_, H_, 0, 0, H_);
    logsoftmax_act_kernel<<<R_, 256, 0, stream>>>(actbuf, act_out);

    // 13. edit head (bf16 W) + in-place log-softmax
    dim3 gedit((R_ + 127) / 128, (V_ + 127) / 128);
    gemm_mfma<bf16, bf16><<<gedit, 256, 0, stream>>>(he, Wob, b_out, nullptr, nullptr, edit_out, R_, V_, H_, 0, 0, H_);
    logsoftmax_edit_kernel<<<R_, 1024, 0, stream>>>(edit_out);
}